// Round 3
// baseline (7727.132 us; speedup 1.0000x reference)
//
#include <hip/hip_runtime.h>
#include <hip/hip_bf16.h>

typedef __hip_bfloat16 bf16;

#define N_NODES 16384
#define HDIM    256
#define NE      131072
#define NE2     147456   // NE + N self loops

__device__ __forceinline__ float b2f(bf16 v){ return __bfloat162float(v); }
__device__ __forceinline__ bf16  f2b(float v){ return __float2bfloat16(v); }
__device__ __forceinline__ float us2f(unsigned short u){
  union { unsigned int i; float f; } c; c.i = ((unsigned int)u) << 16; return c.f;
}
__device__ __forceinline__ unsigned short f2us(float f){
  bf16 h = __float2bfloat16(f);
  unsigned short u; __builtin_memcpy(&u, &h, 2); return u;
}
// fast-math-proof NaN/Inf test (bit pattern, cannot be folded)
__device__ __forceinline__ bool badf(float v){
  unsigned u = __float_as_uint(v); return ((u >> 23) & 0xFF) == 0xFF;
}
__device__ __forceinline__ float gelu_f(float x){
  return 0.5f * x * (1.0f + erff(x * 0.7071067811865476f));
}
__device__ __forceinline__ float wave_sum(float v){
  #pragma unroll
  for (int o = 32; o > 0; o >>= 1) v += __shfl_xor(v, o);
  return v;
}
__device__ __forceinline__ float wave_max(float v){
  #pragma unroll
  for (int o = 32; o > 0; o >>= 1) v = fmaxf(v, __shfl_xor(v, o));
  return v;
}
__device__ __forceinline__ float block_sum_256(float v, float* red){
  v = wave_sum(v);
  __syncthreads();
  if ((threadIdx.x & 63) == 0) red[threadIdx.x >> 6] = v;
  __syncthreads();
  return red[0] + red[1] + red[2] + red[3];
}

__device__ __forceinline__ float4 load4(const float* p){ return *(const float4*)p; }
__device__ __forceinline__ float4 load4(const bf16* p){
  ushort4 u = *(const ushort4*)p;
  return make_float4(us2f(u.x), us2f(u.y), us2f(u.z), us2f(u.w));
}
__device__ __forceinline__ void store4(float* p, float4 v){ *(float4*)p = v; }
__device__ __forceinline__ void store4(bf16* p, float4 v){
  ushort4 u = make_ushort4(f2us(v.x), f2us(v.y), f2us(v.z), f2us(v.w));
  *(ushort4*)p = u;
}

// ---------------------------------------------------------------------------
// dtype detection + normalization
// flags[0] = NaN-phase bits, flags[1] = input-is-f32
// ---------------------------------------------------------------------------
__global__ void detect_dtype(const unsigned short* __restrict__ x, int n, int* __restrict__ flags){
  int i = blockIdx.x * 256 + threadIdx.x;
  if (i < n) {
    unsigned short u = x[i];
    if ((u & 0x7F80) == 0x7F80) atomicOr(&flags[1], 1);  // bf16 NaN/Inf pattern
  }
}
__global__ void conv_in(const void* __restrict__ src, unsigned short* __restrict__ dst,
                        int n, const int* __restrict__ flags){
  int i = blockIdx.x * 256 + threadIdx.x;
  if (i >= n) return;
  if (flags[1]) dst[i] = f2us(((const float*)src)[i]);
  else          dst[i] = ((const unsigned short*)src)[i];
}
__global__ void emit_out(const unsigned short* __restrict__ stage, void* __restrict__ out,
                         int n, const int* __restrict__ flags){
  int i = blockIdx.x * 256 + threadIdx.x;
  if (i >= n) return;
  if (flags[1]) ((float*)out)[i] = us2f(stage[i]);
  else          ((unsigned short*)out)[i] = stage[i];
}

// ---------------------------------------------------------------------------
// Diagnostics
// ---------------------------------------------------------------------------
__global__ void write_sentinel(bf16* out, float v){ out[threadIdx.x] = f2b(v); }
__global__ void scrub(float* __restrict__ buf, int n, int* __restrict__ flag, int which){
  int i = blockIdx.x * 256 + threadIdx.x;
  if (i < n) {
    float v = buf[i];
    if (badf(v)) { buf[i] = 0.5f; atomicOr(flag, 1 << which); }
  }
}
__global__ void flag_report(const int* __restrict__ flags, void* __restrict__ out){
  if (threadIdx.x == 0) {
    int f = flags[0];
    float code = 0.f;
    if (f & 1) code = 100.f;
    else if (f & 2) code = 200.f;
    else if (f & 4) code = 300.f;
    if (code != 0.f) {
      if (flags[1]) code += 50.f;
      for (int i = 0; i < 256; ++i) {
        if (flags[1]) ((float*)out)[i] = code;
        else          ((unsigned short*)out)[i] = f2us(code);
      }
    }
  }
}

// ---------------------------------------------------------------------------
// Generic NT GEMM: C[M,Nn] = A[M,K] * W[Nn,K]^T (+bias) (+epilogue)
// EPI: 0 = bias only, 1 = gelu, 2 = residual add. M%64==0, Nn%64==0, K%32==0.
// ---------------------------------------------------------------------------
template<typename TA, typename TO, int EPI>
__global__ __launch_bounds__(256) void gemm_nt(
    const TA* __restrict__ A, const bf16* __restrict__ W,
    const bf16* __restrict__ bias, const float* __restrict__ res,
    TO* __restrict__ C, int M, int Nn, int K)
{
  __shared__ float As[32][68];
  __shared__ float Bs[32][68];
  const int tid = threadIdx.x;
  const int tx = tid & 15, ty = tid >> 4;
  const int row0 = blockIdx.y << 6, col0 = blockIdx.x << 6;
  float acc[4][4] = {};
  for (int kt = 0; kt < K; kt += 32) {
    #pragma unroll
    for (int it = 0; it < 2; ++it) {
      int s  = tid + it * 256;
      int r  = s >> 3;          // 0..63
      int kk = (s & 7) << 2;    // 0,4,...,28
      float4 av = load4(A + (size_t)(row0 + r) * K + kt + kk);
      As[kk+0][r] = av.x; As[kk+1][r] = av.y; As[kk+2][r] = av.z; As[kk+3][r] = av.w;
      float4 bv = load4(W + (size_t)(col0 + r) * K + kt + kk);
      Bs[kk+0][r] = bv.x; Bs[kk+1][r] = bv.y; Bs[kk+2][r] = bv.z; Bs[kk+3][r] = bv.w;
    }
    __syncthreads();
    #pragma unroll
    for (int kk = 0; kk < 32; ++kk) {
      float4 a = *(const float4*)&As[kk][ty << 2];
      float4 b = *(const float4*)&Bs[kk][tx << 2];
      acc[0][0] += a.x*b.x; acc[0][1] += a.x*b.y; acc[0][2] += a.x*b.z; acc[0][3] += a.x*b.w;
      acc[1][0] += a.y*b.x; acc[1][1] += a.y*b.y; acc[1][2] += a.y*b.z; acc[1][3] += a.y*b.w;
      acc[2][0] += a.z*b.x; acc[2][1] += a.z*b.y; acc[2][2] += a.z*b.z; acc[2][3] += a.z*b.w;
      acc[3][0] += a.w*b.x; acc[3][1] += a.w*b.y; acc[3][2] += a.w*b.z; acc[3][3] += a.w*b.w;
    }
    __syncthreads();
  }
  const int c0 = col0 + (tx << 2);
  #pragma unroll
  for (int i = 0; i < 4; ++i) {
    int r = row0 + (ty << 2) + i;
    size_t base = (size_t)r * Nn + c0;
    float v0 = acc[i][0], v1 = acc[i][1], v2 = acc[i][2], v3 = acc[i][3];
    if (bias) {
      v0 += b2f(bias[c0+0]); v1 += b2f(bias[c0+1]);
      v2 += b2f(bias[c0+2]); v3 += b2f(bias[c0+3]);
    }
    if (EPI == 1) { v0 = gelu_f(v0); v1 = gelu_f(v1); v2 = gelu_f(v2); v3 = gelu_f(v3); }
    if (EPI == 2) {
      float4 rv = *(const float4*)(res + base);
      v0 += rv.x; v1 += rv.y; v2 += rv.z; v3 += rv.w;
    }
    store4(C + base, make_float4(v0, v1, v2, v3));
  }
}

// ---------------------------------------------------------------------------
// CSR build over dst
// ---------------------------------------------------------------------------
__global__ void csr_count(const int* __restrict__ edst, int* __restrict__ cnt){
  int e = blockIdx.x * 256 + threadIdx.x;
  if (e < NE2) {
    int d = (e < NE) ? edst[e] : (e - NE);
    atomicAdd(&cnt[d], 1);
  }
}
__global__ __launch_bounds__(1024) void csr_scan(const int* __restrict__ cnt, int* __restrict__ off){
  __shared__ int ls[1024];
  int t = threadIdx.x;
  int base = t * 16;
  int loc[16]; int s = 0;
  #pragma unroll
  for (int j = 0; j < 16; ++j) { loc[j] = s; s += cnt[base + j]; }
  ls[t] = s;
  __syncthreads();
  for (int o = 1; o < 1024; o <<= 1) {
    int v = (t >= o) ? ls[t - o] : 0;
    __syncthreads();
    ls[t] += v;
    __syncthreads();
  }
  int pre = (t == 0) ? 0 : ls[t - 1];
  #pragma unroll
  for (int j = 0; j < 16; ++j) off[base + j] = pre + loc[j];
  if (t == 1023) off[N_NODES] = ls[1023];
}
__global__ void csr_fill(const int* __restrict__ edst, const int* __restrict__ off,
                         int* __restrict__ fillc, int* __restrict__ list){
  int e = blockIdx.x * 256 + threadIdx.x;
  if (e < NE2) {
    int d = (e < NE) ? edst[e] : (e - NE);
    int p = atomicAdd(&fillc[d], 1);
    list[off[d] + p] = e;
  }
}

// ---------------------------------------------------------------------------
// GAT pieces (hp is bf16)
// ---------------------------------------------------------------------------
__global__ __launch_bounds__(256) void gat_alsd(
    const bf16* __restrict__ hp, const bf16* __restrict__ a_s, const bf16* __restrict__ a_d,
    float* __restrict__ al_s, float* __restrict__ al_d)
{
  int i = blockIdx.x; int g = threadIdx.x >> 6; int lane = threadIdx.x & 63;
  const bf16* hr = hp + ((size_t)i * 4 + g) * 256;
  float s1 = 0.f, s2 = 0.f;
  #pragma unroll
  for (int j = 0; j < 4; ++j) {
    int c = j * 64 + lane;
    float hv = b2f(hr[c]);
    s1 += hv * b2f(a_s[g * 256 + c]);
    s2 += hv * b2f(a_d[g * 256 + c]);
  }
  s1 = wave_sum(s1); s2 = wave_sum(s2);
  if (lane == 0) { al_s[i * 4 + g] = s1; al_d[i * 4 + g] = s2; }
}
__global__ __launch_bounds__(256) void gat_edge(
    const int* __restrict__ esrc,
    const float* __restrict__ al_s, const float* __restrict__ al_d,
    const int* __restrict__ off, const int* __restrict__ list,
    float* __restrict__ exw, float* __restrict__ den)
{
  int i = blockIdx.x; int g = threadIdx.x >> 6; int lane = threadIdx.x & 63;
  int start = off[i]; int deg = off[i + 1] - start;
  float ad = al_d[i * 4 + g];
  float mx = -1e30f;
  for (int e = lane; e < deg; e += 64) {
    int edge = list[start + e];
    int s = (edge < NE) ? esrc[edge] : (edge - NE);
    float v = al_s[s * 4 + g] + ad;
    v = (v > 0.f) ? v : 0.2f * v;
    mx = fmaxf(mx, v);
  }
  mx = wave_max(mx);
  float sum = 0.f;
  for (int e = lane; e < deg; e += 64) {
    int edge = list[start + e];
    int s = (edge < NE) ? esrc[edge] : (edge - NE);
    float v = al_s[s * 4 + g] + ad;
    v = (v > 0.f) ? v : 0.2f * v;
    float ex = expf(v - mx);
    exw[(size_t)edge * 4 + g] = ex;
    sum += ex;
  }
  sum = wave_sum(sum);
  if (lane == 0) den[i * 4 + g] = sum;
}
__global__ __launch_bounds__(256) void gat_agg(
    const int* __restrict__ esrc, const bf16* __restrict__ hp,
    const float* __restrict__ exw, const float* __restrict__ den,
    const int* __restrict__ off, const int* __restrict__ list,
    const bf16* __restrict__ bias, const bf16* __restrict__ gg, const bf16* __restrict__ gb,
    float* __restrict__ h)
{
  __shared__ float msg[4][256];
  __shared__ float red[4];
  int i = blockIdx.x; int tid = threadIdx.x;
  int g = tid >> 6; int lane = tid & 63;
  int start = off[i]; int deg = off[i + 1] - start;
  float inv = 1.0f / den[i * 4 + g];
  float a0 = 0.f, a1 = 0.f, a2 = 0.f, a3 = 0.f;
  for (int e = 0; e < deg; ++e) {
    int edge = list[start + e];
    int s = (edge < NE) ? esrc[edge] : (edge - NE);
    float w = exw[(size_t)edge * 4 + g] * inv;
    const bf16* hr = hp + ((size_t)s * 4 + g) * 256;
    a0 += w * b2f(hr[lane]);       a1 += w * b2f(hr[64 + lane]);
    a2 += w * b2f(hr[128 + lane]); a3 += w * b2f(hr[192 + lane]);
  }
  msg[g][lane] = a0; msg[g][64 + lane] = a1; msg[g][128 + lane] = a2; msg[g][192 + lane] = a3;
  __syncthreads();
  int c = tid;
  float out = 0.25f * (msg[0][c] + msg[1][c] + msg[2][c] + msg[3][c]) + b2f(bias[c]);
  float mean = block_sum_256(out, red) * (1.0f / 256.0f);
  float d = out - mean;
  float var = block_sum_256(d * d, red) * (1.0f / 256.0f);
  float y = d * rsqrtf(var + 1e-5f) * b2f(gg[c]) + b2f(gb[c]);
  h[(size_t)i * 256 + c] += gelu_f(y);
}

// ---------------------------------------------------------------------------
// LayerNorm: f32 in, bf16 out
// ---------------------------------------------------------------------------
__global__ __launch_bounds__(256) void ln_kernel(
    const float* __restrict__ x, bf16* __restrict__ y,
    const bf16* __restrict__ g, const bf16* __restrict__ b)
{
  __shared__ float red[4];
  int row = blockIdx.x; int c = threadIdx.x;
  float v = x[(size_t)row * 256 + c];
  float mean = block_sum_256(v, red) * (1.0f / 256.0f);
  float d = v - mean;
  float var = block_sum_256(d * d, red) * (1.0f / 256.0f);
  y[(size_t)row * 256 + c] = f2b(d * rsqrtf(var + 1e-5f) * b2f(g[c]) + b2f(b[c]));
}

// ---------------------------------------------------------------------------
// Transformer attention (qkv, obuf bf16). Sequence = 256 graphs; block=(node,head).
// ---------------------------------------------------------------------------
__global__ __launch_bounds__(256) void attn_kernel(
    const bf16* __restrict__ qkv, bf16* __restrict__ obuf)
{
  const int b  = blockIdx.x & 63;
  const int hh = blockIdx.x >> 6;
  __shared__ bf16 Ks[32][256];   // [d][t]
  __shared__ bf16 Vs[256][32];   // [t][d]
  __shared__ float qv[32];
  __shared__ float ps[256];
  __shared__ float part[8][32];
  __shared__ float red[8];
  const int tid = threadIdx.x;
  for (int idx = tid; idx < 256 * 32; idx += 256) {
    int t = idx >> 5, d = idx & 31;
    size_t rowbase = (size_t)(t * 64 + b) * 768;
    Ks[d][t] = qkv[rowbase + 256 + hh * 32 + d];
    Vs[t][d] = qkv[rowbase + 512 + hh * 32 + d];
  }
  __syncthreads();
  const float scale = 0.17677669529663687f;  // 1/sqrt(32)
  for (int s = 0; s < 256; ++s) {
    if (tid < 32) qv[tid] = b2f(qkv[(size_t)(s * 64 + b) * 768 + hh * 32 + tid]);
    __syncthreads();
    float sc = 0.f;
    #pragma unroll
    for (int d = 0; d < 32; ++d) sc += qv[d] * b2f(Ks[d][tid]);
    sc *= scale;
    float m = wave_max(sc);
    if ((tid & 63) == 0) red[tid >> 6] = m;
    __syncthreads();
    m = fmaxf(fmaxf(red[0], red[1]), fmaxf(red[2], red[3]));
    float p = expf(sc - m);
    float sum = wave_sum(p);
    if ((tid & 63) == 0) red[4 + (tid >> 6)] = sum;
    __syncthreads();
    float inv = 1.0f / (red[4] + red[5] + red[6] + red[7]);
    ps[tid] = p * inv;
    __syncthreads();
    int d = tid & 31, ch = tid >> 5;
    float acc = 0.f;
    #pragma unroll
    for (int j = 0; j < 32; ++j) { int t = (ch << 5) + j; acc += ps[t] * b2f(Vs[t][d]); }
    part[ch][d] = acc;
    __syncthreads();
    if (tid < 32) {
      float o = 0.f;
      #pragma unroll
      for (int c2 = 0; c2 < 8; ++c2) o += part[c2][tid];
      obuf[(size_t)(s * 64 + b) * 256 + hh * 32 + tid] = f2b(o);
    }
    __syncthreads();
  }
}

// ---------------------------------------------------------------------------
// Pooling + heads (outputs staged as bf16)
// ---------------------------------------------------------------------------
__global__ __launch_bounds__(256) void pool_logit(
    const float* __restrict__ h, const bf16* __restrict__ pw, const bf16* __restrict__ pb,
    float* __restrict__ logits)
{
  int n = blockIdx.x * 4 + (threadIdx.x >> 6); int lane = threadIdx.x & 63;
  float acc = 0.f;
  #pragma unroll
  for (int j = 0; j < 4; ++j) {
    int c = j * 64 + lane;
    acc += h[(size_t)n * 256 + c] * b2f(pw[c]);
  }
  acc = wave_sum(acc);
  if (lane == 0) logits[n] = acc + b2f(pb[0]);
}
__global__ __launch_bounds__(1024) void pool_reduce(
    const float* __restrict__ logits, float* __restrict__ red)
{
  __shared__ float sm[16];
  int t = threadIdx.x;
  float m = -1e30f;
  for (int i = t; i < N_NODES; i += 1024) m = fmaxf(m, logits[i]);
  m = wave_max(m);
  if ((t & 63) == 0) sm[t >> 6] = m;
  __syncthreads();
  if (t == 0) { float mm = sm[0]; for (int i = 1; i < 16; ++i) mm = fmaxf(mm, sm[i]); sm[0] = mm; }
  __syncthreads();
  float gmax = sm[0];
  __syncthreads();
  float s = 0.f;
  for (int i = t; i < N_NODES; i += 1024) s += expf(logits[i] - gmax);
  s = wave_sum(s);
  if ((t & 63) == 0) sm[t >> 6] = s;
  __syncthreads();
  if (t == 0) { float ss = 0.f; for (int i = 0; i < 16; ++i) ss += sm[i]; red[0] = gmax; red[1] = 1.0f / ss; }
}
__global__ __launch_bounds__(256) void pool_grep(
    const float* __restrict__ h, const float* __restrict__ logits,
    const float* __restrict__ red, float* __restrict__ g_rep)
{
  __shared__ float w[64];
  int g = blockIdx.x; int tid = threadIdx.x;
  if (tid < 64) w[tid] = expf(logits[g * 64 + tid] - red[0]) * red[1];
  __syncthreads();
  float acc = 0.f;
  for (int nd = 0; nd < 64; ++nd) acc += h[((size_t)g * 64 + nd) * 256 + tid] * w[nd];
  g_rep[(size_t)g * 256 + tid] = acc;
}
__global__ __launch_bounds__(256) void head_value(
    const float* __restrict__ vt, const bf16* __restrict__ w2, const bf16* __restrict__ b2,
    bf16* __restrict__ out)
{
  int gidx = blockIdx.x * 4 + (threadIdx.x >> 6); int lane = threadIdx.x & 63;
  float acc = 0.f;
  #pragma unroll
  for (int j = 0; j < 4; ++j) { int c = j * 64 + lane; acc += vt[(size_t)gidx * 256 + c] * b2f(w2[c]); }
  acc = wave_sum(acc);
  if (lane == 0) out[gidx] = f2b(tanhf(acc + b2f(b2[0])));
}
__global__ __launch_bounds__(256) void head_unc(
    const float* __restrict__ ut, const bf16* __restrict__ w2, const bf16* __restrict__ b2,
    bf16* __restrict__ out)
{
  int gidx = blockIdx.x * 4 + (threadIdx.x >> 6); int lane = threadIdx.x & 63;
  float acc = 0.f;
  #pragma unroll
  for (int j = 0; j < 2; ++j) { int c = j * 64 + lane; acc += ut[(size_t)gidx * 128 + c] * b2f(w2[c]); }
  acc = wave_sum(acc);
  if (lane == 0) {
    float x = acc + b2f(b2[0]);
    float sp = (x > 20.f) ? x : log1pf(expf(x));
    out[gidx] = f2b(sp);
  }
}

// ---------------------------------------------------------------------------
extern "C" void kernel_launch(void* const* d_in, const int* in_sizes, int n_in,
                              void* d_out, int out_size, void* d_ws, size_t ws_size,
                              hipStream_t stream)
{
  (void)out_size;
  const int* eidx = (const int*)d_in[1];

  char* ws = (char*)d_ws;
  size_t wo = 0;
  auto alloc = [&](size_t bytes) -> char* {
    char* p = ws + wo; wo += (bytes + 255) & ~(size_t)255; return p;
  };
  int*   flags = (int*)alloc(256);
  // normalized bf16 copies of the 35 float tensors (dict indices 0, 4..37)
  bf16* conv[38] = {};
  {
    static const int fidx[35] = {0,4,5,6,7,8,9,10,11,12,13,14,15,16,17,18,19,
                                 20,21,22,23,24,25,26,27,28,29,30,31,32,33,34,35,36,37};
    for (int j = 0; j < 35; ++j) {
      int idx = fidx[j];
      conv[idx] = (bf16*)alloc((size_t)in_sizes[idx] * 2);
    }
  }
  float* h     = (float*)alloc((size_t)N_NODES * 256 * 4);   // 16 MB (f32 residual stream)
  bf16*  big   = (bf16*) alloc((size_t)N_NODES * 1024 * 2);  // 32 MB (hp / qkv+obuf / ffb)
  bf16*  tn    = (bf16*) alloc((size_t)N_NODES * 256 * 2);   // 8 MB
  float* al_s  = (float*)alloc((size_t)N_NODES * 4 * 4);
  float* al_d  = (float*)alloc((size_t)N_NODES * 4 * 4);
  float* exw   = (float*)alloc((size_t)NE2 * 4 * 4);
  float* den   = (float*)alloc((size_t)N_NODES * 4 * 4);
  int*   cnt   = (int*)alloc((size_t)N_NODES * 4);
  int*   fillc = (int*)alloc((size_t)N_NODES * 4);
  int*   off   = (int*)alloc((size_t)(N_NODES + 1) * 4);
  int*   list  = (int*)alloc((size_t)NE2 * 4);
  float* logits= (float*)alloc((size_t)N_NODES * 4);
  float* redb  = (float*)alloc(256);
  float* g_rep = (float*)alloc((size_t)256 * 256 * 4);
  float* val_t = (float*)alloc((size_t)256 * 256 * 4);
  float* unc_t = (float*)alloc((size_t)256 * 128 * 4);
  const int OUT_ELEMS = 256 + N_NODES * 256 + 256;
  bf16*  ostage = (bf16*)alloc((size_t)OUT_ELEMS * 2);
  size_t needed = wo;

  // guards (finite sentinel codes)
  if (n_in != 38)                   { write_sentinel<<<1,256,0,stream>>>((bf16*)d_out, 4.f);  return; }
  if (in_sizes[0] != N_NODES * 128) { write_sentinel<<<1,256,0,stream>>>((bf16*)d_out, 8.f);  return; }
  if (in_sizes[1] != 2 * NE)        { write_sentinel<<<1,256,0,stream>>>((bf16*)d_out, 16.f); return; }
  if (ws_size < needed)             { write_sentinel<<<1,256,0,stream>>>((bf16*)d_out, 32.f); return; }

  hipMemsetAsync(d_ws, 0, needed, stream);

  // dtype detect on x, then normalize every float tensor to bf16
  detect_dtype<<<256, 256, 0, stream>>>((const unsigned short*)d_in[0], 65536, flags);
  {
    static const int fidx[35] = {0,4,5,6,7,8,9,10,11,12,13,14,15,16,17,18,19,
                                 20,21,22,23,24,25,26,27,28,29,30,31,32,33,34,35,36,37};
    for (int j = 0; j < 35; ++j) {
      int idx = fidx[j]; int n = in_sizes[idx];
      conv_in<<<(n + 255) / 256, 256, 0, stream>>>(d_in[idx], (unsigned short*)conv[idx], n, flags);
    }
  }
  const bf16 *xb = conv[0], *emb_w = conv[4], *emb_b = conv[5], *gat_w = conv[6],
             *gat_as = conv[7], *gat_ad = conv[8], *gat_b = conv[9], *gnn_g = conv[10],
             *gnn_beta = conv[11], *ln1_g = conv[12], *ln1_b = conv[13], *in_w = conv[14],
             *in_b = conv[15], *out_w = conv[16], *out_b = conv[17], *ln2_g = conv[18],
             *ln2_b = conv[19], *ff1_w = conv[20], *ff1_b = conv[21], *ff2_w = conv[22],
             *ff2_b = conv[23], *pool_w = conv[24], *pool_b = conv[25],
             *vw1 = conv[26], *vb1 = conv[27], *vw2 = conv[28], *vb2 = conv[29],
             *pw1 = conv[30], *pb1 = conv[31], *pw2 = conv[32], *pb2 = conv[33],
             *uw1 = conv[34], *ub1 = conv[35], *uw2 = conv[36], *ub2 = conv[37];

  bf16* qkv  = big;                          // N x 768
  bf16* obuf = big + (size_t)N_NODES * 768;  // N x 256
  bf16* hp   = big;                          // N x 1024
  bf16* ffb  = big;                          // N x 1024
  bf16* o_val = ostage;
  bf16* o_pol = ostage + 256;
  bf16* o_unc = ostage + 256 + (size_t)N_NODES * 256;

  // CSR (cnt/fillc zeroed by memset)
  csr_count<<<(NE2 + 255) / 256, 256, 0, stream>>>(eidx + NE, cnt);
  csr_scan<<<1, 1024, 0, stream>>>(cnt, off);
  csr_fill<<<(NE2 + 255) / 256, 256, 0, stream>>>(eidx + NE, off, fillc, list);

  // Embedding
  gemm_nt<bf16, float, 0><<<dim3(4, 256), 256, 0, stream>>>(
      xb, emb_w, emb_b, nullptr, h, N_NODES, 256, 128);
  scrub<<<(N_NODES * 256 + 255) / 256, 256, 0, stream>>>(h, N_NODES * 256, flags, 0);

  // GNN layers
  for (int l = 0; l < 8; ++l) {
    gemm_nt<float, bf16, 0><<<dim3(16, 256), 256, 0, stream>>>(
        h, gat_w + (size_t)l * 1024 * 256, nullptr, nullptr, hp, N_NODES, 1024, 256);
    gat_alsd<<<N_NODES, 256, 0, stream>>>(hp, gat_as + l * 1024, gat_ad + l * 1024, al_s, al_d);
    gat_edge<<<N_NODES, 256, 0, stream>>>(eidx, al_s, al_d, off, list, exw, den);
    gat_agg<<<N_NODES, 256, 0, stream>>>(eidx, hp, exw, den, off, list,
        gat_b + l * 256, gnn_g + l * 256, gnn_beta + l * 256, h);
  }
  scrub<<<(N_NODES * 256 + 255) / 256, 256, 0, stream>>>(h, N_NODES * 256, flags, 1);

  // Transformer layers
  for (int l = 0; l < 6; ++l) {
    ln_kernel<<<N_NODES, 256, 0, stream>>>(h, tn, ln1_g + l * 256, ln1_b + l * 256);
    gemm_nt<bf16, bf16, 0><<<dim3(12, 256), 256, 0, stream>>>(
        tn, in_w + (size_t)l * 768 * 256, in_b + l * 768, nullptr, qkv, N_NODES, 768, 256);
    attn_kernel<<<512, 256, 0, stream>>>(qkv, obuf);
    gemm_nt<bf16, float, 2><<<dim3(4, 256), 256, 0, stream>>>(
        obuf, out_w + (size_t)l * 256 * 256, out_b + l * 256, h, h, N_NODES, 256, 256);
    ln_kernel<<<N_NODES, 256, 0, stream>>>(h, tn, ln2_g + l * 256, ln2_b + l * 256);
    gemm_nt<bf16, bf16, 1><<<dim3(16, 256), 256, 0, stream>>>(
        tn, ff1_w + (size_t)l * 1024 * 256, ff1_b + l * 1024, nullptr, ffb, N_NODES, 1024, 256);
    gemm_nt<bf16, float, 2><<<dim3(4, 256), 256, 0, stream>>>(
        ffb, ff2_w + (size_t)l * 256 * 1024, ff2_b + l * 256, h, h, N_NODES, 256, 1024);
  }
  scrub<<<(N_NODES * 256 + 255) / 256, 256, 0, stream>>>(h, N_NODES * 256, flags, 2);

  // Pooling + heads
  pool_logit<<<N_NODES / 4, 256, 0, stream>>>(h, pool_w, pool_b, logits);
  pool_reduce<<<1, 1024, 0, stream>>>(logits, redb);
  pool_grep<<<256, 256, 0, stream>>>(h, logits, redb, g_rep);
  gemm_nt<float, float, 1><<<dim3(4, 4), 256, 0, stream>>>(
      g_rep, vw1, vb1, nullptr, val_t, 256, 256, 256);
  head_value<<<64, 256, 0, stream>>>(val_t, vw2, vb2, o_val);
  gemm_nt<float, float, 1><<<dim3(2, 4), 256, 0, stream>>>(
      g_rep, uw1, ub1, nullptr, unc_t, 256, 128, 256);
  head_unc<<<64, 256, 0, stream>>>(unc_t, uw2, ub2, o_unc);
  gemm_nt<float, bf16, 1><<<dim3(4, 256), 256, 0, stream>>>(
      h, pw1, pb1, nullptr, tn, N_NODES, 256, 256);
  gemm_nt<bf16, bf16, 0><<<dim3(4, 256), 256, 0, stream>>>(
      tn, pw2, pb2, nullptr, o_pol, N_NODES, 256, 256);

  // emit in detected dtype, then (on NaN) overwrite value region with phase code
  emit_out<<<(OUT_ELEMS + 255) / 256, 256, 0, stream>>>(
      (const unsigned short*)ostage, d_out, OUT_ELEMS, flags);
  flag_report<<<1, 64, 0, stream>>>(flags, d_out);
}

// Round 5
// 4689.121 us; speedup vs baseline: 1.6479x; 1.6479x over previous
//
#include <hip/hip_runtime.h>
#include <hip/hip_bf16.h>

typedef __hip_bfloat16 bf16;

#define N_NODES 16384
#define HDIM    256
#define NE      131072
#define NE2     147456   // NE + N self loops

__device__ __forceinline__ float b2f(bf16 v){ return __bfloat162float(v); }
__device__ __forceinline__ bf16  f2b(float v){ return __float2bfloat16(v); }
__device__ __forceinline__ float us2f(unsigned short u){
  union { unsigned int i; float f; } c; c.i = ((unsigned int)u) << 16; return c.f;
}
__device__ __forceinline__ unsigned short f2us(float f){
  bf16 h = __float2bfloat16(f);
  unsigned short u; __builtin_memcpy(&u, &h, 2); return u;
}
__device__ __forceinline__ float gelu_f(float x){
  return 0.5f * x * (1.0f + erff(x * 0.7071067811865476f));
}
__device__ __forceinline__ float wave_sum(float v){
  #pragma unroll
  for (int o = 32; o > 0; o >>= 1) v += __shfl_xor(v, o);
  return v;
}
__device__ __forceinline__ float wave_max(float v){
  #pragma unroll
  for (int o = 32; o > 0; o >>= 1) v = fmaxf(v, __shfl_xor(v, o));
  return v;
}
__device__ __forceinline__ float block_sum_256(float v, float* red){
  v = wave_sum(v);
  __syncthreads();
  if ((threadIdx.x & 63) == 0) red[threadIdx.x >> 6] = v;
  __syncthreads();
  return red[0] + red[1] + red[2] + red[3];
}

__device__ __forceinline__ float4 load4(const float* p){ return *(const float4*)p; }
__device__ __forceinline__ float4 load4(const bf16* p){
  ushort4 u = *(const ushort4*)p;
  return make_float4(us2f(u.x), us2f(u.y), us2f(u.z), us2f(u.w));
}
__device__ __forceinline__ void store4(float* p, float4 v){ *(float4*)p = v; }
__device__ __forceinline__ void store4(bf16* p, float4 v){
  ushort4 u = make_ushort4(f2us(v.x), f2us(v.y), f2us(v.z), f2us(v.w));
  *(ushort4*)p = u;
}

// ---------------------------------------------------------------------------
// dtype detection + normalization.  flags[1] = input-is-f32
// ---------------------------------------------------------------------------
__global__ void detect_dtype(const unsigned short* __restrict__ x, int n, int* __restrict__ flags){
  int i = blockIdx.x * 256 + threadIdx.x;
  if (i < n) {
    unsigned short u = x[i];
    if ((u & 0x7F80) == 0x7F80) atomicOr(&flags[1], 1);  // bf16 NaN/Inf pattern
  }
}
__global__ void conv_in(const void* __restrict__ src, unsigned short* __restrict__ dst,
                        int n, const int* __restrict__ flags){
  int i = blockIdx.x * 256 + threadIdx.x;
  if (i >= n) return;
  if (flags[1]) dst[i] = f2us(((const float*)src)[i]);
  else          dst[i] = ((const unsigned short*)src)[i];
}
__global__ void emit_out(const unsigned short* __restrict__ stage, void* __restrict__ out,
                         int n, const int* __restrict__ flags){
  int i = blockIdx.x * 256 + threadIdx.x;
  if (i >= n) return;
  if (flags[1]) ((float*)out)[i] = us2f(stage[i]);
  else          ((unsigned short*)out)[i] = stage[i];
}
__global__ void write_sentinel(bf16* out, float v){ out[threadIdx.x] = f2b(v); }

// ---------------------------------------------------------------------------
// Generic NT GEMM: C[M,Nn] = A[M,K] * W[Nn,K]^T (+bias) (+epilogue)
// EPI: 0 = bias only, 1 = gelu, 2 = residual add. M%64==0, Nn%64==0, K%32==0.
// ---------------------------------------------------------------------------
template<typename TA, typename TO, int EPI>
__global__ __launch_bounds__(256) void gemm_nt(
    const TA* __restrict__ A, const bf16* __restrict__ W,
    const bf16* __restrict__ bias, const float* __restrict__ res,
    TO* __restrict__ C, int M, int Nn, int K)
{
  __shared__ float As[32][68];
  __shared__ float Bs[32][68];
  const int tid = threadIdx.x;
  const int tx = tid & 15, ty = tid >> 4;
  const int row0 = blockIdx.y << 6, col0 = blockIdx.x << 6;
  float acc[4][4] = {};
  for (int kt = 0; kt < K; kt += 32) {
    #pragma unroll
    for (int it = 0; it < 2; ++it) {
      int s  = tid + it * 256;
      int r  = s >> 3;          // 0..63
      int kk = (s & 7) << 2;    // 0,4,...,28
      float4 av = load4(A + (size_t)(row0 + r) * K + kt + kk);
      As[kk+0][r] = av.x; As[kk+1][r] = av.y; As[kk+2][r] = av.z; As[kk+3][r] = av.w;
      float4 bv = load4(W + (size_t)(col0 + r) * K + kt + kk);
      Bs[kk+0][r] = bv.x; Bs[kk+1][r] = bv.y; Bs[kk+2][r] = bv.z; Bs[kk+3][r] = bv.w;
    }
    __syncthreads();
    #pragma unroll
    for (int kk = 0; kk < 32; ++kk) {
      float4 a = *(const float4*)&As[kk][ty << 2];
      float4 b = *(const float4*)&Bs[kk][tx << 2];
      acc[0][0] += a.x*b.x; acc[0][1] += a.x*b.y; acc[0][2] += a.x*b.z; acc[0][3] += a.x*b.w;
      acc[1][0] += a.y*b.x; acc[1][1] += a.y*b.y; acc[1][2] += a.y*b.z; acc[1][3] += a.y*b.w;
      acc[2][0] += a.z*b.x; acc[2][1] += a.z*b.y; acc[2][2] += a.z*b.z; acc[2][3] += a.z*b.w;
      acc[3][0] += a.w*b.x; acc[3][1] += a.w*b.y; acc[3][2] += a.w*b.z; acc[3][3] += a.w*b.w;
    }
    __syncthreads();
  }
  const int c0 = col0 + (tx << 2);
  #pragma unroll
  for (int i = 0; i < 4; ++i) {
    int r = row0 + (ty << 2) + i;
    size_t base = (size_t)r * Nn + c0;
    float v0 = acc[i][0], v1 = acc[i][1], v2 = acc[i][2], v3 = acc[i][3];
    if (bias) {
      v0 += b2f(bias[c0+0]); v1 += b2f(bias[c0+1]);
      v2 += b2f(bias[c0+2]); v3 += b2f(bias[c0+3]);
    }
    if (EPI == 1) { v0 = gelu_f(v0); v1 = gelu_f(v1); v2 = gelu_f(v2); v3 = gelu_f(v3); }
    if (EPI == 2) {
      float4 rv = *(const float4*)(res + base);
      v0 += rv.x; v1 += rv.y; v2 += rv.z; v3 += rv.w;
    }
    store4(C + base, make_float4(v0, v1, v2, v3));
  }
}

// ---------------------------------------------------------------------------
// CSR build over dst
// ---------------------------------------------------------------------------
__global__ void csr_count(const int* __restrict__ edst, int* __restrict__ cnt){
  int e = blockIdx.x * 256 + threadIdx.x;
  if (e < NE2) {
    int d = (e < NE) ? edst[e] : (e - NE);
    atomicAdd(&cnt[d], 1);
  }
}
__global__ __launch_bounds__(1024) void csr_scan(const int* __restrict__ cnt, int* __restrict__ off){
  __shared__ int ls[1024];
  int t = threadIdx.x;
  int base = t * 16;
  int loc[16]; int s = 0;
  #pragma unroll
  for (int j = 0; j < 16; ++j) { loc[j] = s; s += cnt[base + j]; }
  ls[t] = s;
  __syncthreads();
  for (int o = 1; o < 1024; o <<= 1) {
    int v = (t >= o) ? ls[t - o] : 0;
    __syncthreads();
    ls[t] += v;
    __syncthreads();
  }
  int pre = (t == 0) ? 0 : ls[t - 1];
  #pragma unroll
  for (int j = 0; j < 16; ++j) off[base + j] = pre + loc[j];
  if (t == 1023) off[N_NODES] = ls[1023];
}
__global__ void csr_fill(const int* __restrict__ edst, const int* __restrict__ off,
                         int* __restrict__ fillc, int* __restrict__ list){
  int e = blockIdx.x * 256 + threadIdx.x;
  if (e < NE2) {
    int d = (e < NE) ? edst[e] : (e - NE);
    int p = atomicAdd(&fillc[d], 1);
    list[off[d] + p] = e;
  }
}

// ---------------------------------------------------------------------------
// GAT: per-(node,head) logits. 4 nodes/block, wave=node, 16-lane group=head.
// ---------------------------------------------------------------------------
__global__ __launch_bounds__(256) void gat_alsd(
    const bf16* __restrict__ hp, const bf16* __restrict__ a_s, const bf16* __restrict__ a_d,
    float* __restrict__ al_s, float* __restrict__ al_d)
{
  int i = blockIdx.x * 4 + (threadIdx.x >> 6);
  int lane = threadIdx.x & 63;
  int head = lane >> 4, sub = lane & 15;
  const bf16* hr  = hp  + ((size_t)i * 4 + head) * 256 + sub * 16;
  const bf16* asp = a_s + head * 256 + sub * 16;
  const bf16* adp = a_d + head * 256 + sub * 16;
  float s1 = 0.f, s2 = 0.f;
  #pragma unroll
  for (int j = 0; j < 16; j += 4) {
    float4 hv = load4(hr + j); float4 av = load4(asp + j); float4 dv = load4(adp + j);
    s1 += hv.x*av.x + hv.y*av.y + hv.z*av.z + hv.w*av.w;
    s2 += hv.x*dv.x + hv.y*dv.y + hv.z*dv.z + hv.w*dv.w;
  }
  #pragma unroll
  for (int o = 8; o > 0; o >>= 1) { s1 += __shfl_xor(s1, o); s2 += __shfl_xor(s2, o); }
  if (sub == 0) { al_s[i * 4 + head] = s1; al_d[i * 4 + head] = s2; }
}

// ---------------------------------------------------------------------------
// Fused GAT softmax + aggregation + head-mean + bias + LN + GELU + residual.
// block=node (256 thr = 4 heads x 64 lanes); channels c = 4*lane+j per head.
// ---------------------------------------------------------------------------
__global__ __launch_bounds__(256) void gat_fused(
    const int* __restrict__ esrc, const bf16* __restrict__ hp,
    const float* __restrict__ al_s, const float* __restrict__ al_d,
    const int* __restrict__ off, const int* __restrict__ list,
    const bf16* __restrict__ bias, const bf16* __restrict__ gg, const bf16* __restrict__ gb,
    float* __restrict__ h)
{
  __shared__ float msg[4][256];
  __shared__ float red[4];
  int i = blockIdx.x; int tid = threadIdx.x;
  int g = tid >> 6; int lane = tid & 63;
  int start = off[i]; int deg = off[i + 1] - start;
  float ad = al_d[i * 4 + g];
  // pass 1: per-head max over incoming edges (lanes parallel over edges)
  float mx = -1e30f;
  for (int e = lane; e < deg; e += 64) {
    int edge = list[start + e];
    int s = (edge < NE) ? esrc[edge] : (edge - NE);
    float v = al_s[s * 4 + g] + ad;
    v = (v > 0.f) ? v : 0.2f * v;
    mx = fmaxf(mx, v);
  }
  mx = wave_max(mx);
  // pass 2: serial edges; exp-weight + aggregate (one ushort4 load per lane)
  float a0 = 0.f, a1 = 0.f, a2 = 0.f, a3 = 0.f, den = 0.f;
  for (int e = 0; e < deg; ++e) {
    int edge = list[start + e];
    int s = (edge < NE) ? esrc[edge] : (edge - NE);
    float v = al_s[s * 4 + g] + ad;
    v = (v > 0.f) ? v : 0.2f * v;
    float w = __expf(v - mx);
    den += w;
    float4 hv = load4(hp + ((size_t)s * 4 + g) * 256 + lane * 4);
    a0 += w * hv.x; a1 += w * hv.y; a2 += w * hv.z; a3 += w * hv.w;
  }
  float inv = 1.0f / den;
  msg[g][lane * 4 + 0] = a0 * inv; msg[g][lane * 4 + 1] = a1 * inv;
  msg[g][lane * 4 + 2] = a2 * inv; msg[g][lane * 4 + 3] = a3 * inv;
  __syncthreads();
  int c = tid;
  float out = 0.25f * (msg[0][c] + msg[1][c] + msg[2][c] + msg[3][c]) + b2f(bias[c]);
  float mean = block_sum_256(out, red) * (1.0f / 256.0f);
  float d = out - mean;
  float var = block_sum_256(d * d, red) * (1.0f / 256.0f);
  float y = d * rsqrtf(var + 1e-5f) * b2f(gg[c]) + b2f(gb[c]);
  h[(size_t)i * 256 + c] += gelu_f(y);
}

// ---------------------------------------------------------------------------
// LayerNorm: wave-per-row (4 rows/block), f32 in, bf16 out
// ---------------------------------------------------------------------------
__global__ __launch_bounds__(256) void ln_kernel(
    const float* __restrict__ x, bf16* __restrict__ y,
    const bf16* __restrict__ g, const bf16* __restrict__ b)
{
  int row = blockIdx.x * 4 + (threadIdx.x >> 6);
  int lane = threadIdx.x & 63;
  int c = lane * 4;
  float4 v = load4(x + (size_t)row * 256 + c);
  float mean = wave_sum(v.x + v.y + v.z + v.w) * (1.0f / 256.0f);
  float dx = v.x - mean, dy = v.y - mean, dz = v.z - mean, dw = v.w - mean;
  float var = wave_sum(dx*dx + dy*dy + dz*dz + dw*dw) * (1.0f / 256.0f);
  float r = rsqrtf(var + 1e-5f);
  float4 gv = load4(g + c); float4 bv = load4(b + c);
  store4(y + (size_t)row * 256 + c,
         make_float4(dx*r*gv.x + bv.x, dy*r*gv.y + bv.y, dz*r*gv.z + bv.z, dw*r*gv.w + bv.w));
}

// ---------------------------------------------------------------------------
// Transformer attention: seq = 256 graphs, block = (node b, head hh).
// One query per thread; K/V staged f32 in LDS (64 KB, 2 blocks/CU).
// Max-free exp-sum softmax (scores are O(10); exact vs ref's shifted form).
// ---------------------------------------------------------------------------
__global__ __launch_bounds__(256) void attn_kernel(
    const bf16* __restrict__ qkv, bf16* __restrict__ obuf)
{
  const int b  = blockIdx.x & 63;
  const int hh = blockIdx.x >> 6;
  __shared__ float Ks[256][32];
  __shared__ float Vs[256][32];
  const int tid = threadIdx.x;
  for (int idx = tid; idx < 256 * 8; idx += 256) {
    int t = idx >> 3, d4 = (idx & 7) << 2;
    size_t rb = (size_t)(t * 64 + b) * 768 + hh * 32 + d4;
    float4 kv = load4(qkv + rb + 256);
    float4 vv = load4(qkv + rb + 512);
    Ks[t][d4] = kv.x; Ks[t][d4+1] = kv.y; Ks[t][d4+2] = kv.z; Ks[t][d4+3] = kv.w;
    Vs[t][d4] = vv.x; Vs[t][d4+1] = vv.y; Vs[t][d4+2] = vv.z; Vs[t][d4+3] = vv.w;
  }
  float q[32];
  {
    const bf16* qp = qkv + (size_t)(tid * 64 + b) * 768 + hh * 32;
    #pragma unroll
    for (int d = 0; d < 32; d += 4) {
      float4 v = load4(qp + d);
      q[d] = v.x; q[d+1] = v.y; q[d+2] = v.z; q[d+3] = v.w;
    }
  }
  __syncthreads();
  const float scale = 0.17677669529663687f;  // 1/sqrt(32)
  float acc[32] = {}; float l = 0.f;
  for (int k = 0; k < 256; ++k) {
    float sc = 0.f;
    #pragma unroll
    for (int d = 0; d < 32; ++d) sc += q[d] * Ks[k][d];
    sc = fminf(fmaxf(sc * scale, -60.f), 60.f);
    float e = __expf(sc);
    l += e;
    #pragma unroll
    for (int d = 0; d < 32; ++d) acc[d] += e * Vs[k][d];
  }
  float inv = 1.0f / l;
  bf16* op = obuf + (size_t)(tid * 64 + b) * 256 + hh * 32;
  #pragma unroll
  for (int d = 0; d < 32; d += 4)
    store4(op + d, make_float4(acc[d]*inv, acc[d+1]*inv, acc[d+2]*inv, acc[d+3]*inv));
}

// ---------------------------------------------------------------------------
// Pooling + heads
// ---------------------------------------------------------------------------
__global__ __launch_bounds__(256) void pool_logit(
    const float* __restrict__ h, const bf16* __restrict__ pw, const bf16* __restrict__ pb,
    float* __restrict__ logits)
{
  int n = blockIdx.x * 4 + (threadIdx.x >> 6); int lane = threadIdx.x & 63;
  float4 hv = load4(h + (size_t)n * 256 + lane * 4);
  float4 wv = load4(pw + lane * 4);
  float acc = wave_sum(hv.x*wv.x + hv.y*wv.y + hv.z*wv.z + hv.w*wv.w);
  if (lane == 0) logits[n] = acc + b2f(pb[0]);
}
__global__ __launch_bounds__(1024) void pool_reduce(
    const float* __restrict__ logits, float* __restrict__ red)
{
  __shared__ float sm[16];
  int t = threadIdx.x;
  float m = -1e30f;
  for (int i = t; i < N_NODES; i += 1024) m = fmaxf(m, logits[i]);
  m = wave_max(m);
  if ((t & 63) == 0) sm[t >> 6] = m;
  __syncthreads();
  if (t == 0) { float mm = sm[0]; for (int i = 1; i < 16; ++i) mm = fmaxf(mm, sm[i]); sm[0] = mm; }
  __syncthreads();
  float gmax = sm[0];
  __syncthreads();
  float s = 0.f;
  for (int i = t; i < N_NODES; i += 1024) s += expf(logits[i] - gmax);
  s = wave_sum(s);
  if ((t & 63) == 0) sm[t >> 6] = s;
  __syncthreads();
  if (t == 0) { float ss = 0.f; for (int i = 0; i < 16; ++i) ss += sm[i]; red[0] = gmax; red[1] = 1.0f / ss; }
}
__global__ __launch_bounds__(256) void pool_grep(
    const float* __restrict__ h, const float* __restrict__ logits,
    const float* __restrict__ red, float* __restrict__ g_rep)
{
  __shared__ float w[64];
  int g = blockIdx.x; int tid = threadIdx.x;
  if (tid < 64) w[tid] = expf(logits[g * 64 + tid] - red[0]) * red[1];
  __syncthreads();
  float acc = 0.f;
  for (int nd = 0; nd < 64; ++nd) acc += h[((size_t)g * 64 + nd) * 256 + tid] * w[nd];
  g_rep[(size_t)g * 256 + tid] = acc;
}
__global__ __launch_bounds__(256) void head_value(
    const float* __restrict__ vt, const bf16* __restrict__ w2, const bf16* __restrict__ b2,
    bf16* __restrict__ out)
{
  int gidx = blockIdx.x * 4 + (threadIdx.x >> 6); int lane = threadIdx.x & 63;
  float acc = 0.f;
  #pragma unroll
  for (int j = 0; j < 4; ++j) { int c = j * 64 + lane; acc += vt[(size_t)gidx * 256 + c] * b2f(w2[c]); }
  acc = wave_sum(acc);
  if (lane == 0) out[gidx] = f2b(tanhf(acc + b2f(b2[0])));
}
__global__ __launch_bounds__(256) void head_unc(
    const float* __restrict__ ut, const bf16* __restrict__ w2, const bf16* __restrict__ b2,
    bf16* __restrict__ out)
{
  int gidx = blockIdx.x * 4 + (threadIdx.x >> 6); int lane = threadIdx.x & 63;
  float acc = 0.f;
  #pragma unroll
  for (int j = 0; j < 2; ++j) { int c = j * 64 + lane; acc += ut[(size_t)gidx * 128 + c] * b2f(w2[c]); }
  acc = wave_sum(acc);
  if (lane == 0) {
    float x = acc + b2f(b2[0]);
    float sp = (x > 20.f) ? x : log1pf(expf(x));
    out[gidx] = f2b(sp);
  }
}

// ---------------------------------------------------------------------------
extern "C" void kernel_launch(void* const* d_in, const int* in_sizes, int n_in,
                              void* d_out, int out_size, void* d_ws, size_t ws_size,
                              hipStream_t stream)
{
  (void)out_size;
  const int* eidx = (const int*)d_in[1];

  char* ws = (char*)d_ws;
  size_t wo = 0;
  auto alloc = [&](size_t bytes) -> char* {
    char* p = ws + wo; wo += (bytes + 255) & ~(size_t)255; return p;
  };
  // zero-required region first (single small memset)
  int*   flags = (int*)alloc(256);
  int*   cnt   = (int*)alloc((size_t)N_NODES * 4);
  int*   fillc = (int*)alloc((size_t)N_NODES * 4);
  size_t zero_end = wo;

  bf16* conv[38] = {};
  static const int fidx[35] = {0,4,5,6,7,8,9,10,11,12,13,14,15,16,17,18,19,
                               20,21,22,23,24,25,26,27,28,29,30,31,32,33,34,35,36,37};
  for (int j = 0; j < 35; ++j) {
    int idx = fidx[j];
    conv[idx] = (bf16*)alloc((size_t)in_sizes[idx] * 2);
  }
  float* h     = (float*)alloc((size_t)N_NODES * 256 * 4);   // 16 MB (f32 residual)
  bf16*  big   = (bf16*) alloc((size_t)N_NODES * 1024 * 2);  // 32 MB (hp / qkv+obuf / ffb)
  bf16*  tn    = (bf16*) alloc((size_t)N_NODES * 256 * 2);   // 8 MB
  float* al_s  = (float*)alloc((size_t)N_NODES * 4 * 4);
  float* al_d  = (float*)alloc((size_t)N_NODES * 4 * 4);
  int*   off   = (int*)alloc((size_t)(N_NODES + 1) * 4);
  int*   list  = (int*)alloc((size_t)NE2 * 4);
  float* logits= (float*)alloc((size_t)N_NODES * 4);
  float* redb  = (float*)alloc(256);
  float* g_rep = (float*)alloc((size_t)256 * 256 * 4);
  float* val_t = (float*)alloc((size_t)256 * 256 * 4);
  float* unc_t = (float*)alloc((size_t)256 * 128 * 4);
  const int OUT_ELEMS = 256 + N_NODES * 256 + 256;
  bf16*  ostage = (bf16*)alloc((size_t)OUT_ELEMS * 2);
  size_t needed = wo;

  if (n_in != 38)                   { write_sentinel<<<1,256,0,stream>>>((bf16*)d_out, 4.f);  return; }
  if (in_sizes[0] != N_NODES * 128) { write_sentinel<<<1,256,0,stream>>>((bf16*)d_out, 8.f);  return; }
  if (in_sizes[1] != 2 * NE)        { write_sentinel<<<1,256,0,stream>>>((bf16*)d_out, 16.f); return; }
  if (ws_size < needed)             { write_sentinel<<<1,256,0,stream>>>((bf16*)d_out, 32.f); return; }

  hipMemsetAsync(d_ws, 0, zero_end, stream);

  // dtype detect on x, then normalize every float tensor to bf16
  detect_dtype<<<256, 256, 0, stream>>>((const unsigned short*)d_in[0], 65536, flags);
  for (int j = 0; j < 35; ++j) {
    int idx = fidx[j]; int n = in_sizes[idx];
    conv_in<<<(n + 255) / 256, 256, 0, stream>>>(d_in[idx], (unsigned short*)conv[idx], n, flags);
  }
  const bf16 *xb = conv[0], *emb_w = conv[4], *emb_b = conv[5], *gat_w = conv[6],
             *gat_as = conv[7], *gat_ad = conv[8], *gat_b = conv[9], *gnn_g = conv[10],
             *gnn_beta = conv[11], *ln1_g = conv[12], *ln1_b = conv[13], *in_w = conv[14],
             *in_b = conv[15], *out_w = conv[16], *out_b = conv[17], *ln2_g = conv[18],
             *ln2_b = conv[19], *ff1_w = conv[20], *ff1_b = conv[21], *ff2_w = conv[22],
             *ff2_b = conv[23], *pool_w = conv[24], *pool_b = conv[25],
             *vw1 = conv[26], *vb1 = conv[27], *vw2 = conv[28], *vb2 = conv[29],
             *pw1 = conv[30], *pb1 = conv[31], *pw2 = conv[32], *pb2 = conv[33],
             *uw1 = conv[34], *ub1 = conv[35], *uw2 = conv[36], *ub2 = conv[37];

  bf16* qkv  = big;                          // N x 768
  bf16* obuf = big + (size_t)N_NODES * 768;  // N x 256
  bf16* hp   = big;                          // N x 1024
  bf16* ffb  = big;                          // N x 1024
  bf16* o_val = ostage;
  bf16* o_pol = ostage + 256;
  bf16* o_unc = ostage + 256 + (size_t)N_NODES * 256;

  // CSR (cnt/fillc zeroed by memset)
  csr_count<<<(NE2 + 255) / 256, 256, 0, stream>>>(eidx + NE, cnt);
  csr_scan<<<1, 1024, 0, stream>>>(cnt, off);
  csr_fill<<<(NE2 + 255) / 256, 256, 0, stream>>>(eidx + NE, off, fillc, list);

  // Embedding
  gemm_nt<bf16, float, 0><<<dim3(4, 256), 256, 0, stream>>>(
      xb, emb_w, emb_b, nullptr, h, N_NODES, 256, 128);

  // GNN layers
  for (int l = 0; l < 8; ++l) {
    gemm_nt<float, bf16, 0><<<dim3(16, 256), 256, 0, stream>>>(
        h, gat_w + (size_t)l * 1024 * 256, nullptr, nullptr, hp, N_NODES, 1024, 256);
    gat_alsd<<<N_NODES / 4, 256, 0, stream>>>(hp, gat_as + l * 1024, gat_ad + l * 1024, al_s, al_d);
    gat_fused<<<N_NODES, 256, 0, stream>>>(eidx, hp, al_s, al_d, off, list,
        gat_b + l * 256, gnn_g + l * 256, gnn_beta + l * 256, h);
  }

  // Transformer layers
  for (int l = 0; l < 6; ++l) {
    ln_kernel<<<N_NODES / 4, 256, 0, stream>>>(h, tn, ln1_g + l * 256, ln1_b + l * 256);
    gemm_nt<bf16, bf16, 0><<<dim3(12, 256), 256, 0, stream>>>(
        tn, in_w + (size_t)l * 768 * 256, in_b + l * 768, nullptr, qkv, N_NODES, 768, 256);
    attn_kernel<<<512, 256, 0, stream>>>(qkv, obuf);
    gemm_nt<bf16, float, 2><<<dim3(4, 256), 256, 0, stream>>>(
        obuf, out_w + (size_t)l * 256 * 256, out_b + l * 256, h, h, N_NODES, 256, 256);
    ln_kernel<<<N_NODES / 4, 256, 0, stream>>>(h, tn, ln2_g + l * 256, ln2_b + l * 256);
    gemm_nt<bf16, bf16, 1><<<dim3(16, 256), 256, 0, stream>>>(
        tn, ff1_w + (size_t)l * 1024 * 256, ff1_b + l * 1024, nullptr, ffb, N_NODES, 1024, 256);
    gemm_nt<bf16, float, 2><<<dim3(4, 256), 256, 0, stream>>>(
        ffb, ff2_w + (size_t)l * 256 * 1024, ff2_b + l * 256, h, h, N_NODES, 256, 1024);
  }

  // Pooling + heads
  pool_logit<<<N_NODES / 4, 256, 0, stream>>>(h, pool_w, pool_b, logits);
  pool_reduce<<<1, 1024, 0, stream>>>(logits, redb);
  pool_grep<<<256, 256, 0, stream>>>(h, logits, redb, g_rep);
  gemm_nt<float, float, 1><<<dim3(4, 4), 256, 0, stream>>>(
      g_rep, vw1, vb1, nullptr, val_t, 256, 256, 256);
  head_value<<<64, 256, 0, stream>>>(val_t, vw2, vb2, o_val);
  gemm_nt<float, float, 1><<<dim3(2, 4), 256, 0, stream>>>(
      g_rep, uw1, ub1, nullptr, unc_t, 256, 128, 256);
  head_unc<<<64, 256, 0, stream>>>(unc_t, uw2, ub2, o_unc);
  gemm_nt<float, bf16, 1><<<dim3(4, 256), 256, 0, stream>>>(
      h, pw1, pb1, nullptr, tn, N_NODES, 256, 256);
  gemm_nt<bf16, bf16, 0><<<dim3(4, 256), 256, 0, stream>>>(
      tn, pw2, pb2, nullptr, o_pol, N_NODES, 256, 256);

  emit_out<<<(OUT_ELEMS + 255) / 256, 256, 0, stream>>>(
      (const unsigned short*)ostage, d_out, OUT_ELEMS, flags);
}

// Round 6
// 2362.375 us; speedup vs baseline: 3.2709x; 1.9849x over previous
//
#include <hip/hip_runtime.h>
#include <hip/hip_bf16.h>

typedef __hip_bfloat16 bf16;
typedef __bf16 bf16x8 __attribute__((ext_vector_type(8)));
typedef float  f32x4  __attribute__((ext_vector_type(4)));

#define N_NODES 16384
#define HDIM    256
#define NE      131072
#define NE2     147456   // NE + N self loops

__device__ __forceinline__ float b2f(bf16 v){ return __bfloat162float(v); }
__device__ __forceinline__ bf16  f2b(float v){ return __float2bfloat16(v); }
__device__ __forceinline__ float us2f(unsigned short u){
  union { unsigned int i; float f; } c; c.i = ((unsigned int)u) << 16; return c.f;
}
__device__ __forceinline__ unsigned short f2us(float f){
  bf16 h = __float2bfloat16(f);
  unsigned short u; __builtin_memcpy(&u, &h, 2); return u;
}
__device__ __forceinline__ float gelu_f(float x){
  return 0.5f * x * (1.0f + erff(x * 0.7071067811865476f));
}
__device__ __forceinline__ float wave_sum(float v){
  #pragma unroll
  for (int o = 32; o > 0; o >>= 1) v += __shfl_xor(v, o);
  return v;
}
__device__ __forceinline__ float wave_max(float v){
  #pragma unroll
  for (int o = 32; o > 0; o >>= 1) v = fmaxf(v, __shfl_xor(v, o));
  return v;
}
__device__ __forceinline__ float block_sum_256(float v, float* red){
  v = wave_sum(v);
  __syncthreads();
  if ((threadIdx.x & 63) == 0) red[threadIdx.x >> 6] = v;
  __syncthreads();
  return red[0] + red[1] + red[2] + red[3];
}

__device__ __forceinline__ float4 load4(const float* p){ return *(const float4*)p; }
__device__ __forceinline__ float4 load4(const bf16* p){
  ushort4 u = *(const ushort4*)p;
  return make_float4(us2f(u.x), us2f(u.y), us2f(u.z), us2f(u.w));
}
__device__ __forceinline__ void store4(float* p, float4 v){ *(float4*)p = v; }
__device__ __forceinline__ void store4(bf16* p, float4 v){
  ushort4 u = make_ushort4(f2us(v.x), f2us(v.y), f2us(v.z), f2us(v.w));
  *(ushort4*)p = u;
}
__device__ __forceinline__ void store_one(float* p, float v){ *p = v; }
__device__ __forceinline__ void store_one(bf16*  p, float v){ *p = f2b(v); }

// ---------------------------------------------------------------------------
// dtype detection + normalization.  flags[1] = input-is-f32
// ---------------------------------------------------------------------------
__global__ void detect_dtype(const unsigned short* __restrict__ x, int n, int* __restrict__ flags){
  int i = blockIdx.x * 256 + threadIdx.x;
  if (i < n) {
    unsigned short u = x[i];
    if ((u & 0x7F80) == 0x7F80) atomicOr(&flags[1], 1);  // bf16 NaN/Inf pattern
  }
}
struct ConvArgs {
  const void* src[35];
  unsigned short* dst[35];
  int cum[36];
};
__global__ void conv_all(ConvArgs a, const int* __restrict__ flags){
  int gi = blockIdx.x * 256 + threadIdx.x;
  if (gi >= a.cum[35]) return;
  int lo = 0, hi = 34;
  while (lo < hi) { int mid = (lo + hi + 1) >> 1; if (gi >= a.cum[mid]) lo = mid; else hi = mid - 1; }
  int off = gi - a.cum[lo];
  if (flags[1]) a.dst[lo][off] = f2us(((const float*)a.src[lo])[off]);
  else          a.dst[lo][off] = ((const unsigned short*)a.src[lo])[off];
}
__global__ void emit_out(const unsigned short* __restrict__ stage, void* __restrict__ out,
                         int n, const int* __restrict__ flags){
  int i = blockIdx.x * 256 + threadIdx.x;
  if (i >= n) return;
  if (flags[1]) ((float*)out)[i] = us2f(stage[i]);
  else          ((unsigned short*)out)[i] = stage[i];
}
__global__ void write_sentinel(bf16* out, float v){ out[threadIdx.x] = f2b(v); }

// ---------------------------------------------------------------------------
// MFMA bf16 NT GEMM: C[M,Nn] = A[M,K] * W[Nn,K]^T (+bias) (+epilogue)
// EPI: 0 = bias only, 1 = gelu, 2 = residual add.
// Tile 128x128, 4 waves x (4x4 of 16x16x32 mfma). M%128==0, Nn%128==0, K%32==0.
// Layouts (HW-verified per guide): A-frag A[m=lane&15][k=quad*8+j];
// B-frag B[n=lane&15][k=quad*8+j] (row n of W); C/D col=lane&15,row=quad*4+reg.
// ---------------------------------------------------------------------------
#define LDT 40   // padded LDS row stride (elements); 80 B keeps b128 16B-aligned

__device__ __forceinline__ void stage16(const bf16* src, unsigned short* dst){
  uint4 a = *(const uint4*)src;
  uint4 b = *(const uint4*)(src + 8);
  *(uint4*)dst = a;
  *(uint4*)(dst + 8) = b;
}
__device__ __forceinline__ unsigned pack2(float lo, float hi){
  return (unsigned)f2us(lo) | ((unsigned)f2us(hi) << 16);
}
__device__ __forceinline__ void stage16(const float* src, unsigned short* dst){
  float4 v0 = *(const float4*)(src + 0);
  float4 v1 = *(const float4*)(src + 4);
  float4 v2 = *(const float4*)(src + 8);
  float4 v3 = *(const float4*)(src + 12);
  uint4 w0 = { pack2(v0.x, v0.y), pack2(v0.z, v0.w), pack2(v1.x, v1.y), pack2(v1.z, v1.w) };
  uint4 w1 = { pack2(v2.x, v2.y), pack2(v2.z, v2.w), pack2(v3.x, v3.y), pack2(v3.z, v3.w) };
  *(uint4*)dst = w0;
  *(uint4*)(dst + 8) = w1;
}

template<typename TA, typename TO, int EPI>
__global__ __launch_bounds__(256) void gemm_mfma(
    const TA* __restrict__ A, const bf16* __restrict__ W,
    const bf16* __restrict__ bias, const float* __restrict__ res,
    TO* __restrict__ C, int M, int Nn, int K)
{
  __shared__ unsigned short Asl[128 * LDT];
  __shared__ unsigned short Bsl[128 * LDT];
  const int tid  = threadIdx.x;
  const int wave = tid >> 6, lane = tid & 63;
  const int wm = wave & 1, wn = wave >> 1;
  const int quad = lane >> 4, l16 = lane & 15;
  const int row0 = blockIdx.y << 7, col0 = blockIdx.x << 7;
  const int srow = tid >> 1;            // 0..127
  const int scol = (tid & 1) << 4;      // 0 or 16

  f32x4 acc[4][4] = {};

  for (int kt = 0; kt < K; kt += 32) {
    stage16(A + (size_t)(row0 + srow) * K + kt + scol, &Asl[srow * LDT + scol]);
    stage16(W + (size_t)(col0 + srow) * K + kt + scol, &Bsl[srow * LDT + scol]);
    __syncthreads();
    bf16x8 af[4];
    #pragma unroll
    for (int i = 0; i < 4; ++i) {
      int m = (wm << 6) + (i << 4) + l16;
      af[i] = *(const bf16x8*)&Asl[m * LDT + (quad << 3)];
    }
    #pragma unroll
    for (int j = 0; j < 4; ++j) {
      int n = (wn << 6) + (j << 4) + l16;
      bf16x8 bfr = *(const bf16x8*)&Bsl[n * LDT + (quad << 3)];
      #pragma unroll
      for (int i = 0; i < 4; ++i)
        acc[i][j] = __builtin_amdgcn_mfma_f32_16x16x32_bf16(af[i], bfr, acc[i][j], 0, 0, 0);
    }
    __syncthreads();
  }

  #pragma unroll
  for (int j = 0; j < 4; ++j) {
    int col = col0 + (wn << 6) + (j << 4) + l16;
    float bv = bias ? b2f(bias[col]) : 0.f;
    #pragma unroll
    for (int i = 0; i < 4; ++i) {
      int rbase = row0 + (wm << 6) + (i << 4) + (quad << 2);
      #pragma unroll
      for (int r = 0; r < 4; ++r) {
        size_t base = (size_t)(rbase + r) * Nn + col;
        float v = acc[i][j][r] + bv;
        if (EPI == 1) v = gelu_f(v);
        if (EPI == 2) v += res[base];
        store_one(C + base, v);
      }
    }
  }
}

// ---------------------------------------------------------------------------
// CSR build over dst
// ---------------------------------------------------------------------------
__global__ void csr_count(const int* __restrict__ edst, int* __restrict__ cnt){
  int e = blockIdx.x * 256 + threadIdx.x;
  if (e < NE2) {
    int d = (e < NE) ? edst[e] : (e - NE);
    atomicAdd(&cnt[d], 1);
  }
}
__global__ __launch_bounds__(1024) void csr_scan(const int* __restrict__ cnt, int* __restrict__ off){
  __shared__ int ls[1024];
  int t = threadIdx.x;
  int base = t * 16;
  int loc[16]; int s = 0;
  #pragma unroll
  for (int j = 0; j < 16; ++j) { loc[j] = s; s += cnt[base + j]; }
  ls[t] = s;
  __syncthreads();
  for (int o = 1; o < 1024; o <<= 1) {
    int v = (t >= o) ? ls[t - o] : 0;
    __syncthreads();
    ls[t] += v;
    __syncthreads();
  }
  int pre = (t == 0) ? 0 : ls[t - 1];
  #pragma unroll
  for (int j = 0; j < 16; ++j) off[base + j] = pre + loc[j];
  if (t == 1023) off[N_NODES] = ls[1023];
}
__global__ void csr_fill(const int* __restrict__ edst, const int* __restrict__ off,
                         int* __restrict__ fillc, int* __restrict__ list){
  int e = blockIdx.x * 256 + threadIdx.x;
  if (e < NE2) {
    int d = (e < NE) ? edst[e] : (e - NE);
    int p = atomicAdd(&fillc[d], 1);
    list[off[d] + p] = e;
  }
}

// ---------------------------------------------------------------------------
// GAT: per-(node,head) logits. 4 nodes/block, wave=node, 16-lane group=head.
// ---------------------------------------------------------------------------
__global__ __launch_bounds__(256) void gat_alsd(
    const bf16* __restrict__ hp, const bf16* __restrict__ a_s, const bf16* __restrict__ a_d,
    float* __restrict__ al_s, float* __restrict__ al_d)
{
  int i = blockIdx.x * 4 + (threadIdx.x >> 6);
  int lane = threadIdx.x & 63;
  int head = lane >> 4, sub = lane & 15;
  const bf16* hr  = hp  + ((size_t)i * 4 + head) * 256 + sub * 16;
  const bf16* asp = a_s + head * 256 + sub * 16;
  const bf16* adp = a_d + head * 256 + sub * 16;
  float s1 = 0.f, s2 = 0.f;
  #pragma unroll
  for (int j = 0; j < 16; j += 4) {
    float4 hv = load4(hr + j); float4 av = load4(asp + j); float4 dv = load4(adp + j);
    s1 += hv.x*av.x + hv.y*av.y + hv.z*av.z + hv.w*av.w;
    s2 += hv.x*dv.x + hv.y*dv.y + hv.z*dv.z + hv.w*dv.w;
  }
  #pragma unroll
  for (int o = 8; o > 0; o >>= 1) { s1 += __shfl_xor(s1, o); s2 += __shfl_xor(s2, o); }
  if (sub == 0) { al_s[i * 4 + head] = s1; al_d[i * 4 + head] = s2; }
}

// ---------------------------------------------------------------------------
// Fused GAT softmax + aggregation + head-mean + bias + LN + GELU + residual.
// ---------------------------------------------------------------------------
__global__ __launch_bounds__(256) void gat_fused(
    const int* __restrict__ esrc, const bf16* __restrict__ hp,
    const float* __restrict__ al_s, const float* __restrict__ al_d,
    const int* __restrict__ off, const int* __restrict__ list,
    const bf16* __restrict__ bias, const bf16* __restrict__ gg, const bf16* __restrict__ gb,
    float* __restrict__ h)
{
  __shared__ float msg[4][256];
  __shared__ float red[4];
  int i = blockIdx.x; int tid = threadIdx.x;
  int g = tid >> 6; int lane = tid & 63;
  int start = off[i]; int deg = off[i + 1] - start;
  float ad = al_d[i * 4 + g];
  float mx = -1e30f;
  for (int e = lane; e < deg; e += 64) {
    int edge = list[start + e];
    int s = (edge < NE) ? esrc[edge] : (edge - NE);
    float v = al_s[s * 4 + g] + ad;
    v = (v > 0.f) ? v : 0.2f * v;
    mx = fmaxf(mx, v);
  }
  mx = wave_max(mx);
  float a0 = 0.f, a1 = 0.f, a2 = 0.f, a3 = 0.f, den = 0.f;
  for (int e = 0; e < deg; ++e) {
    int edge = list[start + e];
    int s = (edge < NE) ? esrc[edge] : (edge - NE);
    float v = al_s[s * 4 + g] + ad;
    v = (v > 0.f) ? v : 0.2f * v;
    float w = __expf(v - mx);
    den += w;
    float4 hv = load4(hp + ((size_t)s * 4 + g) * 256 + lane * 4);
    a0 += w * hv.x; a1 += w * hv.y; a2 += w * hv.z; a3 += w * hv.w;
  }
  float inv = 1.0f / den;
  msg[g][lane * 4 + 0] = a0 * inv; msg[g][lane * 4 + 1] = a1 * inv;
  msg[g][lane * 4 + 2] = a2 * inv; msg[g][lane * 4 + 3] = a3 * inv;
  __syncthreads();
  int c = tid;
  float out = 0.25f * (msg[0][c] + msg[1][c] + msg[2][c] + msg[3][c]) + b2f(bias[c]);
  float mean = block_sum_256(out, red) * (1.0f / 256.0f);
  float d = out - mean;
  float var = block_sum_256(d * d, red) * (1.0f / 256.0f);
  float y = d * rsqrtf(var + 1e-5f) * b2f(gg[c]) + b2f(gb[c]);
  h[(size_t)i * 256 + c] += gelu_f(y);
}

// ---------------------------------------------------------------------------
// LayerNorm: wave-per-row (4 rows/block), f32 in, bf16 out
// ---------------------------------------------------------------------------
__global__ __launch_bounds__(256) void ln_kernel(
    const float* __restrict__ x, bf16* __restrict__ y,
    const bf16* __restrict__ g, const bf16* __restrict__ b)
{
  int row = blockIdx.x * 4 + (threadIdx.x >> 6);
  int lane = threadIdx.x & 63;
  int c = lane * 4;
  float4 v = load4(x + (size_t)row * 256 + c);
  float mean = wave_sum(v.x + v.y + v.z + v.w) * (1.0f / 256.0f);
  float dx = v.x - mean, dy = v.y - mean, dz = v.z - mean, dw = v.w - mean;
  float var = wave_sum(dx*dx + dy*dy + dz*dz + dw*dw) * (1.0f / 256.0f);
  float r = rsqrtf(var + 1e-5f);
  float4 gv = load4(g + c); float4 bv = load4(b + c);
  store4(y + (size_t)row * 256 + c,
         make_float4(dx*r*gv.x + bv.x, dy*r*gv.y + bv.y, dz*r*gv.z + bv.z, dw*r*gv.w + bv.w));
}

// ---------------------------------------------------------------------------
// Transformer attention: seq = 256 graphs, block = (node b, head hh).
// One query per thread; K/V staged f32 in LDS (64 KB, 2 blocks/CU).
// ---------------------------------------------------------------------------
__global__ __launch_bounds__(256) void attn_kernel(
    const bf16* __restrict__ qkv, bf16* __restrict__ obuf)
{
  const int b  = blockIdx.x & 63;
  const int hh = blockIdx.x >> 6;
  __shared__ float Ks[256][32];
  __shared__ float Vs[256][32];
  const int tid = threadIdx.x;
  for (int idx = tid; idx < 256 * 8; idx += 256) {
    int t = idx >> 3, d4 = (idx & 7) << 2;
    size_t rb = (size_t)(t * 64 + b) * 768 + hh * 32 + d4;
    float4 kv = load4(qkv + rb + 256);
    float4 vv = load4(qkv + rb + 512);
    Ks[t][d4] = kv.x; Ks[t][d4+1] = kv.y; Ks[t][d4+2] = kv.z; Ks[t][d4+3] = kv.w;
    Vs[t][d4] = vv.x; Vs[t][d4+1] = vv.y; Vs[t][d4+2] = vv.z; Vs[t][d4+3] = vv.w;
  }
  float q[32];
  {
    const bf16* qp = qkv + (size_t)(tid * 64 + b) * 768 + hh * 32;
    #pragma unroll
    for (int d = 0; d < 32; d += 4) {
      float4 v = load4(qp + d);
      q[d] = v.x; q[d+1] = v.y; q[d+2] = v.z; q[d+3] = v.w;
    }
  }
  __syncthreads();
  const float scale = 0.17677669529663687f;  // 1/sqrt(32)
  float acc[32] = {}; float l = 0.f;
  for (int k = 0; k < 256; ++k) {
    float sc = 0.f;
    #pragma unroll
    for (int d = 0; d < 32; ++d) sc += q[d] * Ks[k][d];
    sc = fminf(fmaxf(sc * scale, -60.f), 60.f);
    float e = __expf(sc);
    l += e;
    #pragma unroll
    for (int d = 0; d < 32; ++d) acc[d] += e * Vs[k][d];
  }
  float inv = 1.0f / l;
  bf16* op = obuf + (size_t)(tid * 64 + b) * 256 + hh * 32;
  #pragma unroll
  for (int d = 0; d < 32; d += 4)
    store4(op + d, make_float4(acc[d]*inv, acc[d+1]*inv, acc[d+2]*inv, acc[d+3]*inv));
}

// ---------------------------------------------------------------------------
// Pooling + heads
// ---------------------------------------------------------------------------
__global__ __launch_bounds__(256) void pool_logit(
    const float* __restrict__ h, const bf16* __restrict__ pw, const bf16* __restrict__ pb,
    float* __restrict__ logits)
{
  int n = blockIdx.x * 4 + (threadIdx.x >> 6); int lane = threadIdx.x & 63;
  float4 hv = load4(h + (size_t)n * 256 + lane * 4);
  float4 wv = load4(pw + lane * 4);
  float acc = wave_sum(hv.x*wv.x + hv.y*wv.y + hv.z*wv.z + hv.w*wv.w);
  if (lane == 0) logits[n] = acc + b2f(pb[0]);
}
__global__ __launch_bounds__(1024) void pool_reduce(
    const float* __restrict__ logits, float* __restrict__ red)
{
  __shared__ float sm[16];
  int t = threadIdx.x;
  float m = -1e30f;
  for (int i = t; i < N_NODES; i += 1024) m = fmaxf(m, logits[i]);
  m = wave_max(m);
  if ((t & 63) == 0) sm[t >> 6] = m;
  __syncthreads();
  if (t == 0) { float mm = sm[0]; for (int i = 1; i < 16; ++i) mm = fmaxf(mm, sm[i]); sm[0] = mm; }
  __syncthreads();
  float gmax = sm[0];
  __syncthreads();
  float s = 0.f;
  for (int i = t; i < N_NODES; i += 1024) s += expf(logits[i] - gmax);
  s = wave_sum(s);
  if ((t & 63) == 0) sm[t >> 6] = s;
  __syncthreads();
  if (t == 0) { float ss = 0.f; for (int i = 0; i < 16; ++i) ss += sm[i]; red[0] = gmax; red[1] = 1.0f / ss; }
}
__global__ __launch_bounds__(256) void pool_grep(
    const float* __restrict__ h, const float* __restrict__ logits,
    const float* __restrict__ red, float* __restrict__ g_rep)
{
  __shared__ float w[64];
  int g = blockIdx.x; int tid = threadIdx.x;
  if (tid < 64) w[tid] = expf(logits[g * 64 + tid] - red[0]) * red[1];
  __syncthreads();
  float acc = 0.f;
  for (int nd = 0; nd < 64; ++nd) acc += h[((size_t)g * 64 + nd) * 256 + tid] * w[nd];
  g_rep[(size_t)g * 256 + tid] = acc;
}
__global__ __launch_bounds__(256) void head_value(
    const float* __restrict__ vt, const bf16* __restrict__ w2, const bf16* __restrict__ b2,
    bf16* __restrict__ out)
{
  int gidx = blockIdx.x * 4 + (threadIdx.x >> 6); int lane = threadIdx.x & 63;
  float acc = 0.f;
  #pragma unroll
  for (int j = 0; j < 4; ++j) { int c = j * 64 + lane; acc += vt[(size_t)gidx * 256 + c] * b2f(w2[c]); }
  acc = wave_sum(acc);
  if (lane == 0) out[gidx] = f2b(tanhf(acc + b2f(b2[0])));
}
__global__ __launch_bounds__(256) void head_unc(
    const float* __restrict__ ut, const bf16* __restrict__ w2, const bf16* __restrict__ b2,
    bf16* __restrict__ out)
{
  int gidx = blockIdx.x * 4 + (threadIdx.x >> 6); int lane = threadIdx.x & 63;
  float acc = 0.f;
  #pragma unroll
  for (int j = 0; j < 2; ++j) { int c = j * 64 + lane; acc += ut[(size_t)gidx * 128 + c] * b2f(w2[c]); }
  acc = wave_sum(acc);
  if (lane == 0) {
    float x = acc + b2f(b2[0]);
    float sp = (x > 20.f) ? x : log1pf(expf(x));
    out[gidx] = f2b(sp);
  }
}

// ---------------------------------------------------------------------------
extern "C" void kernel_launch(void* const* d_in, const int* in_sizes, int n_in,
                              void* d_out, int out_size, void* d_ws, size_t ws_size,
                              hipStream_t stream)
{
  (void)out_size;
  const int* eidx = (const int*)d_in[1];

  char* ws = (char*)d_ws;
  size_t wo = 0;
  auto alloc = [&](size_t bytes) -> char* {
    char* p = ws + wo; wo += (bytes + 255) & ~(size_t)255; return p;
  };
  int*   flags = (int*)alloc(256);
  int*   cnt   = (int*)alloc((size_t)N_NODES * 4);
  int*   fillc = (int*)alloc((size_t)N_NODES * 4);
  size_t zero_end = wo;

  bf16* conv[38] = {};
  static const int fidx[35] = {0,4,5,6,7,8,9,10,11,12,13,14,15,16,17,18,19,
                               20,21,22,23,24,25,26,27,28,29,30,31,32,33,34,35,36,37};
  for (int j = 0; j < 35; ++j) {
    int idx = fidx[j];
    conv[idx] = (bf16*)alloc((size_t)in_sizes[idx] * 2);
  }
  float* h     = (float*)alloc((size_t)N_NODES * 256 * 4);   // 16 MB (f32 residual)
  bf16*  big   = (bf16*) alloc((size_t)N_NODES * 1024 * 2);  // 32 MB (hp / qkv+obuf / ffb)
  bf16*  tn    = (bf16*) alloc((size_t)N_NODES * 256 * 2);   // 8 MB
  float* al_s  = (float*)alloc((size_t)N_NODES * 4 * 4);
  float* al_d  = (float*)alloc((size_t)N_NODES * 4 * 4);
  int*   off   = (int*)alloc((size_t)(N_NODES + 1) * 4);
  int*   list  = (int*)alloc((size_t)NE2 * 4);
  float* logits= (float*)alloc((size_t)N_NODES * 4);
  float* redb  = (float*)alloc(256);
  float* g_rep = (float*)alloc((size_t)256 * 256 * 4);
  float* val_t = (float*)alloc((size_t)256 * 256 * 4);
  float* unc_t = (float*)alloc((size_t)256 * 128 * 4);
  const int OUT_ELEMS = 256 + N_NODES * 256 + 256;
  bf16*  ostage = (bf16*)alloc((size_t)OUT_ELEMS * 2);
  size_t needed = wo;

  if (n_in != 38)                   { write_sentinel<<<1,256,0,stream>>>((bf16*)d_out, 4.f);  return; }
  if (in_sizes[0] != N_NODES * 128) { write_sentinel<<<1,256,0,stream>>>((bf16*)d_out, 8.f);  return; }
  if (in_sizes[1] != 2 * NE)        { write_sentinel<<<1,256,0,stream>>>((bf16*)d_out, 16.f); return; }
  if (ws_size < needed)             { write_sentinel<<<1,256,0,stream>>>((bf16*)d_out, 32.f); return; }

  hipMemsetAsync(d_ws, 0, zero_end, stream);

  // dtype detect on x, then normalize every float tensor to bf16 (one kernel)
  detect_dtype<<<256, 256, 0, stream>>>((const unsigned short*)d_in[0], 65536, flags);
  {
    ConvArgs ca;
    int cum = 0;
    for (int j = 0; j < 35; ++j) {
      int idx = fidx[j];
      ca.src[j] = d_in[idx];
      ca.dst[j] = (unsigned short*)conv[idx];
      ca.cum[j] = cum;
      cum += in_sizes[idx];
    }
    ca.cum[35] = cum;
    conv_all<<<(cum + 255) / 256, 256, 0, stream>>>(ca, flags);
  }
  const bf16 *xb = conv[0], *emb_w = conv[4], *emb_b = conv[5], *gat_w = conv[6],
             *gat_as = conv[7], *gat_ad = conv[8], *gat_b = conv[9], *gnn_g = conv[10],
             *gnn_beta = conv[11], *ln1_g = conv[12], *ln1_b = conv[13], *in_w = conv[14],
             *in_b = conv[15], *out_w = conv[16], *out_b = conv[17], *ln2_g = conv[18],
             *ln2_b = conv[19], *ff1_w = conv[20], *ff1_b = conv[21], *ff2_w = conv[22],
             *ff2_b = conv[23], *pool_w = conv[24], *pool_b = conv[25],
             *vw1 = conv[26], *vb1 = conv[27], *vw2 = conv[28], *vb2 = conv[29],
             *pw1 = conv[30], *pb1 = conv[31], *pw2 = conv[32], *pb2 = conv[33],
             *uw1 = conv[34], *ub1 = conv[35], *uw2 = conv[36], *ub2 = conv[37];

  bf16* qkv  = big;                          // N x 768
  bf16* obuf = big + (size_t)N_NODES * 768;  // N x 256
  bf16* hp   = big;                          // N x 1024
  bf16* ffb  = big;                          // N x 1024
  bf16* o_val = ostage;
  bf16* o_pol = ostage + 256;
  bf16* o_unc = ostage + 256 + (size_t)N_NODES * 256;

  // CSR (cnt/fillc zeroed by memset)
  csr_count<<<(NE2 + 255) / 256, 256, 0, stream>>>(eidx + NE, cnt);
  csr_scan<<<1, 1024, 0, stream>>>(cnt, off);
  csr_fill<<<(NE2 + 255) / 256, 256, 0, stream>>>(eidx + NE, off, fillc, list);

  // Embedding
  gemm_mfma<bf16, float, 0><<<dim3(2, 128), 256, 0, stream>>>(
      xb, emb_w, emb_b, nullptr, h, N_NODES, 256, 128);

  // GNN layers
  for (int l = 0; l < 8; ++l) {
    gemm_mfma<float, bf16, 0><<<dim3(8, 128), 256, 0, stream>>>(
        h, gat_w + (size_t)l * 1024 * 256, nullptr, nullptr, hp, N_NODES, 1024, 256);
    gat_alsd<<<N_NODES / 4, 256, 0, stream>>>(hp, gat_as + l * 1024, gat_ad + l * 1024, al_s, al_d);
    gat_fused<<<N_NODES, 256, 0, stream>>>(eidx, hp, al_s, al_d, off, list,
        gat_b + l * 256, gnn_g + l * 256, gnn_beta + l * 256, h);
  }

  // Transformer layers
  for (int l = 0; l < 6; ++l) {
    ln_kernel<<<N_NODES / 4, 256, 0, stream>>>(h, tn, ln1_g + l * 256, ln1_b + l * 256);
    gemm_mfma<bf16, bf16, 0><<<dim3(6, 128), 256, 0, stream>>>(
        tn, in_w + (size_t)l * 768 * 256, in_b + l * 768, nullptr, qkv, N_NODES, 768, 256);
    attn_kernel<<<512, 256, 0, stream>>>(qkv, obuf);
    gemm_mfma<bf16, float, 2><<<dim3(2, 128), 256, 0, stream>>>(
        obuf, out_w + (size_t)l * 256 * 256, out_b + l * 256, h, h, N_NODES, 256, 256);
    ln_kernel<<<N_NODES / 4, 256, 0, stream>>>(h, tn, ln2_g + l * 256, ln2_b + l * 256);
    gemm_mfma<bf16, bf16, 1><<<dim3(8, 128), 256, 0, stream>>>(
        tn, ff1_w + (size_t)l * 1024 * 256, ff1_b + l * 1024, nullptr, ffb, N_NODES, 1024, 256);
    gemm_mfma<bf16, float, 2><<<dim3(2, 128), 256, 0, stream>>>(
        ffb, ff2_w + (size_t)l * 256 * 1024, ff2_b + l * 256, h, h, N_NODES, 256, 1024);
  }

  // Pooling + heads
  pool_logit<<<N_NODES / 4, 256, 0, stream>>>(h, pool_w, pool_b, logits);
  pool_reduce<<<1, 1024, 0, stream>>>(logits, redb);
  pool_grep<<<256, 256, 0, stream>>>(h, logits, redb, g_rep);
  gemm_mfma<float, float, 1><<<dim3(2, 2), 256, 0, stream>>>(
      g_rep, vw1, vb1, nullptr, val_t, 256, 256, 256);
  head_value<<<64, 256, 0, stream>>>(val_t, vw2, vb2, o_val);
  gemm_mfma<float, float, 1><<<dim3(1, 2), 256, 0, stream>>>(
      g_rep, uw1, ub1, nullptr, unc_t, 256, 128, 256);
  head_unc<<<64, 256, 0, stream>>>(unc_t, uw2, ub2, o_unc);
  gemm_mfma<float, bf16, 1><<<dim3(2, 128), 256, 0, stream>>>(
      h, pw1, pb1, nullptr, tn, N_NODES, 256, 256);
  gemm_mfma<bf16, bf16, 0><<<dim3(2, 128), 256, 0, stream>>>(
      tn, pw2, pb2, nullptr, o_pol, N_NODES, 256, 256);

  emit_out<<<(OUT_ELEMS + 255) / 256, 256, 0, stream>>>(
      (const unsigned short*)ostage, d_out, OUT_ELEMS, flags);
}

// Round 7
// 1966.920 us; speedup vs baseline: 3.9285x; 1.2011x over previous
//
#include <hip/hip_runtime.h>
#include <hip/hip_bf16.h>

typedef __hip_bfloat16 bf16;
typedef __bf16 bf16x8 __attribute__((ext_vector_type(8)));
typedef float  f32x4  __attribute__((ext_vector_type(4)));

#define N_NODES 16384
#define HDIM    256
#define NE      131072
#define NE2     147456   // NE + N self loops

__device__ __forceinline__ float b2f(bf16 v){ return __bfloat162float(v); }
__device__ __forceinline__ bf16  f2b(float v){ return __float2bfloat16(v); }
__device__ __forceinline__ float us2f(unsigned short u){
  union { unsigned int i; float f; } c; c.i = ((unsigned int)u) << 16; return c.f;
}
__device__ __forceinline__ unsigned short f2us(float f){
  bf16 h = __float2bfloat16(f);
  unsigned short u; __builtin_memcpy(&u, &h, 2); return u;
}
__device__ __forceinline__ float gelu_f(float x){
  return 0.5f * x * (1.0f + erff(x * 0.7071067811865476f));
}
__device__ __forceinline__ float wave_sum(float v){
  #pragma unroll
  for (int o = 32; o > 0; o >>= 1) v += __shfl_xor(v, o);
  return v;
}
__device__ __forceinline__ float wave_max(float v){
  #pragma unroll
  for (int o = 32; o > 0; o >>= 1) v = fmaxf(v, __shfl_xor(v, o));
  return v;
}
__device__ __forceinline__ float block_sum_256(float v, float* red){
  v = wave_sum(v);
  __syncthreads();
  if ((threadIdx.x & 63) == 0) red[threadIdx.x >> 6] = v;
  __syncthreads();
  return red[0] + red[1] + red[2] + red[3];
}

__device__ __forceinline__ float4 load4(const float* p){ return *(const float4*)p; }
__device__ __forceinline__ float4 load4(const bf16* p){
  ushort4 u = *(const ushort4*)p;
  return make_float4(us2f(u.x), us2f(u.y), us2f(u.z), us2f(u.w));
}
__device__ __forceinline__ void store4(float* p, float4 v){ *(float4*)p = v; }
__device__ __forceinline__ void store4(bf16* p, float4 v){
  ushort4 u = make_ushort4(f2us(v.x), f2us(v.y), f2us(v.z), f2us(v.w));
  *(ushort4*)p = u;
}
__device__ __forceinline__ void store_one(float* p, float v){ *p = v; }
__device__ __forceinline__ void store_one(bf16*  p, float v){ *p = f2b(v); }

// ---------------------------------------------------------------------------
// dtype detection + normalization.  flags[1] = input-is-f32
// ---------------------------------------------------------------------------
__global__ void detect_dtype(const unsigned short* __restrict__ x, int n, int* __restrict__ flags){
  int i = blockIdx.x * 256 + threadIdx.x;
  if (i < n) {
    unsigned short u = x[i];
    if ((u & 0x7F80) == 0x7F80) atomicOr(&flags[1], 1);  // bf16 NaN/Inf pattern
  }
}
struct ConvArgs {
  const void* src[35];
  unsigned short* dst[35];
  int cum[36];
};
__global__ void conv_all(ConvArgs a, const int* __restrict__ flags){
  int gi = blockIdx.x * 256 + threadIdx.x;
  if (gi >= a.cum[35]) return;
  int lo = 0, hi = 34;
  while (lo < hi) { int mid = (lo + hi + 1) >> 1; if (gi >= a.cum[mid]) lo = mid; else hi = mid - 1; }
  int off = gi - a.cum[lo];
  if (flags[1]) a.dst[lo][off] = f2us(((const float*)a.src[lo])[off]);
  else          a.dst[lo][off] = ((const unsigned short*)a.src[lo])[off];
}
__global__ void emit_out(const unsigned short* __restrict__ stage, void* __restrict__ out,
                         int n, const int* __restrict__ flags){
  int i = blockIdx.x * 256 + threadIdx.x;
  if (i >= n) return;
  if (flags[1]) ((float*)out)[i] = us2f(stage[i]);
  else          ((unsigned short*)out)[i] = stage[i];
}
__global__ void write_sentinel(bf16* out, float v){ out[threadIdx.x] = f2b(v); }

// ---------------------------------------------------------------------------
// MFMA bf16 NT GEMM: C[M,Nn] = A[M,K] * W[Nn,K]^T (+bias) (+epilogue)
// EPI: 0 = bias only, 1 = gelu, 2 = residual add.
// Tile 128x128, 4 waves x (4x4 of 16x16x32 mfma). M%128==0, Nn%128==0, K%32==0.
// ---------------------------------------------------------------------------
#define LDT 40   // padded LDS row stride (elements); 80 B keeps b128 16B-aligned

__device__ __forceinline__ void stage16(const bf16* src, unsigned short* dst){
  uint4 a = *(const uint4*)src;
  uint4 b = *(const uint4*)(src + 8);
  *(uint4*)dst = a;
  *(uint4*)(dst + 8) = b;
}
__device__ __forceinline__ unsigned pack2(float lo, float hi){
  return (unsigned)f2us(lo) | ((unsigned)f2us(hi) << 16);
}
__device__ __forceinline__ void stage16(const float* src, unsigned short* dst){
  float4 v0 = *(const float4*)(src + 0);
  float4 v1 = *(const float4*)(src + 4);
  float4 v2 = *(const float4*)(src + 8);
  float4 v3 = *(const float4*)(src + 12);
  uint4 w0 = { pack2(v0.x, v0.y), pack2(v0.z, v0.w), pack2(v1.x, v1.y), pack2(v1.z, v1.w) };
  uint4 w1 = { pack2(v2.x, v2.y), pack2(v2.z, v2.w), pack2(v3.x, v3.y), pack2(v3.z, v3.w) };
  *(uint4*)dst = w0;
  *(uint4*)(dst + 8) = w1;
}

template<typename TA, typename TO, int EPI>
__global__ __launch_bounds__(256) void gemm_mfma(
    const TA* __restrict__ A, const bf16* __restrict__ W,
    const bf16* __restrict__ bias, const float* __restrict__ res,
    TO* __restrict__ C, int M, int Nn, int K)
{
  __shared__ unsigned short Asl[128 * LDT];
  __shared__ unsigned short Bsl[128 * LDT];
  const int tid  = threadIdx.x;
  const int wave = tid >> 6, lane = tid & 63;
  const int wm = wave & 1, wn = wave >> 1;
  const int quad = lane >> 4, l16 = lane & 15;
  const int row0 = blockIdx.y << 7, col0 = blockIdx.x << 7;
  const int srow = tid >> 1;            // 0..127
  const int scol = (tid & 1) << 4;      // 0 or 16

  f32x4 acc[4][4] = {};

  for (int kt = 0; kt < K; kt += 32) {
    stage16(A + (size_t)(row0 + srow) * K + kt + scol, &Asl[srow * LDT + scol]);
    stage16(W + (size_t)(col0 + srow) * K + kt + scol, &Bsl[srow * LDT + scol]);
    __syncthreads();
    bf16x8 af[4];
    #pragma unroll
    for (int i = 0; i < 4; ++i) {
      int m = (wm << 6) + (i << 4) + l16;
      af[i] = *(const bf16x8*)&Asl[m * LDT + (quad << 3)];
    }
    #pragma unroll
    for (int j = 0; j < 4; ++j) {
      int n = (wn << 6) + (j << 4) + l16;
      bf16x8 bfr = *(const bf16x8*)&Bsl[n * LDT + (quad << 3)];
      #pragma unroll
      for (int i = 0; i < 4; ++i)
        acc[i][j] = __builtin_amdgcn_mfma_f32_16x16x32_bf16(af[i], bfr, acc[i][j], 0, 0, 0);
    }
    __syncthreads();
  }

  #pragma unroll
  for (int j = 0; j < 4; ++j) {
    int col = col0 + (wn << 6) + (j << 4) + l16;
    float bv = bias ? b2f(bias[col]) : 0.f;
    #pragma unroll
    for (int i = 0; i < 4; ++i) {
      int rbase = row0 + (wm << 6) + (i << 4) + (quad << 2);
      #pragma unroll
      for (int r = 0; r < 4; ++r) {
        size_t base = (size_t)(rbase + r) * Nn + col;
        float v = acc[i][j][r] + bv;
        if (EPI == 1) v = gelu_f(v);
        if (EPI == 2) v += res[base];
        store_one(C + base, v);
      }
    }
  }
}

// ---------------------------------------------------------------------------
// CSR build over dst
// ---------------------------------------------------------------------------
__global__ void csr_count(const int* __restrict__ edst, int* __restrict__ cnt){
  int e = blockIdx.x * 256 + threadIdx.x;
  if (e < NE2) {
    int d = (e < NE) ? edst[e] : (e - NE);
    atomicAdd(&cnt[d], 1);
  }
}
__global__ __launch_bounds__(1024) void csr_scan(const int* __restrict__ cnt, int* __restrict__ off){
  __shared__ int ls[1024];
  int t = threadIdx.x;
  int base = t * 16;
  int loc[16]; int s = 0;
  #pragma unroll
  for (int j = 0; j < 16; ++j) { loc[j] = s; s += cnt[base + j]; }
  ls[t] = s;
  __syncthreads();
  for (int o = 1; o < 1024; o <<= 1) {
    int v = (t >= o) ? ls[t - o] : 0;
    __syncthreads();
    ls[t] += v;
    __syncthreads();
  }
  int pre = (t == 0) ? 0 : ls[t - 1];
  #pragma unroll
  for (int j = 0; j < 16; ++j) off[base + j] = pre + loc[j];
  if (t == 1023) off[N_NODES] = ls[1023];
}
__global__ void csr_fill(const int* __restrict__ edst, const int* __restrict__ off,
                         int* __restrict__ fillc, int* __restrict__ list){
  int e = blockIdx.x * 256 + threadIdx.x;
  if (e < NE2) {
    int d = (e < NE) ? edst[e] : (e - NE);
    int p = atomicAdd(&fillc[d], 1);
    list[off[d] + p] = e;
  }
}

// ---------------------------------------------------------------------------
// GAT: per-(node,head) logits. 4 nodes/block, wave=node, 16-lane group=head.
// ---------------------------------------------------------------------------
__global__ __launch_bounds__(256) void gat_alsd(
    const bf16* __restrict__ hp, const bf16* __restrict__ a_s, const bf16* __restrict__ a_d,
    float* __restrict__ al_s, float* __restrict__ al_d)
{
  int i = blockIdx.x * 4 + (threadIdx.x >> 6);
  int lane = threadIdx.x & 63;
  int head = lane >> 4, sub = lane & 15;
  const bf16* hr  = hp  + ((size_t)i * 4 + head) * 256 + sub * 16;
  const bf16* asp = a_s + head * 256 + sub * 16;
  const bf16* adp = a_d + head * 256 + sub * 16;
  float s1 = 0.f, s2 = 0.f;
  #pragma unroll
  for (int j = 0; j < 16; j += 4) {
    float4 hv = load4(hr + j); float4 av = load4(asp + j); float4 dv = load4(adp + j);
    s1 += hv.x*av.x + hv.y*av.y + hv.z*av.z + hv.w*av.w;
    s2 += hv.x*dv.x + hv.y*dv.y + hv.z*dv.z + hv.w*dv.w;
  }
  #pragma unroll
  for (int o = 8; o > 0; o >>= 1) { s1 += __shfl_xor(s1, o); s2 += __shfl_xor(s2, o); }
  if (sub == 0) { al_s[i * 4 + head] = s1; al_d[i * 4 + head] = s2; }
}

// ---------------------------------------------------------------------------
// Fused GAT softmax + aggregation + head-mean + bias + LN + GELU + residual.
// ---------------------------------------------------------------------------
__global__ __launch_bounds__(256) void gat_fused(
    const int* __restrict__ esrc, const bf16* __restrict__ hp,
    const float* __restrict__ al_s, const float* __restrict__ al_d,
    const int* __restrict__ off, const int* __restrict__ list,
    const bf16* __restrict__ bias, const bf16* __restrict__ gg, const bf16* __restrict__ gb,
    float* __restrict__ h)
{
  __shared__ float msg[4][256];
  __shared__ float red[4];
  int i = blockIdx.x; int tid = threadIdx.x;
  int g = tid >> 6; int lane = tid & 63;
  int start = off[i]; int deg = off[i + 1] - start;
  float ad = al_d[i * 4 + g];
  float mx = -1e30f;
  for (int e = lane; e < deg; e += 64) {
    int edge = list[start + e];
    int s = (edge < NE) ? esrc[edge] : (edge - NE);
    float v = al_s[s * 4 + g] + ad;
    v = (v > 0.f) ? v : 0.2f * v;
    mx = fmaxf(mx, v);
  }
  mx = wave_max(mx);
  float a0 = 0.f, a1 = 0.f, a2 = 0.f, a3 = 0.f, den = 0.f;
  for (int e = 0; e < deg; ++e) {
    int edge = list[start + e];
    int s = (edge < NE) ? esrc[edge] : (edge - NE);
    float v = al_s[s * 4 + g] + ad;
    v = (v > 0.f) ? v : 0.2f * v;
    float w = __expf(v - mx);
    den += w;
    float4 hv = load4(hp + ((size_t)s * 4 + g) * 256 + lane * 4);
    a0 += w * hv.x; a1 += w * hv.y; a2 += w * hv.z; a3 += w * hv.w;
  }
  float inv = 1.0f / den;
  msg[g][lane * 4 + 0] = a0 * inv; msg[g][lane * 4 + 1] = a1 * inv;
  msg[g][lane * 4 + 2] = a2 * inv; msg[g][lane * 4 + 3] = a3 * inv;
  __syncthreads();
  int c = tid;
  float out = 0.25f * (msg[0][c] + msg[1][c] + msg[2][c] + msg[3][c]) + b2f(bias[c]);
  float mean = block_sum_256(out, red) * (1.0f / 256.0f);
  float d = out - mean;
  float var = block_sum_256(d * d, red) * (1.0f / 256.0f);
  float y = d * rsqrtf(var + 1e-5f) * b2f(gg[c]) + b2f(gb[c]);
  h[(size_t)i * 256 + c] += gelu_f(y);
}

// ---------------------------------------------------------------------------
// LayerNorm: wave-per-row (4 rows/block), f32 in, bf16 out
// ---------------------------------------------------------------------------
__global__ __launch_bounds__(256) void ln_kernel(
    const float* __restrict__ x, bf16* __restrict__ y,
    const bf16* __restrict__ g, const bf16* __restrict__ b)
{
  int row = blockIdx.x * 4 + (threadIdx.x >> 6);
  int lane = threadIdx.x & 63;
  int c = lane * 4;
  float4 v = load4(x + (size_t)row * 256 + c);
  float mean = wave_sum(v.x + v.y + v.z + v.w) * (1.0f / 256.0f);
  float dx = v.x - mean, dy = v.y - mean, dz = v.z - mean, dw = v.w - mean;
  float var = wave_sum(dx*dx + dy*dy + dz*dz + dw*dw) * (1.0f / 256.0f);
  float r = rsqrtf(var + 1e-5f);
  float4 gv = load4(g + c); float4 bv = load4(b + c);
  store4(y + (size_t)row * 256 + c,
         make_float4(dx*r*gv.x + bv.x, dy*r*gv.y + bv.y, dz*r*gv.z + bv.z, dw*r*gv.w + bv.w));
}

// ---------------------------------------------------------------------------
// MFMA flash-style attention. seq = 256 graphs, block = (node b, head hh).
// 4 waves; wave w owns query rows [64w, 64w+64). Q/K frags read directly from
// global (16B-aligned slices); V^T staged in LDS; P round-trips through a
// wave-private LDS tile (C-layout -> A-layout), no barriers in the main loop.
// Max-free softmax (clamp +-60), matches rounds 5/6 numerics.
// ---------------------------------------------------------------------------
#define VT_LDS 268   // V^T row stride (shorts): 536 B -> conflict-free B-frags
#define P_LDS  72    // P row stride (shorts): 144 B, 16B-aligned frag reads

__global__ __launch_bounds__(256) void attn_mfma(
    const bf16* __restrict__ qkv, bf16* __restrict__ obuf)
{
  const int b  = blockIdx.x & 63;
  const int hh = blockIdx.x >> 6;
  __shared__ unsigned short VTs[32 * VT_LDS];   // 16.75 KB
  __shared__ unsigned short Ps[4][64 * P_LDS];  // 4 x 9 KB (wave-private)
  const int tid  = threadIdx.x;
  const int wave = tid >> 6, lane = tid & 63;
  const int quad = lane >> 4, l16 = lane & 15;

  // stage V transposed: thread t reads V row (t*64+b), writes VTs[d][t]
  {
    const bf16* vb = qkv + (size_t)(tid * 64 + b) * 768 + 512 + hh * 32;
    unsigned short vv[32];
    *(uint4*)&vv[0]  = *(const uint4*)(vb);
    *(uint4*)&vv[8]  = *(const uint4*)(vb + 8);
    *(uint4*)&vv[16] = *(const uint4*)(vb + 16);
    *(uint4*)&vv[24] = *(const uint4*)(vb + 24);
    #pragma unroll
    for (int d = 0; d < 32; ++d) VTs[d * VT_LDS + tid] = vv[d];
  }
  // Q A-frags direct from global: rows s = wave*64 + i*16 + l16
  bf16x8 qf[4];
  #pragma unroll
  for (int i = 0; i < 4; ++i) {
    int s = (wave << 6) + (i << 4) + l16;
    qf[i] = *(const bf16x8*)(qkv + (size_t)(s * 64 + b) * 768 + hh * 32 + (quad << 3));
  }
  __syncthreads();

  const float scale = 0.17677669529663687f;   // 1/sqrt(32)
  f32x4 oacc[4][2] = {};
  float lsum[4][4] = {};
  unsigned short* Pw = &Ps[wave][0];

  for (int nt = 0; nt < 4; ++nt) {
    // K B-frags direct from global: rows t = nt*64 + j*16 + l16
    bf16x8 kf[4];
    #pragma unroll
    for (int j = 0; j < 4; ++j) {
      int t = (nt << 6) + (j << 4) + l16;
      kf[j] = *(const bf16x8*)(qkv + (size_t)(t * 64 + b) * 768 + 256 + hh * 32 + (quad << 3));
    }
    f32x4 zero = {0.f, 0.f, 0.f, 0.f};
    f32x4 sx[4][4];
    #pragma unroll
    for (int i = 0; i < 4; ++i)
      #pragma unroll
      for (int j = 0; j < 4; ++j)
        sx[i][j] = __builtin_amdgcn_mfma_f32_16x16x32_bf16(qf[i], kf[j], zero, 0, 0, 0);
    // exp + row sums + P -> LDS (A-layout tile, wave-private)
    #pragma unroll
    for (int i = 0; i < 4; ++i) {
      #pragma unroll
      for (int r = 0; r < 4; ++r) {
        float p[4]; float rs = 0.f;
        #pragma unroll
        for (int j = 0; j < 4; ++j) {
          float sc = fminf(fmaxf(sx[i][j][r] * scale, -60.f), 60.f);
          p[j] = __expf(sc);
          rs += p[j];
        }
        #pragma unroll
        for (int o = 1; o < 16; o <<= 1) rs += __shfl_xor(rs, o);
        lsum[i][r] += rs;
        int row = (i << 4) + (quad << 2) + r;
        #pragma unroll
        for (int j = 0; j < 4; ++j)
          Pw[row * P_LDS + (j << 4) + l16] = f2us(p[j]);
      }
    }
    // PV: O[s][d] += P[s][t] V[t][d];  A = P tile, B = V^T rows
    #pragma unroll
    for (int kk = 0; kk < 2; ++kk) {
      bf16x8 vf[2];
      #pragma unroll
      for (int j2 = 0; j2 < 2; ++j2)
        vf[j2] = *(const bf16x8*)&VTs[((j2 << 4) + l16) * VT_LDS + (nt << 6) + (kk << 5) + (quad << 3)];
      #pragma unroll
      for (int i2 = 0; i2 < 4; ++i2) {
        bf16x8 pf = *(const bf16x8*)&Pw[((i2 << 4) + l16) * P_LDS + (kk << 5) + (quad << 3)];
        #pragma unroll
        for (int j2 = 0; j2 < 2; ++j2)
          oacc[i2][j2] = __builtin_amdgcn_mfma_f32_16x16x32_bf16(pf, vf[j2], oacc[i2][j2], 0, 0, 0);
      }
    }
  }
  // epilogue: normalize and store (C-layout rows match lsum rows)
  #pragma unroll
  for (int i = 0; i < 4; ++i) {
    #pragma unroll
    for (int r = 0; r < 4; ++r) {
      int srow = (wave << 6) + (i << 4) + (quad << 2) + r;
      float inv = 1.0f / lsum[i][r];
      #pragma unroll
      for (int j2 = 0; j2 < 2; ++j2)
        obuf[(size_t)(srow * 64 + b) * 256 + hh * 32 + (j2 << 4) + l16] = f2b(oacc[i][j2][r] * inv);
    }
  }
}

// ---------------------------------------------------------------------------
// Pooling + heads
// ---------------------------------------------------------------------------
__global__ __launch_bounds__(256) void pool_logit(
    const float* __restrict__ h, const bf16* __restrict__ pw, const bf16* __restrict__ pb,
    float* __restrict__ logits)
{
  int n = blockIdx.x * 4 + (threadIdx.x >> 6); int lane = threadIdx.x & 63;
  float4 hv = load4(h + (size_t)n * 256 + lane * 4);
  float4 wv = load4(pw + lane * 4);
  float acc = wave_sum(hv.x*wv.x + hv.y*wv.y + hv.z*wv.z + hv.w*wv.w);
  if (lane == 0) logits[n] = acc + b2f(pb[0]);
}
__global__ __launch_bounds__(1024) void pool_reduce(
    const float* __restrict__ logits, float* __restrict__ red)
{
  __shared__ float sm[16];
  int t = threadIdx.x;
  float m = -1e30f;
  for (int i = t; i < N_NODES; i += 1024) m = fmaxf(m, logits[i]);
  m = wave_max(m);
  if ((t & 63) == 0) sm[t >> 6] = m;
  __syncthreads();
  if (t == 0) { float mm = sm[0]; for (int i = 1; i < 16; ++i) mm = fmaxf(mm, sm[i]); sm[0] = mm; }
  __syncthreads();
  float gmax = sm[0];
  __syncthreads();
  float s = 0.f;
  for (int i = t; i < N_NODES; i += 1024) s += expf(logits[i] - gmax);
  s = wave_sum(s);
  if ((t & 63) == 0) sm[t >> 6] = s;
  __syncthreads();
  if (t == 0) { float ss = 0.f; for (int i = 0; i < 16; ++i) ss += sm[i]; red[0] = gmax; red[1] = 1.0f / ss; }
}
__global__ __launch_bounds__(256) void pool_grep(
    const float* __restrict__ h, const float* __restrict__ logits,
    const float* __restrict__ red, float* __restrict__ g_rep)
{
  __shared__ float w[64];
  int g = blockIdx.x; int tid = threadIdx.x;
  if (tid < 64) w[tid] = expf(logits[g * 64 + tid] - red[0]) * red[1];
  __syncthreads();
  float acc = 0.f;
  for (int nd = 0; nd < 64; ++nd) acc += h[((size_t)g * 64 + nd) * 256 + tid] * w[nd];
  g_rep[(size_t)g * 256 + tid] = acc;
}
__global__ __launch_bounds__(256) void head_value(
    const float* __restrict__ vt, const bf16* __restrict__ w2, const bf16* __restrict__ b2,
    bf16* __restrict__ out)
{
  int gidx = blockIdx.x * 4 + (threadIdx.x >> 6); int lane = threadIdx.x & 63;
  float acc = 0.f;
  #pragma unroll
  for (int j = 0; j < 4; ++j) { int c = j * 64 + lane; acc += vt[(size_t)gidx * 256 + c] * b2f(w2[c]); }
  acc = wave_sum(acc);
  if (lane == 0) out[gidx] = f2b(tanhf(acc + b2f(b2[0])));
}
__global__ __launch_bounds__(256) void head_unc(
    const float* __restrict__ ut, const bf16* __restrict__ w2, const bf16* __restrict__ b2,
    bf16* __restrict__ out)
{
  int gidx = blockIdx.x * 4 + (threadIdx.x >> 6); int lane = threadIdx.x & 63;
  float acc = 0.f;
  #pragma unroll
  for (int j = 0; j < 2; ++j) { int c = j * 64 + lane; acc += ut[(size_t)gidx * 128 + c] * b2f(w2[c]); }
  acc = wave_sum(acc);
  if (lane == 0) {
    float x = acc + b2f(b2[0]);
    float sp = (x > 20.f) ? x : log1pf(expf(x));
    out[gidx] = f2b(sp);
  }
}

// ---------------------------------------------------------------------------
extern "C" void kernel_launch(void* const* d_in, const int* in_sizes, int n_in,
                              void* d_out, int out_size, void* d_ws, size_t ws_size,
                              hipStream_t stream)
{
  (void)out_size;
  const int* eidx = (const int*)d_in[1];

  char* ws = (char*)d_ws;
  size_t wo = 0;
  auto alloc = [&](size_t bytes) -> char* {
    char* p = ws + wo; wo += (bytes + 255) & ~(size_t)255; return p;
  };
  int*   flags = (int*)alloc(256);
  int*   cnt   = (int*)alloc((size_t)N_NODES * 4);
  int*   fillc = (int*)alloc((size_t)N_NODES * 4);
  size_t zero_end = wo;

  bf16* conv[38] = {};
  static const int fidx[35] = {0,4,5,6,7,8,9,10,11,12,13,14,15,16,17,18,19,
                               20,21,22,23,24,25,26,27,28,29,30,31,32,33,34,35,36,37};
  for (int j = 0; j < 35; ++j) {
    int idx = fidx[j];
    conv[idx] = (bf16*)alloc((size_t)in_sizes[idx] * 2);
  }
  float* h     = (float*)alloc((size_t)N_NODES * 256 * 4);   // 16 MB (f32 residual)
  bf16*  big   = (bf16*) alloc((size_t)N_NODES * 1024 * 2);  // 32 MB (hp / qkv+obuf / ffb)
  bf16*  tn    = (bf16*) alloc((size_t)N_NODES * 256 * 2);   // 8 MB
  float* al_s  = (float*)alloc((size_t)N_NODES * 4 * 4);
  float* al_d  = (float*)alloc((size_t)N_NODES * 4 * 4);
  int*   off   = (int*)alloc((size_t)(N_NODES + 1) * 4);
  int*   list  = (int*)alloc((size_t)NE2 * 4);
  float* logits= (float*)alloc((size_t)N_NODES * 4);
  float* redb  = (float*)alloc(256);
  float* g_rep = (float*)alloc((size_t)256 * 256 * 4);
  float* val_t = (float*)alloc((size_t)256 * 256 * 4);
  float* unc_t = (float*)alloc((size_t)256 * 128 * 4);
  const int OUT_ELEMS = 256 + N_NODES * 256 + 256;
  bf16*  ostage = (bf16*)alloc((size_t)OUT_ELEMS * 2);
  size_t needed = wo;

  if (n_in != 38)                   { write_sentinel<<<1,256,0,stream>>>((bf16*)d_out, 4.f);  return; }
  if (in_sizes[0] != N_NODES * 128) { write_sentinel<<<1,256,0,stream>>>((bf16*)d_out, 8.f);  return; }
  if (in_sizes[1] != 2 * NE)        { write_sentinel<<<1,256,0,stream>>>((bf16*)d_out, 16.f); return; }
  if (ws_size < needed)             { write_sentinel<<<1,256,0,stream>>>((bf16*)d_out, 32.f); return; }

  hipMemsetAsync(d_ws, 0, zero_end, stream);

  // dtype detect on x, then normalize every float tensor to bf16 (one kernel)
  detect_dtype<<<256, 256, 0, stream>>>((const unsigned short*)d_in[0], 65536, flags);
  {
    ConvArgs ca;
    int cum = 0;
    for (int j = 0; j < 35; ++j) {
      int idx = fidx[j];
      ca.src[j] = d_in[idx];
      ca.dst[j] = (unsigned short*)conv[idx];
      ca.cum[j] = cum;
      cum += in_sizes[idx];
    }
    ca.cum[35] = cum;
    conv_all<<<(cum + 255) / 256, 256, 0, stream>>>(ca, flags);
  }
  const bf16 *xb = conv[0], *emb_w = conv[4], *emb_b = conv[5], *gat_w = conv[6],
             *gat_as = conv[7], *gat_ad = conv[8], *gat_b = conv[9], *gnn_g = conv[10],
             *gnn_beta = conv[11], *ln1_g = conv[12], *ln1_b = conv[13], *in_w = conv[14],
             *in_b = conv[15], *out_w = conv[16], *out_b = conv[17], *ln2_g = conv[18],
             *ln2_b = conv[19], *ff1_w = conv[20], *ff1_b = conv[21], *ff2_w = conv[22],
             *ff2_b = conv[23], *pool_w = conv[24], *pool_b = conv[25],
             *vw1 = conv[26], *vb1 = conv[27], *vw2 = conv[28], *vb2 = conv[29],
             *pw1 = conv[30], *pb1 = conv[31], *pw2 = conv[32], *pb2 = conv[33],
             *uw1 = conv[34], *ub1 = conv[35], *uw2 = conv[36], *ub2 = conv[37];

  bf16* qkv  = big;                          // N x 768
  bf16* obuf = big + (size_t)N_NODES * 768;  // N x 256
  bf16* hp   = big;                          // N x 1024
  bf16* ffb  = big;                          // N x 1024
  bf16* o_val = ostage;
  bf16* o_pol = ostage + 256;
  bf16* o_unc = ostage + 256 + (size_t)N_NODES * 256;

  // CSR (cnt/fillc zeroed by memset)
  csr_count<<<(NE2 + 255) / 256, 256, 0, stream>>>(eidx + NE, cnt);
  csr_scan<<<1, 1024, 0, stream>>>(cnt, off);
  csr_fill<<<(NE2 + 255) / 256, 256, 0, stream>>>(eidx + NE, off, fillc, list);

  // Embedding
  gemm_mfma<bf16, float, 0><<<dim3(2, 128), 256, 0, stream>>>(
      xb, emb_w, emb_b, nullptr, h, N_NODES, 256, 128);

  // GNN layers
  for (int l = 0; l < 8; ++l) {
    gemm_mfma<float, bf16, 0><<<dim3(8, 128), 256, 0, stream>>>(
        h, gat_w + (size_t)l * 1024 * 256, nullptr, nullptr, hp, N_NODES, 1024, 256);
    gat_alsd<<<N_NODES / 4, 256, 0, stream>>>(hp, gat_as + l * 1024, gat_ad + l * 1024, al_s, al_d);
    gat_fused<<<N_NODES, 256, 0, stream>>>(eidx, hp, al_s, al_d, off, list,
        gat_b + l * 256, gnn_g + l * 256, gnn_beta + l * 256, h);
  }

  // Transformer layers
  for (int l = 0; l < 6; ++l) {
    ln_kernel<<<N_NODES / 4, 256, 0, stream>>>(h, tn, ln1_g + l * 256, ln1_b + l * 256);
    gemm_mfma<bf16, bf16, 0><<<dim3(6, 128), 256, 0, stream>>>(
        tn, in_w + (size_t)l * 768 * 256, in_b + l * 768, nullptr, qkv, N_NODES, 768, 256);
    attn_mfma<<<512, 256, 0, stream>>>(qkv, obuf);
    gemm_mfma<bf16, float, 2><<<dim3(2, 128), 256, 0, stream>>>(
        obuf, out_w + (size_t)l * 256 * 256, out_b + l * 256, h, h, N_NODES, 256, 256);
    ln_kernel<<<N_NODES / 4, 256, 0, stream>>>(h, tn, ln2_g + l * 256, ln2_b + l * 256);
    gemm_mfma<bf16, bf16, 1><<<dim3(8, 128), 256, 0, stream>>>(
        tn, ff1_w + (size_t)l * 1024 * 256, ff1_b + l * 1024, nullptr, ffb, N_NODES, 1024, 256);
    gemm_mfma<bf16, float, 2><<<dim3(2, 128), 256, 0, stream>>>(
        ffb, ff2_w + (size_t)l * 256 * 1024, ff2_b + l * 256, h, h, N_NODES, 256, 1024);
  }

  // Pooling + heads
  pool_logit<<<N_NODES / 4, 256, 0, stream>>>(h, pool_w, pool_b, logits);
  pool_reduce<<<1, 1024, 0, stream>>>(logits, redb);
  pool_grep<<<256, 256, 0, stream>>>(h, logits, redb, g_rep);
  gemm_mfma<float, float, 1><<<dim3(2, 2), 256, 0, stream>>>(
      g_rep, vw1, vb1, nullptr, val_t, 256, 256, 256);
  head_value<<<64, 256, 0, stream>>>(val_t, vw2, vb2, o_val);
  gemm_mfma<float, float, 1><<<dim3(1, 2), 256, 0, stream>>>(
      g_rep, uw1, ub1, nullptr, unc_t, 256, 128, 256);
  head_unc<<<64, 256, 0, stream>>>(unc_t, uw2, ub2, o_unc);
  gemm_mfma<float, bf16, 1><<<dim3(2, 128), 256, 0, stream>>>(
      h, pw1, pb1, nullptr, tn, N_NODES, 256, 256);
  gemm_mfma<bf16, bf16, 0><<<dim3(2, 128), 256, 0, stream>>>(
      tn, pw2, pb2, nullptr, o_pol, N_NODES, 256, 256);

  emit_out<<<(OUT_ELEMS + 255) / 256, 256, 0, stream>>>(
      (const unsigned short*)ostage, d_out, OUT_ELEMS, flags);
}

// Round 8
// 1880.342 us; speedup vs baseline: 4.1094x; 1.0460x over previous
//
#include <hip/hip_runtime.h>
#include <hip/hip_bf16.h>

typedef __hip_bfloat16 bf16;
typedef __bf16 bf16x8 __attribute__((ext_vector_type(8)));
typedef float  f32x4  __attribute__((ext_vector_type(4)));

#define N_NODES 16384
#define HDIM    256
#define NE      131072
#define NE2     147456   // NE + N self loops

__device__ __forceinline__ float b2f(bf16 v){ return __bfloat162float(v); }
__device__ __forceinline__ bf16  f2b(float v){ return __float2bfloat16(v); }
__device__ __forceinline__ float us2f(unsigned short u){
  union { unsigned int i; float f; } c; c.i = ((unsigned int)u) << 16; return c.f;
}
__device__ __forceinline__ unsigned short f2us(float f){
  bf16 h = __float2bfloat16(f);
  unsigned short u; __builtin_memcpy(&u, &h, 2); return u;
}
__device__ __forceinline__ float gelu_f(float x){
  return 0.5f * x * (1.0f + erff(x * 0.7071067811865476f));
}
__device__ __forceinline__ float wave_sum(float v){
  #pragma unroll
  for (int o = 32; o > 0; o >>= 1) v += __shfl_xor(v, o);
  return v;
}
__device__ __forceinline__ float wave_max(float v){
  #pragma unroll
  for (int o = 32; o > 0; o >>= 1) v = fmaxf(v, __shfl_xor(v, o));
  return v;
}

__device__ __forceinline__ float4 load4(const float* p){ return *(const float4*)p; }
__device__ __forceinline__ float4 load4(const bf16* p){
  ushort4 u = *(const ushort4*)p;
  return make_float4(us2f(u.x), us2f(u.y), us2f(u.z), us2f(u.w));
}
__device__ __forceinline__ void store4(float* p, float4 v){ *(float4*)p = v; }
__device__ __forceinline__ void store4(bf16* p, float4 v){
  ushort4 u = make_ushort4(f2us(v.x), f2us(v.y), f2us(v.z), f2us(v.w));
  *(ushort4*)p = u;
}
__device__ __forceinline__ void store_one(float* p, float v){ *p = v; }
__device__ __forceinline__ void store_one(bf16*  p, float v){ *p = f2b(v); }

// ---------------------------------------------------------------------------
// dtype detection + normalization.  flags[1] = input-is-f32
// ---------------------------------------------------------------------------
__global__ void detect_dtype(const unsigned short* __restrict__ x, int n, int* __restrict__ flags){
  int i = blockIdx.x * 256 + threadIdx.x;
  if (i < n) {
    unsigned short u = x[i];
    if ((u & 0x7F80) == 0x7F80) atomicOr(&flags[1], 1);  // bf16 NaN/Inf pattern
  }
}
struct ConvArgs {
  const void* src[35];
  unsigned short* dst[35];
  int cum[36];
};
__global__ void conv_all(ConvArgs a, const int* __restrict__ flags){
  int gi = blockIdx.x * 256 + threadIdx.x;
  if (gi >= a.cum[35]) return;
  int lo = 0, hi = 34;
  while (lo < hi) { int mid = (lo + hi + 1) >> 1; if (gi >= a.cum[mid]) lo = mid; else hi = mid - 1; }
  int off = gi - a.cum[lo];
  if (flags[1]) a.dst[lo][off] = f2us(((const float*)a.src[lo])[off]);
  else          a.dst[lo][off] = ((const unsigned short*)a.src[lo])[off];
}
__global__ void emit_out(const unsigned short* __restrict__ stage, void* __restrict__ out,
                         int n, const int* __restrict__ flags){
  int i = blockIdx.x * 256 + threadIdx.x;
  if (i >= n) return;
  if (flags[1]) ((float*)out)[i] = us2f(stage[i]);
  else          ((unsigned short*)out)[i] = stage[i];
}
__global__ void write_sentinel(bf16* out, float v){ out[threadIdx.x] = f2b(v); }

// ---------------------------------------------------------------------------
// MFMA bf16 NT GEMM: C[M,Nn] = A[M,K] * W[Nn,K]^T (+bias) (+epilogue)
// ---------------------------------------------------------------------------
#define LDT 40

__device__ __forceinline__ void stage16(const bf16* src, unsigned short* dst){
  uint4 a = *(const uint4*)src;
  uint4 b = *(const uint4*)(src + 8);
  *(uint4*)dst = a;
  *(uint4*)(dst + 8) = b;
}
__device__ __forceinline__ unsigned pack2(float lo, float hi){
  return (unsigned)f2us(lo) | ((unsigned)f2us(hi) << 16);
}
__device__ __forceinline__ void stage16(const float* src, unsigned short* dst){
  float4 v0 = *(const float4*)(src + 0);
  float4 v1 = *(const float4*)(src + 4);
  float4 v2 = *(const float4*)(src + 8);
  float4 v3 = *(const float4*)(src + 12);
  uint4 w0 = { pack2(v0.x, v0.y), pack2(v0.z, v0.w), pack2(v1.x, v1.y), pack2(v1.z, v1.w) };
  uint4 w1 = { pack2(v2.x, v2.y), pack2(v2.z, v2.w), pack2(v3.x, v3.y), pack2(v3.z, v3.w) };
  *(uint4*)dst = w0;
  *(uint4*)(dst + 8) = w1;
}

template<typename TA, typename TO, int EPI>
__global__ __launch_bounds__(256) void gemm_mfma(
    const TA* __restrict__ A, const bf16* __restrict__ W,
    const bf16* __restrict__ bias, const float* __restrict__ res,
    TO* __restrict__ C, int M, int Nn, int K)
{
  __shared__ unsigned short Asl[128 * LDT];
  __shared__ unsigned short Bsl[128 * LDT];
  const int tid  = threadIdx.x;
  const int wave = tid >> 6, lane = tid & 63;
  const int wm = wave & 1, wn = wave >> 1;
  const int quad = lane >> 4, l16 = lane & 15;
  const int row0 = blockIdx.y << 7, col0 = blockIdx.x << 7;
  const int srow = tid >> 1;
  const int scol = (tid & 1) << 4;

  f32x4 acc[4][4] = {};

  for (int kt = 0; kt < K; kt += 32) {
    stage16(A + (size_t)(row0 + srow) * K + kt + scol, &Asl[srow * LDT + scol]);
    stage16(W + (size_t)(col0 + srow) * K + kt + scol, &Bsl[srow * LDT + scol]);
    __syncthreads();
    bf16x8 af[4];
    #pragma unroll
    for (int i = 0; i < 4; ++i) {
      int m = (wm << 6) + (i << 4) + l16;
      af[i] = *(const bf16x8*)&Asl[m * LDT + (quad << 3)];
    }
    #pragma unroll
    for (int j = 0; j < 4; ++j) {
      int n = (wn << 6) + (j << 4) + l16;
      bf16x8 bfr = *(const bf16x8*)&Bsl[n * LDT + (quad << 3)];
      #pragma unroll
      for (int i = 0; i < 4; ++i)
        acc[i][j] = __builtin_amdgcn_mfma_f32_16x16x32_bf16(af[i], bfr, acc[i][j], 0, 0, 0);
    }
    __syncthreads();
  }

  #pragma unroll
  for (int j = 0; j < 4; ++j) {
    int col = col0 + (wn << 6) + (j << 4) + l16;
    float bv = bias ? b2f(bias[col]) : 0.f;
    #pragma unroll
    for (int i = 0; i < 4; ++i) {
      int rbase = row0 + (wm << 6) + (i << 4) + (quad << 2);
      #pragma unroll
      for (int r = 0; r < 4; ++r) {
        size_t base = (size_t)(rbase + r) * Nn + col;
        float v = acc[i][j][r] + bv;
        if (EPI == 1) v = gelu_f(v);
        if (EPI == 2) v += res[base];
        store_one(C + base, v);
      }
    }
  }
}

// ---------------------------------------------------------------------------
// CSR build over dst
// ---------------------------------------------------------------------------
__global__ void csr_count(const int* __restrict__ edst, int* __restrict__ cnt){
  int e = blockIdx.x * 256 + threadIdx.x;
  if (e < NE2) {
    int d = (e < NE) ? edst[e] : (e - NE);
    atomicAdd(&cnt[d], 1);
  }
}
__global__ __launch_bounds__(1024) void csr_scan(const int* __restrict__ cnt, int* __restrict__ off){
  __shared__ int ls[1024];
  int t = threadIdx.x;
  int base = t * 16;
  int loc[16]; int s = 0;
  #pragma unroll
  for (int j = 0; j < 16; ++j) { loc[j] = s; s += cnt[base + j]; }
  ls[t] = s;
  __syncthreads();
  for (int o = 1; o < 1024; o <<= 1) {
    int v = (t >= o) ? ls[t - o] : 0;
    __syncthreads();
    ls[t] += v;
    __syncthreads();
  }
  int pre = (t == 0) ? 0 : ls[t - 1];
  #pragma unroll
  for (int j = 0; j < 16; ++j) off[base + j] = pre + loc[j];
  if (t == 1023) off[N_NODES] = ls[1023];
}
__global__ void csr_fill(const int* __restrict__ edst, const int* __restrict__ off,
                         int* __restrict__ fillc, int* __restrict__ list){
  int e = blockIdx.x * 256 + threadIdx.x;
  if (e < NE2) {
    int d = (e < NE) ? edst[e] : (e - NE);
    int p = atomicAdd(&fillc[d], 1);
    list[off[d] + p] = e;
  }
}

// ---------------------------------------------------------------------------
// Graph-dense MFMA GAT layer: one block per graph (64 nodes).
// Per head: stage hp^T (LDS) + al dots in-pass; dense 64x64 alpha via
// per-dst max/exp (LDS atomicAdd handles multi-edges = segment_sum);
// alpha (bf16) x hp (64x256x64) via MFMA, accumulated over heads in C-frags.
// Epilogue: /4 + bias + LayerNorm + GELU + residual into h (f32).
// ---------------------------------------------------------------------------
#define HPT_S 72   // hp^T row stride (shorts): 144 B, 16B-aligned frags
#define AB_S  72   // alpha row stride (shorts)

__global__ __launch_bounds__(256) void gat_graph(
    const int* __restrict__ esrc, const bf16* __restrict__ hp,
    const int* __restrict__ off, const int* __restrict__ list,
    const bf16* __restrict__ a_s, const bf16* __restrict__ a_d,
    const bf16* __restrict__ bias, const bf16* __restrict__ gg, const bf16* __restrict__ gb,
    float* __restrict__ h)
{
  __shared__ __align__(16) unsigned short hpT[256 * HPT_S];   // [c][src] 36 KB
  __shared__ float alpha_f[64][64];                           // 16 KB
  __shared__ __align__(16) unsigned short alpha_b[64 * AB_S]; // 9 KB
  __shared__ float als[64], ald[64], dinv[64];
  __shared__ float lsum[64][4];
  __shared__ float mrow[64], rrow[64];

  const int g = blockIdx.x;
  const int tid = threadIdx.x;
  const int wave = tid >> 6, lane = tid & 63;
  const int quad = lane >> 4, l16 = lane & 15;
  const int s4 = tid >> 2;     // node/dst index 0..63 (4 threads per node)
  const int k4 = tid & 3;

  f32x4 acc[4][4] = {};

  for (int hd = 0; hd < 4; ++hd) {
    // --- stage hp^T for this head + al_s/al_d dot products in-pass ---
    {
      const bf16* hrow = hp + (((size_t)((g << 6) + s4)) * 4 + hd) * 256 + (k4 << 6);
      const bf16* asp = a_s + hd * 256 + (k4 << 6);
      const bf16* adp = a_d + hd * 256 + (k4 << 6);
      float s1 = 0.f, s2 = 0.f;
      #pragma unroll
      for (int jj = 0; jj < 64; jj += 8) {
        ushort4 u0 = *(const ushort4*)(hrow + jj);
        ushort4 u1 = *(const ushort4*)(hrow + jj + 4);
        unsigned short hv[8] = {u0.x, u0.y, u0.z, u0.w, u1.x, u1.y, u1.z, u1.w};
        #pragma unroll
        for (int t = 0; t < 8; ++t) {
          hpT[((k4 << 6) + jj + t) * HPT_S + s4] = hv[t];
          float hf = us2f(hv[t]);
          s1 += hf * b2f(asp[jj + t]);
          s2 += hf * b2f(adp[jj + t]);
        }
      }
      s1 += __shfl_xor(s1, 1); s1 += __shfl_xor(s1, 2);
      s2 += __shfl_xor(s2, 1); s2 += __shfl_xor(s2, 2);
      if (k4 == 0) { als[s4] = s1; ald[s4] = s2; }
    }
    // zero dense alpha
    #pragma unroll
    for (int idx = tid; idx < 4096; idx += 256) ((float*)alpha_f)[idx] = 0.f;
    __syncthreads();

    // --- edge softmax for dst=s4 (4 threads stride the CSR range) ---
    {
      int st = off[(g << 6) + s4];
      int deg = off[(g << 6) + s4 + 1] - st;
      float ad = ald[s4];
      float mx = -1e30f;
      for (int e = k4; e < deg; e += 4) {
        int ed = list[st + e];
        int sl = ((ed < NE) ? esrc[ed] : (ed - NE)) - (g << 6);
        float v = als[sl] + ad;
        v = (v > 0.f) ? v : 0.2f * v;
        mx = fmaxf(mx, v);
      }
      mx = fmaxf(mx, __shfl_xor(mx, 1)); mx = fmaxf(mx, __shfl_xor(mx, 2));
      float den = 0.f;
      for (int e = k4; e < deg; e += 4) {
        int ed = list[st + e];
        int sl = ((ed < NE) ? esrc[ed] : (ed - NE)) - (g << 6);
        float v = als[sl] + ad;
        v = (v > 0.f) ? v : 0.2f * v;
        float w = __expf(v - mx);
        den += w;
        atomicAdd(&alpha_f[s4][sl], w);
      }
      den += __shfl_xor(den, 1); den += __shfl_xor(den, 2);
      if (k4 == 0) dinv[s4] = 1.0f / den;
    }
    __syncthreads();

    // --- normalize alpha -> bf16 tile ---
    #pragma unroll
    for (int idx = tid; idx < 4096; idx += 256) {
      int m = idx >> 6, k = idx & 63;
      alpha_b[m * AB_S + k] = f2us(alpha_f[m][k] * dinv[m]);
    }
    __syncthreads();

    // --- MFMA: msg[64 x 256] += alpha[64 x 64] * hp[64 x 256]; wave w: cols 64w.. ---
    #pragma unroll
    for (int kk = 0; kk < 2; ++kk) {
      bf16x8 af[4];
      #pragma unroll
      for (int i = 0; i < 4; ++i)
        af[i] = *(const bf16x8*)&alpha_b[((i << 4) + l16) * AB_S + (kk << 5) + (quad << 3)];
      #pragma unroll
      for (int j = 0; j < 4; ++j) {
        bf16x8 bfr = *(const bf16x8*)&hpT[((wave << 6) + (j << 4) + l16) * HPT_S + (kk << 5) + (quad << 3)];
        #pragma unroll
        for (int i = 0; i < 4; ++i)
          acc[i][j] = __builtin_amdgcn_mfma_f32_16x16x32_bf16(af[i], bfr, acc[i][j], 0, 0, 0);
      }
    }
    __syncthreads();   // protect hpT/alpha before next head restages
  }

  // --- epilogue: /4 + bias, LayerNorm per dst row, GELU, residual ---
  #pragma unroll
  for (int j = 0; j < 4; ++j) {
    int col = (wave << 6) + (j << 4) + l16;
    float bcol = b2f(bias[col]);
    #pragma unroll
    for (int i = 0; i < 4; ++i)
      #pragma unroll
      for (int r = 0; r < 4; ++r)
        acc[i][j][r] = acc[i][j][r] * 0.25f + bcol;
  }
  #pragma unroll
  for (int i = 0; i < 4; ++i)
    #pragma unroll
    for (int r = 0; r < 4; ++r) {
      float s = acc[i][0][r] + acc[i][1][r] + acc[i][2][r] + acc[i][3][r];
      #pragma unroll
      for (int o = 1; o < 16; o <<= 1) s += __shfl_xor(s, o);
      if (l16 == 0) lsum[(i << 4) + (quad << 2) + r][wave] = s;
    }
  __syncthreads();
  if (tid < 64) mrow[tid] = (lsum[tid][0] + lsum[tid][1] + lsum[tid][2] + lsum[tid][3]) * (1.0f / 256.0f);
  __syncthreads();
  #pragma unroll
  for (int i = 0; i < 4; ++i)
    #pragma unroll
    for (int r = 0; r < 4; ++r) {
      float mean = mrow[(i << 4) + (quad << 2) + r];
      float s = 0.f;
      #pragma unroll
      for (int j = 0; j < 4; ++j) { float d = acc[i][j][r] - mean; s += d * d; }
      #pragma unroll
      for (int o = 1; o < 16; o <<= 1) s += __shfl_xor(s, o);
      if (l16 == 0) lsum[(i << 4) + (quad << 2) + r][wave] = s;
    }
  __syncthreads();
  if (tid < 64) rrow[tid] = rsqrtf((lsum[tid][0] + lsum[tid][1] + lsum[tid][2] + lsum[tid][3]) * (1.0f / 256.0f) + 1e-5f);
  __syncthreads();
  #pragma unroll
  for (int j = 0; j < 4; ++j) {
    int col = (wave << 6) + (j << 4) + l16;
    float gv = b2f(gg[col]), bv = b2f(gb[col]);
    #pragma unroll
    for (int i = 0; i < 4; ++i) {
      #pragma unroll
      for (int r = 0; r < 4; ++r) {
        int d = (i << 4) + (quad << 2) + r;
        float y = (acc[i][j][r] - mrow[d]) * rrow[d] * gv + bv;
        size_t idx = ((size_t)((g << 6) + d)) * 256 + col;
        h[idx] += gelu_f(y);
      }
    }
  }
}

// ---------------------------------------------------------------------------
// LayerNorm: wave-per-row (4 rows/block), f32 in, bf16 out
// ---------------------------------------------------------------------------
__global__ __launch_bounds__(256) void ln_kernel(
    const float* __restrict__ x, bf16* __restrict__ y,
    const bf16* __restrict__ g, const bf16* __restrict__ b)
{
  int row = blockIdx.x * 4 + (threadIdx.x >> 6);
  int lane = threadIdx.x & 63;
  int c = lane * 4;
  float4 v = load4(x + (size_t)row * 256 + c);
  float mean = wave_sum(v.x + v.y + v.z + v.w) * (1.0f / 256.0f);
  float dx = v.x - mean, dy = v.y - mean, dz = v.z - mean, dw = v.w - mean;
  float var = wave_sum(dx*dx + dy*dy + dz*dz + dw*dw) * (1.0f / 256.0f);
  float r = rsqrtf(var + 1e-5f);
  float4 gv = load4(g + c); float4 bv = load4(b + c);
  store4(y + (size_t)row * 256 + c,
         make_float4(dx*r*gv.x + bv.x, dy*r*gv.y + bv.y, dz*r*gv.z + bv.z, dw*r*gv.w + bv.w));
}

// ---------------------------------------------------------------------------
// MFMA flash-style attention (unchanged from round 7)
// ---------------------------------------------------------------------------
#define VT_LDS 268
#define P_LDS  72

__global__ __launch_bounds__(256) void attn_mfma(
    const bf16* __restrict__ qkv, bf16* __restrict__ obuf)
{
  const int b  = blockIdx.x & 63;
  const int hh = blockIdx.x >> 6;
  __shared__ unsigned short VTs[32 * VT_LDS];
  __shared__ unsigned short Ps[4][64 * P_LDS];
  const int tid  = threadIdx.x;
  const int wave = tid >> 6, lane = tid & 63;
  const int quad = lane >> 4, l16 = lane & 15;

  {
    const bf16* vb = qkv + (size_t)(tid * 64 + b) * 768 + 512 + hh * 32;
    unsigned short vv[32];
    *(uint4*)&vv[0]  = *(const uint4*)(vb);
    *(uint4*)&vv[8]  = *(const uint4*)(vb + 8);
    *(uint4*)&vv[16] = *(const uint4*)(vb + 16);
    *(uint4*)&vv[24] = *(const uint4*)(vb + 24);
    #pragma unroll
    for (int d = 0; d < 32; ++d) VTs[d * VT_LDS + tid] = vv[d];
  }
  bf16x8 qf[4];
  #pragma unroll
  for (int i = 0; i < 4; ++i) {
    int s = (wave << 6) + (i << 4) + l16;
    qf[i] = *(const bf16x8*)(qkv + (size_t)(s * 64 + b) * 768 + hh * 32 + (quad << 3));
  }
  __syncthreads();

  const float scale = 0.17677669529663687f;
  f32x4 oacc[4][2] = {};
  float lsum[4][4] = {};
  unsigned short* Pw = &Ps[wave][0];

  for (int nt = 0; nt < 4; ++nt) {
    bf16x8 kf[4];
    #pragma unroll
    for (int j = 0; j < 4; ++j) {
      int t = (nt << 6) + (j << 4) + l16;
      kf[j] = *(const bf16x8*)(qkv + (size_t)(t * 64 + b) * 768 + 256 + hh * 32 + (quad << 3));
    }
    f32x4 zero = {0.f, 0.f, 0.f, 0.f};
    f32x4 sx[4][4];
    #pragma unroll
    for (int i = 0; i < 4; ++i)
      #pragma unroll
      for (int j = 0; j < 4; ++j)
        sx[i][j] = __builtin_amdgcn_mfma_f32_16x16x32_bf16(qf[i], kf[j], zero, 0, 0, 0);
    #pragma unroll
    for (int i = 0; i < 4; ++i) {
      #pragma unroll
      for (int r = 0; r < 4; ++r) {
        float p[4]; float rs = 0.f;
        #pragma unroll
        for (int j = 0; j < 4; ++j) {
          float sc = fminf(fmaxf(sx[i][j][r] * scale, -60.f), 60.f);
          p[j] = __expf(sc);
          rs += p[j];
        }
        #pragma unroll
        for (int o = 1; o < 16; o <<= 1) rs += __shfl_xor(rs, o);
        lsum[i][r] += rs;
        int row = (i << 4) + (quad << 2) + r;
        #pragma unroll
        for (int j = 0; j < 4; ++j)
          Pw[row * P_LDS + (j << 4) + l16] = f2us(p[j]);
      }
    }
    #pragma unroll
    for (int kk = 0; kk < 2; ++kk) {
      bf16x8 vf[2];
      #pragma unroll
      for (int j2 = 0; j2 < 2; ++j2)
        vf[j2] = *(const bf16x8*)&VTs[((j2 << 4) + l16) * VT_LDS + (nt << 6) + (kk << 5) + (quad << 3)];
      #pragma unroll
      for (int i2 = 0; i2 < 4; ++i2) {
        bf16x8 pf = *(const bf16x8*)&Pw[((i2 << 4) + l16) * P_LDS + (kk << 5) + (quad << 3)];
        #pragma unroll
        for (int j2 = 0; j2 < 2; ++j2)
          oacc[i2][j2] = __builtin_amdgcn_mfma_f32_16x16x32_bf16(pf, vf[j2], oacc[i2][j2], 0, 0, 0);
      }
    }
  }
  #pragma unroll
  for (int i = 0; i < 4; ++i) {
    #pragma unroll
    for (int r = 0; r < 4; ++r) {
      int srow = (wave << 6) + (i << 4) + (quad << 2) + r;
      float inv = 1.0f / lsum[i][r];
      #pragma unroll
      for (int j2 = 0; j2 < 2; ++j2)
        obuf[(size_t)(srow * 64 + b) * 256 + hh * 32 + (j2 << 4) + l16] = f2b(oacc[i][j2][r] * inv);
    }
  }
}

// ---------------------------------------------------------------------------
// Pooling + heads
// ---------------------------------------------------------------------------
__global__ __launch_bounds__(256) void pool_logit(
    const float* __restrict__ h, const bf16* __restrict__ pw, const bf16* __restrict__ pb,
    float* __restrict__ logits)
{
  int n = blockIdx.x * 4 + (threadIdx.x >> 6); int lane = threadIdx.x & 63;
  float4 hv = load4(h + (size_t)n * 256 + lane * 4);
  float4 wv = load4(pw + lane * 4);
  float acc = wave_sum(hv.x*wv.x + hv.y*wv.y + hv.z*wv.z + hv.w*wv.w);
  if (lane == 0) logits[n] = acc + b2f(pb[0]);
}
__global__ __launch_bounds__(1024) void pool_reduce(
    const float* __restrict__ logits, float* __restrict__ red)
{
  __shared__ float sm[16];
  int t = threadIdx.x;
  float m = -1e30f;
  for (int i = t; i < N_NODES; i += 1024) m = fmaxf(m, logits[i]);
  m = wave_max(m);
  if ((t & 63) == 0) sm[t >> 6] = m;
  __syncthreads();
  if (t == 0) { float mm = sm[0]; for (int i = 1; i < 16; ++i) mm = fmaxf(mm, sm[i]); sm[0] = mm; }
  __syncthreads();
  float gmax = sm[0];
  __syncthreads();
  float s = 0.f;
  for (int i = t; i < N_NODES; i += 1024) s += expf(logits[i] - gmax);
  s = wave_sum(s);
  if ((t & 63) == 0) sm[t >> 6] = s;
  __syncthreads();
  if (t == 0) { float ss = 0.f; for (int i = 0; i < 16; ++i) ss += sm[i]; red[0] = gmax; red[1] = 1.0f / ss; }
}
__global__ __launch_bounds__(256) void pool_grep(
    const float* __restrict__ h, const float* __restrict__ logits,
    const float* __restrict__ red, float* __restrict__ g_rep)
{
  __shared__ float w[64];
  int g = blockIdx.x; int tid = threadIdx.x;
  if (tid < 64) w[tid] = expf(logits[g * 64 + tid] - red[0]) * red[1];
  __syncthreads();
  float acc = 0.f;
  for (int nd = 0; nd < 64; ++nd) acc += h[((size_t)g * 64 + nd) * 256 + tid] * w[nd];
  g_rep[(size_t)g * 256 + tid] = acc;
}
__global__ __launch_bounds__(256) void head_value(
    const float* __restrict__ vt, const bf16* __restrict__ w2, const bf16* __restrict__ b2,
    bf16* __restrict__ out)
{
  int gidx = blockIdx.x * 4 + (threadIdx.x >> 6); int lane = threadIdx.x & 63;
  float acc = 0.f;
  #pragma unroll
  for (int j = 0; j < 4; ++j) { int c = j * 64 + lane; acc += vt[(size_t)gidx * 256 + c] * b2f(w2[c]); }
  acc = wave_sum(acc);
  if (lane == 0) out[gidx] = f2b(tanhf(acc + b2f(b2[0])));
}
__global__ __launch_bounds__(256) void head_unc(
    const float* __restrict__ ut, const bf16* __restrict__ w2, const bf16* __restrict__ b2,
    bf16* __restrict__ out)
{
  int gidx = blockIdx.x * 4 + (threadIdx.x >> 6); int lane = threadIdx.x & 63;
  float acc = 0.f;
  #pragma unroll
  for (int j = 0; j < 2; ++j) { int c = j * 64 + lane; acc += ut[(size_t)gidx * 128 + c] * b2f(w2[c]); }
  acc = wave_sum(acc);
  if (lane == 0) {
    float x = acc + b2f(b2[0]);
    float sp = (x > 20.f) ? x : log1pf(expf(x));
    out[gidx] = f2b(sp);
  }
}

// ---------------------------------------------------------------------------
extern "C" void kernel_launch(void* const* d_in, const int* in_sizes, int n_in,
                              void* d_out, int out_size, void* d_ws, size_t ws_size,
                              hipStream_t stream)
{
  (void)out_size;
  const int* eidx = (const int*)d_in[1];

  char* ws = (char*)d_ws;
  size_t wo = 0;
  auto alloc = [&](size_t bytes) -> char* {
    char* p = ws + wo; wo += (bytes + 255) & ~(size_t)255; return p;
  };
  int*   flags = (int*)alloc(256);
  int*   cnt   = (int*)alloc((size_t)N_NODES * 4);
  int*   fillc = (int*)alloc((size_t)N_NODES * 4);
  size_t zero_end = wo;

  bf16* conv[38] = {};
  static const int fidx[35] = {0,4,5,6,7,8,9,10,11,12,13,14,15,16,17,18,19,
                               20,21,22,23,24,25,26,27,28,29,30,31,32,33,34,35,36,37};
  for (int j = 0; j < 35; ++j) {
    int idx = fidx[j];
    conv[idx] = (bf16*)alloc((size_t)in_sizes[idx] * 2);
  }
  float* h     = (float*)alloc((size_t)N_NODES * 256 * 4);
  bf16*  big   = (bf16*) alloc((size_t)N_NODES * 1024 * 2);
  bf16*  tn    = (bf16*) alloc((size_t)N_NODES * 256 * 2);
  int*   off   = (int*)alloc((size_t)(N_NODES + 1) * 4);
  int*   list  = (int*)alloc((size_t)NE2 * 4);
  float* logits= (float*)alloc((size_t)N_NODES * 4);
  float* redb  = (float*)alloc(256);
  float* g_rep = (float*)alloc((size_t)256 * 256 * 4);
  float* val_t = (float*)alloc((size_t)256 * 256 * 4);
  float* unc_t = (float*)alloc((size_t)256 * 128 * 4);
  const int OUT_ELEMS = 256 + N_NODES * 256 + 256;
  bf16*  ostage = (bf16*)alloc((size_t)OUT_ELEMS * 2);
  size_t needed = wo;

  if (n_in != 38)                   { write_sentinel<<<1,256,0,stream>>>((bf16*)d_out, 4.f);  return; }
  if (in_sizes[0] != N_NODES * 128) { write_sentinel<<<1,256,0,stream>>>((bf16*)d_out, 8.f);  return; }
  if (in_sizes[1] != 2 * NE)        { write_sentinel<<<1,256,0,stream>>>((bf16*)d_out, 16.f); return; }
  if (ws_size < needed)             { write_sentinel<<<1,256,0,stream>>>((bf16*)d_out, 32.f); return; }

  hipMemsetAsync(d_ws, 0, zero_end, stream);

  detect_dtype<<<256, 256, 0, stream>>>((const unsigned short*)d_in[0], 65536, flags);
  {
    ConvArgs ca;
    int cum = 0;
    for (int j = 0; j < 35; ++j) {
      int idx = fidx[j];
      ca.src[j] = d_in[idx];
      ca.dst[j] = (unsigned short*)conv[idx];
      ca.cum[j] = cum;
      cum += in_sizes[idx];
    }
    ca.cum[35] = cum;
    conv_all<<<(cum + 255) / 256, 256, 0, stream>>>(ca, flags);
  }
  const bf16 *xb = conv[0], *emb_w = conv[4], *emb_b = conv[5], *gat_w = conv[6],
             *gat_as = conv[7], *gat_ad = conv[8], *gat_b = conv[9], *gnn_g = conv[10],
             *gnn_beta = conv[11], *ln1_g = conv[12], *ln1_b = conv[13], *in_w = conv[14],
             *in_b = conv[15], *out_w = conv[16], *out_b = conv[17], *ln2_g = conv[18],
             *ln2_b = conv[19], *ff1_w = conv[20], *ff1_b = conv[21], *ff2_w = conv[22],
             *ff2_b = conv[23], *pool_w = conv[24], *pool_b = conv[25],
             *vw1 = conv[26], *vb1 = conv[27], *vw2 = conv[28], *vb2 = conv[29],
             *pw1 = conv[30], *pb1 = conv[31], *pw2 = conv[32], *pb2 = conv[33],
             *uw1 = conv[34], *ub1 = conv[35], *uw2 = conv[36], *ub2 = conv[37];

  bf16* qkv  = big;
  bf16* obuf = big + (size_t)N_NODES * 768;
  bf16* hp   = big;
  bf16* ffb  = big;
  bf16* o_val = ostage;
  bf16* o_pol = ostage + 256;
  bf16* o_unc = ostage + 256 + (size_t)N_NODES * 256;

  csr_count<<<(NE2 + 255) / 256, 256, 0, stream>>>(eidx + NE, cnt);
  csr_scan<<<1, 1024, 0, stream>>>(cnt, off);
  csr_fill<<<(NE2 + 255) / 256, 256, 0, stream>>>(eidx + NE, off, fillc, list);

  gemm_mfma<bf16, float, 0><<<dim3(2, 128), 256, 0, stream>>>(
      xb, emb_w, emb_b, nullptr, h, N_NODES, 256, 128);

  for (int l = 0; l < 8; ++l) {
    gemm_mfma<float, bf16, 0><<<dim3(8, 128), 256, 0, stream>>>(
        h, gat_w + (size_t)l * 1024 * 256, nullptr, nullptr, hp, N_NODES, 1024, 256);
    gat_graph<<<256, 256, 0, stream>>>(eidx, hp, off, list,
        gat_as + l * 1024, gat_ad + l * 1024,
        gat_b + l * 256, gnn_g + l * 256, gnn_beta + l * 256, h);
  }

  for (int l = 0; l < 6; ++l) {
    ln_kernel<<<N_NODES / 4, 256, 0, stream>>>(h, tn, ln1_g + l * 256, ln1_b + l * 256);
    gemm_mfma<bf16, bf16, 0><<<dim3(6, 128), 256, 0, stream>>>(
        tn, in_w + (size_t)l * 768 * 256, in_b + l * 768, nullptr, qkv, N_NODES, 768, 256);
    attn_mfma<<<512, 256, 0, stream>>>(qkv, obuf);
    gemm_mfma<bf16, float, 2><<<dim3(2, 128), 256, 0, stream>>>(
        obuf, out_w + (size_t)l * 256 * 256, out_b + l * 256, h, h, N_NODES, 256, 256);
    ln_kernel<<<N_NODES / 4, 256, 0, stream>>>(h, tn, ln2_g + l * 256, ln2_b + l * 256);
    gemm_mfma<bf16, bf16, 1><<<dim3(8, 128), 256, 0, stream>>>(
        tn, ff1_w + (size_t)l * 1024 * 256, ff1_b + l * 1024, nullptr, ffb, N_NODES, 1024, 256);
    gemm_mfma<bf16, float, 2><<<dim3(2, 128), 256, 0, stream>>>(
        ffb, ff2_w + (size_t)l * 256 * 1024, ff2_b + l * 256, h, h, N_NODES, 256, 1024);
  }

  pool_logit<<<N_NODES / 4, 256, 0, stream>>>(h, pool_w, pool_b, logits);
  pool_reduce<<<1, 1024, 0, stream>>>(logits, redb);
  pool_grep<<<256, 256, 0, stream>>>(h, logits, redb, g_rep);
  gemm_mfma<float, float, 1><<<dim3(2, 2), 256, 0, stream>>>(
      g_rep, vw1, vb1, nullptr, val_t, 256, 256, 256);
  head_value<<<64, 256, 0, stream>>>(val_t, vw2, vb2, o_val);
  gemm_mfma<float, float, 1><<<dim3(1, 2), 256, 0, stream>>>(
      g_rep, uw1, ub1, nullptr, unc_t, 256, 128, 256);
  head_unc<<<64, 256, 0, stream>>>(unc_t, uw2, ub2, o_unc);
  gemm_mfma<float, bf16, 1><<<dim3(2, 128), 256, 0, stream>>>(
      h, pw1, pb1, nullptr, tn, N_NODES, 256, 256);
  gemm_mfma<bf16, bf16, 0><<<dim3(2, 128), 256, 0, stream>>>(
      tn, pw2, pb2, nullptr, o_pol, N_NODES, 256, 256);

  emit_out<<<(OUT_ELEMS + 255) / 256, 256, 0, stream>>>(
      (const unsigned short*)ostage, d_out, OUT_ELEMS, flags);
}

// Round 9
// 1876.616 us; speedup vs baseline: 4.1176x; 1.0020x over previous
//
#include <hip/hip_runtime.h>
#include <hip/hip_bf16.h>

typedef __hip_bfloat16 bf16;
typedef __bf16 bf16x8 __attribute__((ext_vector_type(8)));
typedef float  f32x4  __attribute__((ext_vector_type(4)));

#define N_NODES 16384
#define HDIM    256
#define NE      131072
#define NE2     147456   // NE + N self loops

__device__ __forceinline__ float b2f(bf16 v){ return __bfloat162float(v); }
__device__ __forceinline__ bf16  f2b(float v){ return __float2bfloat16(v); }
__device__ __forceinline__ float us2f(unsigned short u){
  union { unsigned int i; float f; } c; c.i = ((unsigned int)u) << 16; return c.f;
}
__device__ __forceinline__ unsigned short f2us(float f){
  bf16 h = __float2bfloat16(f);
  unsigned short u; __builtin_memcpy(&u, &h, 2); return u;
}
__device__ __forceinline__ float gelu_f(float x){
  return 0.5f * x * (1.0f + erff(x * 0.7071067811865476f));
}
__device__ __forceinline__ float wave_sum(float v){
  #pragma unroll
  for (int o = 32; o > 0; o >>= 1) v += __shfl_xor(v, o);
  return v;
}
__device__ __forceinline__ float wave_max(float v){
  #pragma unroll
  for (int o = 32; o > 0; o >>= 1) v = fmaxf(v, __shfl_xor(v, o));
  return v;
}

__device__ __forceinline__ float4 load4(const float* p){ return *(const float4*)p; }
__device__ __forceinline__ float4 load4(const bf16* p){
  ushort4 u = *(const ushort4*)p;
  return make_float4(us2f(u.x), us2f(u.y), us2f(u.z), us2f(u.w));
}
__device__ __forceinline__ void store4(float* p, float4 v){ *(float4*)p = v; }
__device__ __forceinline__ void store4(bf16* p, float4 v){
  ushort4 u = make_ushort4(f2us(v.x), f2us(v.y), f2us(v.z), f2us(v.w));
  *(ushort4*)p = u;
}
__device__ __forceinline__ void store_one(float* p, float v){ *p = v; }
__device__ __forceinline__ void store_one(bf16*  p, float v){ *p = f2b(v); }

// ---------------------------------------------------------------------------
// dtype detection + normalization.  flags[1] = input-is-f32
// ---------------------------------------------------------------------------
__global__ void detect_dtype(const unsigned short* __restrict__ x, int n, int* __restrict__ flags){
  int i = blockIdx.x * 256 + threadIdx.x;
  if (i < n) {
    unsigned short u = x[i];
    if ((u & 0x7F80) == 0x7F80) atomicOr(&flags[1], 1);  // bf16 NaN/Inf pattern
  }
}
struct ConvArgs {
  const void* src[35];
  unsigned short* dst[35];
  int cumg[36];   // cumulative 4-element groups
  int n[35];
};
__global__ void conv_all4(ConvArgs a, const int* __restrict__ flags){
  int gi = blockIdx.x * 256 + threadIdx.x;
  if (gi >= a.cumg[35]) return;
  int lo = 0, hi = 34;
  while (lo < hi) { int mid = (lo + hi + 1) >> 1; if (gi >= a.cumg[mid]) lo = mid; else hi = mid - 1; }
  int e0 = (gi - a.cumg[lo]) << 2;
  int n = a.n[lo];
  unsigned short* d = a.dst[lo];
  if (flags[1]) {
    const float* s = (const float*)a.src[lo];
    if (e0 + 4 <= n) {
      float4 v = *(const float4*)(s + e0);
      ushort4 o = make_ushort4(f2us(v.x), f2us(v.y), f2us(v.z), f2us(v.w));
      *(ushort4*)(d + e0) = o;
    } else {
      for (int t = 0; t < n - e0; ++t) d[e0 + t] = f2us(s[e0 + t]);
    }
  } else {
    const unsigned short* s = (const unsigned short*)a.src[lo];
    if (e0 + 4 <= n) *(ushort4*)(d + e0) = *(const ushort4*)(s + e0);
    else for (int t = 0; t < n - e0; ++t) d[e0 + t] = s[e0 + t];
  }
}
__global__ void emit_out(const unsigned short* __restrict__ stage, void* __restrict__ out,
                         int n, const int* __restrict__ flags){
  int i = blockIdx.x * 256 + threadIdx.x;
  if (i >= n) return;
  if (flags[1]) ((float*)out)[i] = us2f(stage[i]);
  else          ((unsigned short*)out)[i] = stage[i];
}
__global__ void write_sentinel(bf16* out, float v){ out[threadIdx.x] = f2b(v); }

// ---------------------------------------------------------------------------
// MFMA bf16 NT GEMM: C[M,Nn] = A[M,K] * W[Nn,K]^T (+bias) (+epilogue)
// ---------------------------------------------------------------------------
#define LDT 40

__device__ __forceinline__ void stage16(const bf16* src, unsigned short* dst){
  uint4 a = *(const uint4*)src;
  uint4 b = *(const uint4*)(src + 8);
  *(uint4*)dst = a;
  *(uint4*)(dst + 8) = b;
}
__device__ __forceinline__ unsigned pack2(float lo, float hi){
  return (unsigned)f2us(lo) | ((unsigned)f2us(hi) << 16);
}
__device__ __forceinline__ void stage16(const float* src, unsigned short* dst){
  float4 v0 = *(const float4*)(src + 0);
  float4 v1 = *(const float4*)(src + 4);
  float4 v2 = *(const float4*)(src + 8);
  float4 v3 = *(const float4*)(src + 12);
  uint4 w0 = { pack2(v0.x, v0.y), pack2(v0.z, v0.w), pack2(v1.x, v1.y), pack2(v1.z, v1.w) };
  uint4 w1 = { pack2(v2.x, v2.y), pack2(v2.z, v2.w), pack2(v3.x, v3.y), pack2(v3.z, v3.w) };
  *(uint4*)dst = w0;
  *(uint4*)(dst + 8) = w1;
}

template<typename TA, typename TO, int EPI>
__global__ __launch_bounds__(256) void gemm_mfma(
    const TA* __restrict__ A, const bf16* __restrict__ W,
    const bf16* __restrict__ bias, const float* __restrict__ res,
    TO* __restrict__ C, int M, int Nn, int K)
{
  __shared__ unsigned short Asl[128 * LDT];
  __shared__ unsigned short Bsl[128 * LDT];
  const int tid  = threadIdx.x;
  const int wave = tid >> 6, lane = tid & 63;
  const int wm = wave & 1, wn = wave >> 1;
  const int quad = lane >> 4, l16 = lane & 15;
  const int row0 = blockIdx.y << 7, col0 = blockIdx.x << 7;
  const int srow = tid >> 1;
  const int scol = (tid & 1) << 4;

  f32x4 acc[4][4] = {};

  for (int kt = 0; kt < K; kt += 32) {
    stage16(A + (size_t)(row0 + srow) * K + kt + scol, &Asl[srow * LDT + scol]);
    stage16(W + (size_t)(col0 + srow) * K + kt + scol, &Bsl[srow * LDT + scol]);
    __syncthreads();
    bf16x8 af[4];
    #pragma unroll
    for (int i = 0; i < 4; ++i) {
      int m = (wm << 6) + (i << 4) + l16;
      af[i] = *(const bf16x8*)&Asl[m * LDT + (quad << 3)];
    }
    #pragma unroll
    for (int j = 0; j < 4; ++j) {
      int n = (wn << 6) + (j << 4) + l16;
      bf16x8 bfr = *(const bf16x8*)&Bsl[n * LDT + (quad << 3)];
      #pragma unroll
      for (int i = 0; i < 4; ++i)
        acc[i][j] = __builtin_amdgcn_mfma_f32_16x16x32_bf16(af[i], bfr, acc[i][j], 0, 0, 0);
    }
    __syncthreads();
  }

  #pragma unroll
  for (int j = 0; j < 4; ++j) {
    int col = col0 + (wn << 6) + (j << 4) + l16;
    float bv = bias ? b2f(bias[col]) : 0.f;
    #pragma unroll
    for (int i = 0; i < 4; ++i) {
      int rbase = row0 + (wm << 6) + (i << 4) + (quad << 2);
      #pragma unroll
      for (int r = 0; r < 4; ++r) {
        size_t base = (size_t)(rbase + r) * Nn + col;
        float v = acc[i][j][r] + bv;
        if (EPI == 1) v = gelu_f(v);
        if (EPI == 2) v += res[base];
        store_one(C + base, v);
      }
    }
  }
}

// ---------------------------------------------------------------------------
// CSR build over dst
// ---------------------------------------------------------------------------
__global__ void csr_count(const int* __restrict__ edst, int* __restrict__ cnt){
  int e = blockIdx.x * 256 + threadIdx.x;
  if (e < NE2) {
    int d = (e < NE) ? edst[e] : (e - NE);
    atomicAdd(&cnt[d], 1);
  }
}
__global__ __launch_bounds__(1024) void csr_scan(const int* __restrict__ cnt, int* __restrict__ off){
  __shared__ int ls[1024];
  int t = threadIdx.x;
  int base = t * 16;
  int loc[16]; int s = 0;
  #pragma unroll
  for (int j = 0; j < 16; ++j) { loc[j] = s; s += cnt[base + j]; }
  ls[t] = s;
  __syncthreads();
  for (int o = 1; o < 1024; o <<= 1) {
    int v = (t >= o) ? ls[t - o] : 0;
    __syncthreads();
    ls[t] += v;
    __syncthreads();
  }
  int pre = (t == 0) ? 0 : ls[t - 1];
  #pragma unroll
  for (int j = 0; j < 16; ++j) off[base + j] = pre + loc[j];
  if (t == 1023) off[N_NODES] = ls[1023];
}
__global__ void csr_fill(const int* __restrict__ edst, const int* __restrict__ off,
                         int* __restrict__ fillc, int* __restrict__ list){
  int e = blockIdx.x * 256 + threadIdx.x;
  if (e < NE2) {
    int d = (e < NE) ? edst[e] : (e - NE);
    int p = atomicAdd(&fillc[d], 1);
    list[off[d] + p] = e;
  }
}

// ---------------------------------------------------------------------------
// GAT per-(graph,head) block: stage hpT (XOR-swizzled, 32 KB) + al dots,
// dense 64x64 alpha (LDS f32, atomicAdd = segment_sum), MFMA alpha x hp,
// per-head msg (bf16) -> msg4[hd][hn][256]. hd = blockIdx.x & 3.
// ---------------------------------------------------------------------------
#define ALF_S 68

__device__ __forceinline__ bf16x8 pack8(const float* v, float scale){
  unsigned short u[8];
  #pragma unroll
  for (int t = 0; t < 8; ++t) u[t] = f2us(v[t] * scale);
  bf16x8 r; __builtin_memcpy(&r, u, 16); return r;
}

__global__ __launch_bounds__(256) void gat_graph2(
    const int* __restrict__ esrc, const bf16* __restrict__ hp,
    const int* __restrict__ off, const int* __restrict__ list,
    const bf16* __restrict__ a_s, const bf16* __restrict__ a_d,
    bf16* __restrict__ msg4, int g0, int hn)
{
  __shared__ unsigned short hpT[256 * 64];   // [c][src], XOR-swizzled chunks: 32 KB
  __shared__ float alpha[64 * ALF_S];        // 17 KB (padded rows)
  __shared__ float als[64], ald[64], dinv[64];

  const int hd = blockIdx.x & 3;
  const int lg = blockIdx.x >> 2;
  const int g  = g0 + lg;
  const int tid = threadIdx.x;
  const int wave = tid >> 6, lane = tid & 63;
  const int quad = lane >> 4, l16 = lane & 15;
  const int nd = tid >> 2;     // node index 0..63 (src in staging, dst in softmax)
  const int k4 = tid & 3;

  // --- stage hpT for this head + al_s/al_d dots in-pass ---
  {
    const bf16* hrow = hp + ((size_t)((g << 6) + nd)) * 1024 + hd * 256 + (k4 << 6);
    const bf16* asp = a_s + hd * 256 + (k4 << 6);
    const bf16* adp = a_d + hd * 256 + (k4 << 6);
    const int s3 = nd >> 3, s7 = nd & 7;
    float s1 = 0.f, s2 = 0.f;
    #pragma unroll
    for (int jj = 0; jj < 64; jj += 8) {
      ushort4 u0 = *(const ushort4*)(hrow + jj);
      ushort4 u1 = *(const ushort4*)(hrow + jj + 4);
      unsigned short hv[8] = {u0.x, u0.y, u0.z, u0.w, u1.x, u1.y, u1.z, u1.w};
      #pragma unroll
      for (int t = 0; t < 8; ++t) {
        int c = (k4 << 6) + jj + t;
        hpT[(c << 6) + (((s3 ^ (c & 7)) << 3) | s7)] = hv[t];
        float hf = us2f(hv[t]);
        s1 += hf * b2f(asp[jj + t]);
        s2 += hf * b2f(adp[jj + t]);
      }
    }
    s1 += __shfl_xor(s1, 1); s1 += __shfl_xor(s1, 2);
    s2 += __shfl_xor(s2, 1); s2 += __shfl_xor(s2, 2);
    if (k4 == 0) { als[nd] = s1; ald[nd] = s2; }
  }
  // zero alpha (incl. pad)
  #pragma unroll
  for (int idx = tid; idx < 64 * ALF_S; idx += 256) alpha[idx] = 0.f;
  __syncthreads();

  // --- edge softmax for dst=nd (4 threads stride the CSR range) ---
  {
    int st = off[(g << 6) + nd];
    int deg = off[(g << 6) + nd + 1] - st;
    float ad = ald[nd];
    float mx = -1e30f;
    for (int e = k4; e < deg; e += 4) {
      int ed = list[st + e];
      int sl = ((ed < NE) ? esrc[ed] : (ed - NE)) - (g << 6);
      float v = als[sl] + ad;
      v = (v > 0.f) ? v : 0.2f * v;
      mx = fmaxf(mx, v);
    }
    mx = fmaxf(mx, __shfl_xor(mx, 1)); mx = fmaxf(mx, __shfl_xor(mx, 2));
    float den = 0.f;
    for (int e = k4; e < deg; e += 4) {
      int ed = list[st + e];
      int sl = ((ed < NE) ? esrc[ed] : (ed - NE)) - (g << 6);
      float v = als[sl] + ad;
      v = (v > 0.f) ? v : 0.2f * v;
      float w = __expf(v - mx);
      den += w;
      atomicAdd(&alpha[nd * ALF_S + sl], w);
    }
    den += __shfl_xor(den, 1); den += __shfl_xor(den, 2);
    if (k4 == 0) dinv[nd] = 1.0f / den;
  }
  __syncthreads();

  // --- MFMA: msg[64 x 256] = alpha * hp; wave w owns cols [64w, 64w+64) ---
  f32x4 acc[4][4] = {};
  #pragma unroll
  for (int kk = 0; kk < 2; ++kk) {
    bf16x8 af[4];
    #pragma unroll
    for (int i = 0; i < 4; ++i) {
      int m = (i << 4) + l16;
      const float* ap = &alpha[m * ALF_S + (kk << 5) + (quad << 3)];
      float av[8];
      float4 a0 = *(const float4*)ap, a1 = *(const float4*)(ap + 4);
      av[0]=a0.x; av[1]=a0.y; av[2]=a0.z; av[3]=a0.w;
      av[4]=a1.x; av[5]=a1.y; av[6]=a1.z; av[7]=a1.w;
      af[i] = pack8(av, dinv[m]);
    }
    #pragma unroll
    for (int j = 0; j < 4; ++j) {
      int c2 = (wave << 6) + (j << 4) + l16;
      int chunk = (kk << 2) + quad;
      bf16x8 bfr = *(const bf16x8*)&hpT[(c2 << 6) + ((chunk ^ (c2 & 7)) << 3)];
      #pragma unroll
      for (int i = 0; i < 4; ++i)
        acc[i][j] = __builtin_amdgcn_mfma_f32_16x16x32_bf16(af[i], bfr, acc[i][j], 0, 0, 0);
    }
  }

  // --- store per-head msg (bf16) ---
  #pragma unroll
  for (int j = 0; j < 4; ++j) {
    int col = (wave << 6) + (j << 4) + l16;
    #pragma unroll
    for (int i = 0; i < 4; ++i) {
      int rbase = (i << 4) + (quad << 2);
      #pragma unroll
      for (int r = 0; r < 4; ++r)
        msg4[((size_t)hd * hn + (lg << 6) + rbase + r) * 256 + col] = f2b(acc[i][j][r]);
    }
  }
}

// Head-mean + bias + LayerNorm + GELU + residual. Wave per node.
__global__ __launch_bounds__(256) void gat_epi(
    const bf16* __restrict__ msg4, int hn, int n0,
    const bf16* __restrict__ bias, const bf16* __restrict__ gg, const bf16* __restrict__ gb,
    float* __restrict__ h)
{
  int nl = blockIdx.x * 4 + (threadIdx.x >> 6);
  int lane = threadIdx.x & 63;
  int c = lane * 4;
  float4 s = make_float4(0.f, 0.f, 0.f, 0.f);
  #pragma unroll
  for (int hd = 0; hd < 4; ++hd) {
    float4 m = load4(msg4 + ((size_t)hd * hn + nl) * 256 + c);
    s.x += m.x; s.y += m.y; s.z += m.z; s.w += m.w;
  }
  float4 bv = load4(bias + c);
  float ox = s.x * 0.25f + bv.x, oy = s.y * 0.25f + bv.y;
  float oz = s.z * 0.25f + bv.z, ow = s.w * 0.25f + bv.w;
  float mean = wave_sum(ox + oy + oz + ow) * (1.0f / 256.0f);
  float dx = ox - mean, dy = oy - mean, dz = oz - mean, dw = ow - mean;
  float var = wave_sum(dx*dx + dy*dy + dz*dz + dw*dw) * (1.0f / 256.0f);
  float r = rsqrtf(var + 1e-5f);
  float4 gv = load4(gg + c); float4 b2 = load4(gb + c);
  size_t base = ((size_t)(n0 + nl)) * 256 + c;
  float4 hv = load4(h + base);
  hv.x += gelu_f(dx * r * gv.x + b2.x);
  hv.y += gelu_f(dy * r * gv.y + b2.y);
  hv.z += gelu_f(dz * r * gv.z + b2.z);
  hv.w += gelu_f(dw * r * gv.w + b2.w);
  store4(h + base, hv);
}

// ---------------------------------------------------------------------------
// LayerNorm: wave-per-row (4 rows/block), f32 in, bf16 out
// ---------------------------------------------------------------------------
__global__ __launch_bounds__(256) void ln_kernel(
    const float* __restrict__ x, bf16* __restrict__ y,
    const bf16* __restrict__ g, const bf16* __restrict__ b)
{
  int row = blockIdx.x * 4 + (threadIdx.x >> 6);
  int lane = threadIdx.x & 63;
  int c = lane * 4;
  float4 v = load4(x + (size_t)row * 256 + c);
  float mean = wave_sum(v.x + v.y + v.z + v.w) * (1.0f / 256.0f);
  float dx = v.x - mean, dy = v.y - mean, dz = v.z - mean, dw = v.w - mean;
  float var = wave_sum(dx*dx + dy*dy + dz*dz + dw*dw) * (1.0f / 256.0f);
  float r = rsqrtf(var + 1e-5f);
  float4 gv = load4(g + c); float4 bv = load4(b + c);
  store4(y + (size_t)row * 256 + c,
         make_float4(dx*r*gv.x + bv.x, dy*r*gv.y + bv.y, dz*r*gv.z + bv.z, dw*r*gv.w + bv.w));
}

// ---------------------------------------------------------------------------
// MFMA flash-style attention (unchanged from round 7)
// ---------------------------------------------------------------------------
#define VT_LDS 268
#define P_LDS  72

__global__ __launch_bounds__(256) void attn_mfma(
    const bf16* __restrict__ qkv, bf16* __restrict__ obuf)
{
  const int b  = blockIdx.x & 63;
  const int hh = blockIdx.x >> 6;
  __shared__ unsigned short VTs[32 * VT_LDS];
  __shared__ unsigned short Ps[4][64 * P_LDS];
  const int tid  = threadIdx.x;
  const int wave = tid >> 6, lane = tid & 63;
  const int quad = lane >> 4, l16 = lane & 15;

  {
    const bf16* vb = qkv + (size_t)(tid * 64 + b) * 768 + 512 + hh * 32;
    unsigned short vv[32];
    *(uint4*)&vv[0]  = *(const uint4*)(vb);
    *(uint4*)&vv[8]  = *(const uint4*)(vb + 8);
    *(uint4*)&vv[16] = *(const uint4*)(vb + 16);
    *(uint4*)&vv[24] = *(const uint4*)(vb + 24);
    #pragma unroll
    for (int d = 0; d < 32; ++d) VTs[d * VT_LDS + tid] = vv[d];
  }
  bf16x8 qf[4];
  #pragma unroll
  for (int i = 0; i < 4; ++i) {
    int s = (wave << 6) + (i << 4) + l16;
    qf[i] = *(const bf16x8*)(qkv + (size_t)(s * 64 + b) * 768 + hh * 32 + (quad << 3));
  }
  __syncthreads();

  const float scale = 0.17677669529663687f;
  f32x4 oacc[4][2] = {};
  float lsum[4][4] = {};
  unsigned short* Pw = &Ps[wave][0];

  for (int nt = 0; nt < 4; ++nt) {
    bf16x8 kf[4];
    #pragma unroll
    for (int j = 0; j < 4; ++j) {
      int t = (nt << 6) + (j << 4) + l16;
      kf[j] = *(const bf16x8*)(qkv + (size_t)(t * 64 + b) * 768 + 256 + hh * 32 + (quad << 3));
    }
    f32x4 zero = {0.f, 0.f, 0.f, 0.f};
    f32x4 sx[4][4];
    #pragma unroll
    for (int i = 0; i < 4; ++i)
      #pragma unroll
      for (int j = 0; j < 4; ++j)
        sx[i][j] = __builtin_amdgcn_mfma_f32_16x16x32_bf16(qf[i], kf[j], zero, 0, 0, 0);
    #pragma unroll
    for (int i = 0; i < 4; ++i) {
      #pragma unroll
      for (int r = 0; r < 4; ++r) {
        float p[4]; float rs = 0.f;
        #pragma unroll
        for (int j = 0; j < 4; ++j) {
          float sc = fminf(fmaxf(sx[i][j][r] * scale, -60.f), 60.f);
          p[j] = __expf(sc);
          rs += p[j];
        }
        #pragma unroll
        for (int o = 1; o < 16; o <<= 1) rs += __shfl_xor(rs, o);
        lsum[i][r] += rs;
        int row = (i << 4) + (quad << 2) + r;
        #pragma unroll
        for (int j = 0; j < 4; ++j)
          Pw[row * P_LDS + (j << 4) + l16] = f2us(p[j]);
      }
    }
    #pragma unroll
    for (int kk = 0; kk < 2; ++kk) {
      bf16x8 vf[2];
      #pragma unroll
      for (int j2 = 0; j2 < 2; ++j2)
        vf[j2] = *(const bf16x8*)&VTs[((j2 << 4) + l16) * VT_LDS + (nt << 6) + (kk << 5) + (quad << 3)];
      #pragma unroll
      for (int i2 = 0; i2 < 4; ++i2) {
        bf16x8 pf = *(const bf16x8*)&Pw[((i2 << 4) + l16) * P_LDS + (kk << 5) + (quad << 3)];
        #pragma unroll
        for (int j2 = 0; j2 < 2; ++j2)
          oacc[i2][j2] = __builtin_amdgcn_mfma_f32_16x16x32_bf16(pf, vf[j2], oacc[i2][j2], 0, 0, 0);
      }
    }
  }
  #pragma unroll
  for (int i = 0; i < 4; ++i) {
    #pragma unroll
    for (int r = 0; r < 4; ++r) {
      int srow = (wave << 6) + (i << 4) + (quad << 2) + r;
      float inv = 1.0f / lsum[i][r];
      #pragma unroll
      for (int j2 = 0; j2 < 2; ++j2)
        obuf[(size_t)(srow * 64 + b) * 256 + hh * 32 + (j2 << 4) + l16] = f2b(oacc[i][j2][r] * inv);
    }
  }
}

// ---------------------------------------------------------------------------
// Pooling + heads
// ---------------------------------------------------------------------------
__global__ __launch_bounds__(256) void pool_logit(
    const float* __restrict__ h, const bf16* __restrict__ pw, const bf16* __restrict__ pb,
    float* __restrict__ logits)
{
  int n = blockIdx.x * 4 + (threadIdx.x >> 6); int lane = threadIdx.x & 63;
  float4 hv = load4(h + (size_t)n * 256 + lane * 4);
  float4 wv = load4(pw + lane * 4);
  float acc = wave_sum(hv.x*wv.x + hv.y*wv.y + hv.z*wv.z + hv.w*wv.w);
  if (lane == 0) logits[n] = acc + b2f(pb[0]);
}
__global__ __launch_bounds__(1024) void pool_reduce(
    const float* __restrict__ logits, float* __restrict__ red)
{
  __shared__ float sm[16];
  int t = threadIdx.x;
  float m = -1e30f;
  for (int i = t; i < N_NODES; i += 1024) m = fmaxf(m, logits[i]);
  m = wave_max(m);
  if ((t & 63) == 0) sm[t >> 6] = m;
  __syncthreads();
  if (t == 0) { float mm = sm[0]; for (int i = 1; i < 16; ++i) mm = fmaxf(mm, sm[i]); sm[0] = mm; }
  __syncthreads();
  float gmax = sm[0];
  __syncthreads();
  float s = 0.f;
  for (int i = t; i < N_NODES; i += 1024) s += expf(logits[i] - gmax);
  s = wave_sum(s);
  if ((t & 63) == 0) sm[t >> 6] = s;
  __syncthreads();
  if (t == 0) { float ss = 0.f; for (int i = 0; i < 16; ++i) ss += sm[i]; red[0] = gmax; red[1] = 1.0f / ss; }
}
__global__ __launch_bounds__(256) void pool_grep(
    const float* __restrict__ h, const float* __restrict__ logits,
    const float* __restrict__ red, float* __restrict__ g_rep)
{
  __shared__ float w[64];
  int g = blockIdx.x; int tid = threadIdx.x;
  if (tid < 64) w[tid] = expf(logits[g * 64 + tid] - red[0]) * red[1];
  __syncthreads();
  float acc = 0.f;
  for (int nd = 0; nd < 64; ++nd) acc += h[((size_t)g * 64 + nd) * 256 + tid] * w[nd];
  g_rep[(size_t)g * 256 + tid] = acc;
}
__global__ __launch_bounds__(256) void head_value(
    const float* __restrict__ vt, const bf16* __restrict__ w2, const bf16* __restrict__ b2,
    bf16* __restrict__ out)
{
  int gidx = blockIdx.x * 4 + (threadIdx.x >> 6); int lane = threadIdx.x & 63;
  float acc = 0.f;
  #pragma unroll
  for (int j = 0; j < 4; ++j) { int c = j * 64 + lane; acc += vt[(size_t)gidx * 256 + c] * b2f(w2[c]); }
  acc = wave_sum(acc);
  if (lane == 0) out[gidx] = f2b(tanhf(acc + b2f(b2[0])));
}
__global__ __launch_bounds__(256) void head_unc(
    const float* __restrict__ ut, const bf16* __restrict__ w2, const bf16* __restrict__ b2,
    bf16* __restrict__ out)
{
  int gidx = blockIdx.x * 4 + (threadIdx.x >> 6); int lane = threadIdx.x & 63;
  float acc = 0.f;
  #pragma unroll
  for (int j = 0; j < 2; ++j) { int c = j * 64 + lane; acc += ut[(size_t)gidx * 128 + c] * b2f(w2[c]); }
  acc = wave_sum(acc);
  if (lane == 0) {
    float x = acc + b2f(b2[0]);
    float sp = (x > 20.f) ? x : log1pf(expf(x));
    out[gidx] = f2b(sp);
  }
}

// ---------------------------------------------------------------------------
extern "C" void kernel_launch(void* const* d_in, const int* in_sizes, int n_in,
                              void* d_out, int out_size, void* d_ws, size_t ws_size,
                              hipStream_t stream)
{
  (void)out_size;
  const int* eidx = (const int*)d_in[1];

  char* ws = (char*)d_ws;
  size_t wo = 0;
  auto alloc = [&](size_t bytes) -> char* {
    char* p = ws + wo; wo += (bytes + 255) & ~(size_t)255; return p;
  };
  int*   flags = (int*)alloc(256);
  int*   cnt   = (int*)alloc((size_t)N_NODES * 4);
  int*   fillc = (int*)alloc((size_t)N_NODES * 4);
  size_t zero_end = wo;

  bf16* conv[38] = {};
  static const int fidx[35] = {0,4,5,6,7,8,9,10,11,12,13,14,15,16,17,18,19,
                               20,21,22,23,24,25,26,27,28,29,30,31,32,33,34,35,36,37};
  for (int j = 0; j < 35; ++j) {
    int idx = fidx[j];
    conv[idx] = (bf16*)alloc((size_t)in_sizes[idx] * 2);
  }
  float* h     = (float*)alloc((size_t)N_NODES * 256 * 4);
  bf16*  big   = (bf16*) alloc((size_t)N_NODES * 1024 * 2);
  // tn and ostage MUST be adjacent: msg4 aliases over them in halved mode
  const int OUT_ELEMS = 256 + N_NODES * 256 + 256;
  bf16*  tn     = (bf16*)alloc((size_t)N_NODES * 256 * 2);   // 8.39 MB
  bf16*  ostage = (bf16*)alloc((size_t)OUT_ELEMS * 2);       // 8.39 MB (adjacent)
  int*   off   = (int*)alloc((size_t)(N_NODES + 1) * 4);
  int*   list  = (int*)alloc((size_t)NE2 * 4);
  float* logits= (float*)alloc((size_t)N_NODES * 4);
  float* redb  = (float*)alloc(256);
  float* g_rep = (float*)alloc((size_t)256 * 256 * 4);
  float* val_t = (float*)alloc((size_t)256 * 256 * 4);
  float* unc_t = (float*)alloc((size_t)256 * 128 * 4);
  size_t base_needed = wo;

  if (n_in != 38)                   { write_sentinel<<<1,256,0,stream>>>((bf16*)d_out, 4.f);  return; }
  if (in_sizes[0] != N_NODES * 128) { write_sentinel<<<1,256,0,stream>>>((bf16*)d_out, 8.f);  return; }
  if (in_sizes[1] != 2 * NE)        { write_sentinel<<<1,256,0,stream>>>((bf16*)d_out, 16.f); return; }
  if (ws_size < base_needed)        { write_sentinel<<<1,256,0,stream>>>((bf16*)d_out, 32.f); return; }

  // msg4: full (1 phase) if workspace allows, else aliased over tn+ostage (2 phases)
  size_t msg_bytes = (size_t)4 * N_NODES * 256 * 2;   // 33.5 MB
  bf16* msg4; int halves;
  if (ws_size >= base_needed + msg_bytes + 256) {
    msg4 = (bf16*)alloc(msg_bytes); halves = 1;
  } else {
    msg4 = tn; halves = 2;   // 16.78 MB needed, tn+ostage = 16.78 MB
  }

  hipMemsetAsync(d_ws, 0, zero_end, stream);

  detect_dtype<<<256, 256, 0, stream>>>((const unsigned short*)d_in[0], 65536, flags);
  {
    ConvArgs ca;
    int cum = 0;
    for (int j = 0; j < 35; ++j) {
      int idx = fidx[j];
      ca.src[j] = d_in[idx];
      ca.dst[j] = (unsigned short*)conv[idx];
      ca.cumg[j] = cum;
      ca.n[j] = in_sizes[idx];
      cum += (in_sizes[idx] + 3) >> 2;
    }
    ca.cumg[35] = cum;
    conv_all4<<<(cum + 255) / 256, 256, 0, stream>>>(ca, flags);
  }
  const bf16 *xb = conv[0], *emb_w = conv[4], *emb_b = conv[5], *gat_w = conv[6],
             *gat_as = conv[7], *gat_ad = conv[8], *gat_b = conv[9], *gnn_g = conv[10],
             *gnn_beta = conv[11], *ln1_g = conv[12], *ln1_b = conv[13], *in_w = conv[14],
             *in_b = conv[15], *out_w = conv[16], *out_b = conv[17], *ln2_g = conv[18],
             *ln2_b = conv[19], *ff1_w = conv[20], *ff1_b = conv[21], *ff2_w = conv[22],
             *ff2_b = conv[23], *pool_w = conv[24], *pool_b = conv[25],
             *vw1 = conv[26], *vb1 = conv[27], *vw2 = conv[28], *vb2 = conv[29],
             *pw1 = conv[30], *pb1 = conv[31], *pw2 = conv[32], *pb2 = conv[33],
             *uw1 = conv[34], *ub1 = conv[35], *uw2 = conv[36], *ub2 = conv[37];

  bf16* qkv  = big;
  bf16* obuf = big + (size_t)N_NODES * 768;
  bf16* hp   = big;
  bf16* ffb  = big;
  bf16* o_val = ostage;
  bf16* o_pol = ostage + 256;
  bf16* o_unc = ostage + 256 + (size_t)N_NODES * 256;

  csr_count<<<(NE2 + 255) / 256, 256, 0, stream>>>(eidx + NE, cnt);
  csr_scan<<<1, 1024, 0, stream>>>(cnt, off);
  csr_fill<<<(NE2 + 255) / 256, 256, 0, stream>>>(eidx + NE, off, fillc, list);

  gemm_mfma<bf16, float, 0><<<dim3(2, 128), 256, 0, stream>>>(
      xb, emb_w, emb_b, nullptr, h, N_NODES, 256, 128);

  const int gph = 256 / halves;          // graphs per phase
  const int hn  = N_NODES / halves;      // nodes per phase
  for (int l = 0; l < 8; ++l) {
    gemm_mfma<float, bf16, 0><<<dim3(8, 128), 256, 0, stream>>>(
        h, gat_w + (size_t)l * 1024 * 256, nullptr, nullptr, hp, N_NODES, 1024, 256);
    for (int ph = 0; ph < halves; ++ph) {
      gat_graph2<<<gph * 4, 256, 0, stream>>>(eidx, hp, off, list,
          gat_as + l * 1024, gat_ad + l * 1024, msg4, ph * gph, hn);
      gat_epi<<<hn / 4, 256, 0, stream>>>(msg4, hn, ph * hn,
          gat_b + l * 256, gnn_g + l * 256, gnn_beta + l * 256, h);
    }
  }

  for (int l = 0; l < 6; ++l) {
    ln_kernel<<<N_NODES / 4, 256, 0, stream>>>(h, tn, ln1_g + l * 256, ln1_b + l * 256);
    gemm_mfma<bf16, bf16, 0><<<dim3(6, 128), 256, 0, stream>>>(
        tn, in_w + (size_t)l * 768 * 256, in_b + l * 768, nullptr, qkv, N_NODES, 768, 256);
    attn_mfma<<<512, 256, 0, stream>>>(qkv, obuf);
    gemm_mfma<bf16, float, 2><<<dim3(2, 128), 256, 0, stream>>>(
        obuf, out_w + (size_t)l * 256 * 256, out_b + l * 256, h, h, N_NODES, 256, 256);
    ln_kernel<<<N_NODES / 4, 256, 0, stream>>>(h, tn, ln2_g + l * 256, ln2_b + l * 256);
    gemm_mfma<bf16, bf16, 1><<<dim3(8, 128), 256, 0, stream>>>(
        tn, ff1_w + (size_t)l * 1024 * 256, ff1_b + l * 1024, nullptr, ffb, N_NODES, 1024, 256);
    gemm_mfma<bf16, float, 2><<<dim3(2, 128), 256, 0, stream>>>(
        ffb, ff2_w + (size_t)l * 256 * 1024, ff2_b + l * 256, h, h, N_NODES, 256, 1024);
  }

  pool_logit<<<N_NODES / 4, 256, 0, stream>>>(h, pool_w, pool_b, logits);
  pool_reduce<<<1, 1024, 0, stream>>>(logits, redb);
  pool_grep<<<256, 256, 0, stream>>>(h, logits, redb, g_rep);
  gemm_mfma<float, float, 1><<<dim3(2, 2), 256, 0, stream>>>(
      g_rep, vw1, vb1, nullptr, val_t, 256, 256, 256);
  head_value<<<64, 256, 0, stream>>>(val_t, vw2, vb2, o_val);
  gemm_mfma<float, float, 1><<<dim3(1, 2), 256, 0, stream>>>(
      g_rep, uw1, ub1, nullptr, unc_t, 256, 128, 256);
  head_unc<<<64, 256, 0, stream>>>(unc_t, uw2, ub2, o_unc);
  gemm_mfma<float, bf16, 1><<<dim3(2, 128), 256, 0, stream>>>(
      h, pw1, pb1, nullptr, tn, N_NODES, 256, 256);
  gemm_mfma<bf16, bf16, 0><<<dim3(2, 128), 256, 0, stream>>>(
      tn, pw2, pb2, nullptr, o_pol, N_NODES, 256, 256);

  emit_out<<<(OUT_ELEMS + 255) / 256, 256, 0, stream>>>(
      (const unsigned short*)ostage, d_out, OUT_ELEMS, flags);
}

// Round 10
// 1733.197 us; speedup vs baseline: 4.4583x; 1.0827x over previous
//
#include <hip/hip_runtime.h>
#include <hip/hip_bf16.h>

typedef __hip_bfloat16 bf16;
typedef __bf16 bf16x8 __attribute__((ext_vector_type(8)));
typedef float  f32x4  __attribute__((ext_vector_type(4)));

#define N_NODES 16384
#define HDIM    256
#define NE      131072
#define NE2     147456   // NE + N self loops

__device__ __forceinline__ float b2f(bf16 v){ return __bfloat162float(v); }
__device__ __forceinline__ bf16  f2b(float v){ return __float2bfloat16(v); }
__device__ __forceinline__ float us2f(unsigned short u){
  union { unsigned int i; float f; } c; c.i = ((unsigned int)u) << 16; return c.f;
}
__device__ __forceinline__ unsigned short f2us(float f){
  bf16 h = __float2bfloat16(f);
  unsigned short u; __builtin_memcpy(&u, &h, 2); return u;
}
__device__ __forceinline__ float gelu_f(float x){
  return 0.5f * x * (1.0f + erff(x * 0.7071067811865476f));
}
__device__ __forceinline__ float wave_sum(float v){
  #pragma unroll
  for (int o = 32; o > 0; o >>= 1) v += __shfl_xor(v, o);
  return v;
}
__device__ __forceinline__ float wave_max(float v){
  #pragma unroll
  for (int o = 32; o > 0; o >>= 1) v = fmaxf(v, __shfl_xor(v, o));
  return v;
}

__device__ __forceinline__ float4 load4(const float* p){ return *(const float4*)p; }
__device__ __forceinline__ float4 load4(const bf16* p){
  ushort4 u = *(const ushort4*)p;
  return make_float4(us2f(u.x), us2f(u.y), us2f(u.z), us2f(u.w));
}
__device__ __forceinline__ void store4(float* p, float4 v){ *(float4*)p = v; }
__device__ __forceinline__ void store4(bf16* p, float4 v){
  ushort4 u = make_ushort4(f2us(v.x), f2us(v.y), f2us(v.z), f2us(v.w));
  *(ushort4*)p = u;
}
__device__ __forceinline__ void storev(float* p, float4 v){ *(float4*)p = v; }
__device__ __forceinline__ void storev(bf16*  p, float4 v){ store4(p, v); }

// async 16B/lane global -> LDS (lds dest = wave-uniform base + lane*16)
__device__ __forceinline__ void async_ld16(const bf16* g, unsigned short* l){
  __builtin_amdgcn_global_load_lds(
      (const __attribute__((address_space(1))) void*)g,
      (__attribute__((address_space(3))) void*)l, 16, 0, 0);
}

// ---------------------------------------------------------------------------
// dtype detection + normalization.  flags[1] = input-is-f32
// ---------------------------------------------------------------------------
__global__ void detect_dtype(const unsigned short* __restrict__ x, int n, int* __restrict__ flags){
  int i = blockIdx.x * 256 + threadIdx.x;
  if (i < n) {
    unsigned short u = x[i];
    if ((u & 0x7F80) == 0x7F80) atomicOr(&flags[1], 1);
  }
}
struct ConvArgs {
  const void* src[35];
  unsigned short* dst[35];
  int cumg[36];
  int n[35];
};
__global__ void conv_all4(ConvArgs a, const int* __restrict__ flags){
  int gi = blockIdx.x * 256 + threadIdx.x;
  if (gi >= a.cumg[35]) return;
  int lo = 0, hi = 34;
  while (lo < hi) { int mid = (lo + hi + 1) >> 1; if (gi >= a.cumg[mid]) lo = mid; else hi = mid - 1; }
  int e0 = (gi - a.cumg[lo]) << 2;
  int n = a.n[lo];
  unsigned short* d = a.dst[lo];
  if (flags[1]) {
    const float* s = (const float*)a.src[lo];
    if (e0 + 4 <= n) {
      float4 v = *(const float4*)(s + e0);
      *(ushort4*)(d + e0) = make_ushort4(f2us(v.x), f2us(v.y), f2us(v.z), f2us(v.w));
    } else {
      for (int t = 0; t < n - e0; ++t) d[e0 + t] = f2us(s[e0 + t]);
    }
  } else {
    const unsigned short* s = (const unsigned short*)a.src[lo];
    if (e0 + 4 <= n) *(ushort4*)(d + e0) = *(const ushort4*)(s + e0);
    else for (int t = 0; t < n - e0; ++t) d[e0 + t] = s[e0 + t];
  }
}
__global__ void emit_out(const unsigned short* __restrict__ stage, void* __restrict__ out,
                         int n, const int* __restrict__ flags){
  int i = blockIdx.x * 256 + threadIdx.x;
  if (i >= n) return;
  if (flags[1]) ((float*)out)[i] = us2f(stage[i]);
  else          ((unsigned short*)out)[i] = stage[i];
}
__global__ void write_sentinel(bf16* out, float v){ out[threadIdx.x] = f2b(v); }

// ---------------------------------------------------------------------------
// gemm2: MFMA bf16 NT GEMM with async global->LDS staging (BK=64, XOR swizzle)
// and LDS-transposed vectorized epilogue. C = A[M,K] * W[Nn,K]^T (+bias)...
// FLAGS: 1 = gelu, 2 = residual add (res f32), 4 = also store bf16 mirror C2.
// M%128==0, Nn%128==0, K%64==0.
// ---------------------------------------------------------------------------
#define GF_GELU 1
#define GF_RES  2
#define GF_MIR  4

template<typename TO, int FLAGS>
__global__ __launch_bounds__(256) void gemm2(
    const bf16* __restrict__ A, const bf16* __restrict__ W,
    const bf16* __restrict__ bias, const float* __restrict__ res,
    TO* __restrict__ C, bf16* __restrict__ C2, int M, int Nn, int K)
{
  __shared__ __align__(16) char ldsraw[36864];   // staging 32 KB | epilogue 36 KB
  unsigned short* sA = (unsigned short*)ldsraw;  // 128 rows x 64 shorts
  unsigned short* sB = sA + 128 * 64;
  const int tid = threadIdx.x;
  const int wave = tid >> 6, lane = tid & 63;
  const int quad = lane >> 4, l16 = lane & 15;
  const int wm = wave & 1, wn = wave >> 1;
  const int row0 = blockIdx.y << 7, col0 = blockIdx.x << 7;
  const int lr = lane >> 3, lc = lane & 7;

  f32x4 acc[4][4] = {};

  for (int kt = 0; kt < K; kt += 64) {
    #pragma unroll
    for (int it = 0; it < 4; ++it) {
      int r0 = (wave << 5) + (it << 3);
      int rr = r0 + lr;
      int gch = lc ^ (rr & 7);
      async_ld16(A + (size_t)(row0 + rr) * K + kt + (gch << 3), sA + (r0 << 6));
      async_ld16(W + (size_t)(col0 + rr) * K + kt + (gch << 3), sB + (r0 << 6));
    }
    __syncthreads();
    #pragma unroll
    for (int kk = 0; kk < 2; ++kk) {
      bf16x8 af[4];
      #pragma unroll
      for (int i = 0; i < 4; ++i) {
        int m = (wm << 6) + (i << 4) + l16;
        af[i] = *(const bf16x8*)&sA[(m << 6) + ((((kk << 2) + quad) ^ (l16 & 7)) << 3)];
      }
      #pragma unroll
      for (int j = 0; j < 4; ++j) {
        int n = (wn << 6) + (j << 4) + l16;
        bf16x8 bfr = *(const bf16x8*)&sB[(n << 6) + ((((kk << 2) + quad) ^ (l16 & 7)) << 3)];
        #pragma unroll
        for (int i = 0; i < 4; ++i)
          acc[i][j] = __builtin_amdgcn_mfma_f32_16x16x32_bf16(af[i], bfr, acc[i][j], 0, 0, 0);
      }
    }
    __syncthreads();
  }

  // epilogue: wave-private 64x36 f32 LDS tile, 2 passes of 32 cols
  float* ct = (float*)ldsraw + wave * (64 * 36);
  #pragma unroll
  for (int p = 0; p < 2; ++p) {
    #pragma unroll
    for (int i = 0; i < 4; ++i)
      #pragma unroll
      for (int r = 0; r < 4; ++r) {
        int row = (i << 4) + (quad << 2) + r;
        ct[row * 36 + l16]      = acc[i][(p << 1) + 0][r];
        ct[row * 36 + 16 + l16] = acc[i][(p << 1) + 1][r];
      }
    // same-wave LDS write->read ordering handled by compiler waitcnt
    #pragma unroll
    for (int it2 = 0; it2 < 8; ++it2) {
      int row = (it2 << 3) + lr;
      int c4 = lc << 2;
      float4 v = *(const float4*)&ct[row * 36 + c4];
      int gcol = col0 + (wn << 6) + (p << 5) + c4;
      size_t gidx = (size_t)(row0 + (wm << 6) + row) * Nn + gcol;
      if (bias) {
        float4 bv = load4(bias + gcol);
        v.x += bv.x; v.y += bv.y; v.z += bv.z; v.w += bv.w;
      }
      if (FLAGS & GF_GELU) {
        v.x = gelu_f(v.x); v.y = gelu_f(v.y); v.z = gelu_f(v.z); v.w = gelu_f(v.w);
      }
      if (FLAGS & GF_RES) {
        float4 rv = *(const float4*)&res[gidx];
        v.x += rv.x; v.y += rv.y; v.z += rv.z; v.w += rv.w;
      }
      storev(C + gidx, v);
      if (FLAGS & GF_MIR) store4(C2 + gidx, v);
    }
  }
}

// ---------------------------------------------------------------------------
// CSR build over dst
// ---------------------------------------------------------------------------
__global__ void csr_count(const int* __restrict__ edst, int* __restrict__ cnt){
  int e = blockIdx.x * 256 + threadIdx.x;
  if (e < NE2) {
    int d = (e < NE) ? edst[e] : (e - NE);
    atomicAdd(&cnt[d], 1);
  }
}
__global__ __launch_bounds__(1024) void csr_scan(const int* __restrict__ cnt, int* __restrict__ off){
  __shared__ int ls[1024];
  int t = threadIdx.x;
  int base = t * 16;
  int loc[16]; int s = 0;
  #pragma unroll
  for (int j = 0; j < 16; ++j) { loc[j] = s; s += cnt[base + j]; }
  ls[t] = s;
  __syncthreads();
  for (int o = 1; o < 1024; o <<= 1) {
    int v = (t >= o) ? ls[t - o] : 0;
    __syncthreads();
    ls[t] += v;
    __syncthreads();
  }
  int pre = (t == 0) ? 0 : ls[t - 1];
  #pragma unroll
  for (int j = 0; j < 16; ++j) off[base + j] = pre + loc[j];
  if (t == 1023) off[N_NODES] = ls[1023];
}
__global__ void csr_fill(const int* __restrict__ edst, const int* __restrict__ off,
                         int* __restrict__ fillc, int* __restrict__ list){
  int e = blockIdx.x * 256 + threadIdx.x;
  if (e < NE2) {
    int d = (e < NE) ? edst[e] : (e - NE);
    int p = atomicAdd(&fillc[d], 1);
    list[off[d] + p] = e;
  }
}

// ---------------------------------------------------------------------------
// GAT per-(graph,head) block (from round 9)
// ---------------------------------------------------------------------------
#define ALF_S 68

__device__ __forceinline__ bf16x8 pack8(const float* v, float scale){
  unsigned short u[8];
  #pragma unroll
  for (int t = 0; t < 8; ++t) u[t] = f2us(v[t] * scale);
  bf16x8 r; __builtin_memcpy(&r, u, 16); return r;
}

__global__ __launch_bounds__(256) void gat_graph2(
    const int* __restrict__ esrc, const bf16* __restrict__ hp,
    const int* __restrict__ off, const int* __restrict__ list,
    const bf16* __restrict__ a_s, const bf16* __restrict__ a_d,
    bf16* __restrict__ msg4, int g0, int hn)
{
  __shared__ unsigned short hpT[256 * 64];
  __shared__ float alpha[64 * ALF_S];
  __shared__ float als[64], ald[64], dinv[64];

  const int hd = blockIdx.x & 3;
  const int lg = blockIdx.x >> 2;
  const int g  = g0 + lg;
  const int tid = threadIdx.x;
  const int wave = tid >> 6, lane = tid & 63;
  const int quad = lane >> 4, l16 = lane & 15;
  const int nd = tid >> 2;
  const int k4 = tid & 3;

  {
    const bf16* hrow = hp + ((size_t)((g << 6) + nd)) * 1024 + hd * 256 + (k4 << 6);
    const bf16* asp = a_s + hd * 256 + (k4 << 6);
    const bf16* adp = a_d + hd * 256 + (k4 << 6);
    const int s3 = nd >> 3, s7 = nd & 7;
    float s1 = 0.f, s2 = 0.f;
    #pragma unroll
    for (int jj = 0; jj < 64; jj += 8) {
      ushort4 u0 = *(const ushort4*)(hrow + jj);
      ushort4 u1 = *(const ushort4*)(hrow + jj + 4);
      unsigned short hv[8] = {u0.x, u0.y, u0.z, u0.w, u1.x, u1.y, u1.z, u1.w};
      #pragma unroll
      for (int t = 0; t < 8; ++t) {
        int c = (k4 << 6) + jj + t;
        hpT[(c << 6) + (((s3 ^ (c & 7)) << 3) | s7)] = hv[t];
        float hf = us2f(hv[t]);
        s1 += hf * b2f(asp[jj + t]);
        s2 += hf * b2f(adp[jj + t]);
      }
    }
    s1 += __shfl_xor(s1, 1); s1 += __shfl_xor(s1, 2);
    s2 += __shfl_xor(s2, 1); s2 += __shfl_xor(s2, 2);
    if (k4 == 0) { als[nd] = s1; ald[nd] = s2; }
  }
  #pragma unroll
  for (int idx = tid; idx < 64 * ALF_S; idx += 256) alpha[idx] = 0.f;
  __syncthreads();

  {
    int st = off[(g << 6) + nd];
    int deg = off[(g << 6) + nd + 1] - st;
    float ad = ald[nd];
    float mx = -1e30f;
    for (int e = k4; e < deg; e += 4) {
      int ed = list[st + e];
      int sl = ((ed < NE) ? esrc[ed] : (ed - NE)) - (g << 6);
      float v = als[sl] + ad;
      v = (v > 0.f) ? v : 0.2f * v;
      mx = fmaxf(mx, v);
    }
    mx = fmaxf(mx, __shfl_xor(mx, 1)); mx = fmaxf(mx, __shfl_xor(mx, 2));
    float den = 0.f;
    for (int e = k4; e < deg; e += 4) {
      int ed = list[st + e];
      int sl = ((ed < NE) ? esrc[ed] : (ed - NE)) - (g << 6);
      float v = als[sl] + ad;
      v = (v > 0.f) ? v : 0.2f * v;
      float w = __expf(v - mx);
      den += w;
      atomicAdd(&alpha[nd * ALF_S + sl], w);
    }
    den += __shfl_xor(den, 1); den += __shfl_xor(den, 2);
    if (k4 == 0) dinv[nd] = 1.0f / den;
  }
  __syncthreads();

  f32x4 acc[4][4] = {};
  #pragma unroll
  for (int kk = 0; kk < 2; ++kk) {
    bf16x8 af[4];
    #pragma unroll
    for (int i = 0; i < 4; ++i) {
      int m = (i << 4) + l16;
      const float* ap = &alpha[m * ALF_S + (kk << 5) + (quad << 3)];
      float av[8];
      float4 a0 = *(const float4*)ap, a1 = *(const float4*)(ap + 4);
      av[0]=a0.x; av[1]=a0.y; av[2]=a0.z; av[3]=a0.w;
      av[4]=a1.x; av[5]=a1.y; av[6]=a1.z; av[7]=a1.w;
      af[i] = pack8(av, dinv[m]);
    }
    #pragma unroll
    for (int j = 0; j < 4; ++j) {
      int c2 = (wave << 6) + (j << 4) + l16;
      int chunk = (kk << 2) + quad;
      bf16x8 bfr = *(const bf16x8*)&hpT[(c2 << 6) + ((chunk ^ (c2 & 7)) << 3)];
      #pragma unroll
      for (int i = 0; i < 4; ++i)
        acc[i][j] = __builtin_amdgcn_mfma_f32_16x16x32_bf16(af[i], bfr, acc[i][j], 0, 0, 0);
    }
  }

  #pragma unroll
  for (int j = 0; j < 4; ++j) {
    int col = (wave << 6) + (j << 4) + l16;
    #pragma unroll
    for (int i = 0; i < 4; ++i) {
      int rbase = (i << 4) + (quad << 2);
      #pragma unroll
      for (int r = 0; r < 4; ++r)
        msg4[((size_t)hd * hn + (lg << 6) + rbase + r) * 256 + col] = f2b(acc[i][j][r]);
    }
  }
}

// Head-mean + bias + LayerNorm + GELU + residual; writes f32 h + bf16 mirror hb.
__global__ __launch_bounds__(256) void gat_epi(
    const bf16* __restrict__ msg4, int hn, int n0,
    const bf16* __restrict__ bias, const bf16* __restrict__ gg, const bf16* __restrict__ gb,
    float* __restrict__ h, bf16* __restrict__ hb)
{
  int nl = blockIdx.x * 4 + (threadIdx.x >> 6);
  int lane = threadIdx.x & 63;
  int c = lane * 4;
  float4 s = make_float4(0.f, 0.f, 0.f, 0.f);
  #pragma unroll
  for (int hd = 0; hd < 4; ++hd) {
    float4 m = load4(msg4 + ((size_t)hd * hn + nl) * 256 + c);
    s.x += m.x; s.y += m.y; s.z += m.z; s.w += m.w;
  }
  float4 bv = load4(bias + c);
  float ox = s.x * 0.25f + bv.x, oy = s.y * 0.25f + bv.y;
  float oz = s.z * 0.25f + bv.z, ow = s.w * 0.25f + bv.w;
  float mean = wave_sum(ox + oy + oz + ow) * (1.0f / 256.0f);
  float dx = ox - mean, dy = oy - mean, dz = oz - mean, dw = ow - mean;
  float var = wave_sum(dx*dx + dy*dy + dz*dz + dw*dw) * (1.0f / 256.0f);
  float r = rsqrtf(var + 1e-5f);
  float4 gv = load4(gg + c); float4 b2 = load4(gb + c);
  size_t base = ((size_t)(n0 + nl)) * 256 + c;
  float4 hv = load4(h + base);
  hv.x += gelu_f(dx * r * gv.x + b2.x);
  hv.y += gelu_f(dy * r * gv.y + b2.y);
  hv.z += gelu_f(dz * r * gv.z + b2.z);
  hv.w += gelu_f(dw * r * gv.w + b2.w);
  store4(h + base, hv);
  store4(hb + base, hv);
}

// ---------------------------------------------------------------------------
// LayerNorm: wave-per-row (4 rows/block), f32 in, bf16 out
// ---------------------------------------------------------------------------
__global__ __launch_bounds__(256) void ln_kernel(
    const float* __restrict__ x, bf16* __restrict__ y,
    const bf16* __restrict__ g, const bf16* __restrict__ b)
{
  int row = blockIdx.x * 4 + (threadIdx.x >> 6);
  int lane = threadIdx.x & 63;
  int c = lane * 4;
  float4 v = load4(x + (size_t)row * 256 + c);
  float mean = wave_sum(v.x + v.y + v.z + v.w) * (1.0f / 256.0f);
  float dx = v.x - mean, dy = v.y - mean, dz = v.z - mean, dw = v.w - mean;
  float var = wave_sum(dx*dx + dy*dy + dz*dz + dw*dw) * (1.0f / 256.0f);
  float r = rsqrtf(var + 1e-5f);
  float4 gv = load4(g + c); float4 bv = load4(b + c);
  store4(y + (size_t)row * 256 + c,
         make_float4(dx*r*gv.x + bv.x, dy*r*gv.y + bv.y, dz*r*gv.z + bv.z, dw*r*gv.w + bv.w));
}

// ---------------------------------------------------------------------------
// MFMA flash-style attention (unchanged from round 7)
// ---------------------------------------------------------------------------
#define VT_LDS 268
#define P_LDS  72

__global__ __launch_bounds__(256) void attn_mfma(
    const bf16* __restrict__ qkv, bf16* __restrict__ obuf)
{
  const int b  = blockIdx.x & 63;
  const int hh = blockIdx.x >> 6;
  __shared__ unsigned short VTs[32 * VT_LDS];
  __shared__ unsigned short Ps[4][64 * P_LDS];
  const int tid  = threadIdx.x;
  const int wave = tid >> 6, lane = tid & 63;
  const int quad = lane >> 4, l16 = lane & 15;

  {
    const bf16* vb = qkv + (size_t)(tid * 64 + b) * 768 + 512 + hh * 32;
    unsigned short vv[32];
    *(uint4*)&vv[0]  = *(const uint4*)(vb);
    *(uint4*)&vv[8]  = *(const uint4*)(vb + 8);
    *(uint4*)&vv[16] = *(const uint4*)(vb + 16);
    *(uint4*)&vv[24] = *(const uint4*)(vb + 24);
    #pragma unroll
    for (int d = 0; d < 32; ++d) VTs[d * VT_LDS + tid] = vv[d];
  }
  bf16x8 qf[4];
  #pragma unroll
  for (int i = 0; i < 4; ++i) {
    int s = (wave << 6) + (i << 4) + l16;
    qf[i] = *(const bf16x8*)(qkv + (size_t)(s * 64 + b) * 768 + hh * 32 + (quad << 3));
  }
  __syncthreads();

  const float scale = 0.17677669529663687f;
  f32x4 oacc[4][2] = {};
  float lsum[4][4] = {};
  unsigned short* Pw = &Ps[wave][0];

  for (int nt = 0; nt < 4; ++nt) {
    bf16x8 kf[4];
    #pragma unroll
    for (int j = 0; j < 4; ++j) {
      int t = (nt << 6) + (j << 4) + l16;
      kf[j] = *(const bf16x8*)(qkv + (size_t)(t * 64 + b) * 768 + 256 + hh * 32 + (quad << 3));
    }
    f32x4 zero = {0.f, 0.f, 0.f, 0.f};
    f32x4 sx[4][4];
    #pragma unroll
    for (int i = 0; i < 4; ++i)
      #pragma unroll
      for (int j = 0; j < 4; ++j)
        sx[i][j] = __builtin_amdgcn_mfma_f32_16x16x32_bf16(qf[i], kf[j], zero, 0, 0, 0);
    #pragma unroll
    for (int i = 0; i < 4; ++i) {
      #pragma unroll
      for (int r = 0; r < 4; ++r) {
        float p[4]; float rs = 0.f;
        #pragma unroll
        for (int j = 0; j < 4; ++j) {
          float sc = fminf(fmaxf(sx[i][j][r] * scale, -60.f), 60.f);
          p[j] = __expf(sc);
          rs += p[j];
        }
        #pragma unroll
        for (int o = 1; o < 16; o <<= 1) rs += __shfl_xor(rs, o);
        lsum[i][r] += rs;
        int row = (i << 4) + (quad << 2) + r;
        #pragma unroll
        for (int j = 0; j < 4; ++j)
          Pw[row * P_LDS + (j << 4) + l16] = f2us(p[j]);
      }
    }
    #pragma unroll
    for (int kk = 0; kk < 2; ++kk) {
      bf16x8 vf[2];
      #pragma unroll
      for (int j2 = 0; j2 < 2; ++j2)
        vf[j2] = *(const bf16x8*)&VTs[((j2 << 4) + l16) * VT_LDS + (nt << 6) + (kk << 5) + (quad << 3)];
      #pragma unroll
      for (int i2 = 0; i2 < 4; ++i2) {
        bf16x8 pf = *(const bf16x8*)&Pw[((i2 << 4) + l16) * P_LDS + (kk << 5) + (quad << 3)];
        #pragma unroll
        for (int j2 = 0; j2 < 2; ++j2)
          oacc[i2][j2] = __builtin_amdgcn_mfma_f32_16x16x32_bf16(pf, vf[j2], oacc[i2][j2], 0, 0, 0);
      }
    }
  }
  #pragma unroll
  for (int i = 0; i < 4; ++i) {
    #pragma unroll
    for (int r = 0; r < 4; ++r) {
      int srow = (wave << 6) + (i << 4) + (quad << 2) + r;
      float inv = 1.0f / lsum[i][r];
      #pragma unroll
      for (int j2 = 0; j2 < 2; ++j2)
        obuf[(size_t)(srow * 64 + b) * 256 + hh * 32 + (j2 << 4) + l16] = f2b(oacc[i][j2][r] * inv);
    }
  }
}

// ---------------------------------------------------------------------------
// Pooling + heads (g_rep emitted bf16)
// ---------------------------------------------------------------------------
__global__ __launch_bounds__(256) void pool_logit(
    const float* __restrict__ h, const bf16* __restrict__ pw, const bf16* __restrict__ pb,
    float* __restrict__ logits)
{
  int n = blockIdx.x * 4 + (threadIdx.x >> 6); int lane = threadIdx.x & 63;
  float4 hv = load4(h + (size_t)n * 256 + lane * 4);
  float4 wv = load4(pw + lane * 4);
  float acc = wave_sum(hv.x*wv.x + hv.y*wv.y + hv.z*wv.z + hv.w*wv.w);
  if (lane == 0) logits[n] = acc + b2f(pb[0]);
}
__global__ __launch_bounds__(1024) void pool_reduce(
    const float* __restrict__ logits, float* __restrict__ red)
{
  __shared__ float sm[16];
  int t = threadIdx.x;
  float m = -1e30f;
  for (int i = t; i < N_NODES; i += 1024) m = fmaxf(m, logits[i]);
  m = wave_max(m);
  if ((t & 63) == 0) sm[t >> 6] = m;
  __syncthreads();
  if (t == 0) { float mm = sm[0]; for (int i = 1; i < 16; ++i) mm = fmaxf(mm, sm[i]); sm[0] = mm; }
  __syncthreads();
  float gmax = sm[0];
  __syncthreads();
  float s = 0.f;
  for (int i = t; i < N_NODES; i += 1024) s += expf(logits[i] - gmax);
  s = wave_sum(s);
  if ((t & 63) == 0) sm[t >> 6] = s;
  __syncthreads();
  if (t == 0) { float ss = 0.f; for (int i = 0; i < 16; ++i) ss += sm[i]; red[0] = gmax; red[1] = 1.0f / ss; }
}
__global__ __launch_bounds__(256) void pool_grep(
    const float* __restrict__ h, const float* __restrict__ logits,
    const float* __restrict__ red, bf16* __restrict__ g_rep)
{
  __shared__ float w[64];
  int g = blockIdx.x; int tid = threadIdx.x;
  if (tid < 64) w[tid] = expf(logits[g * 64 + tid] - red[0]) * red[1];
  __syncthreads();
  float acc = 0.f;
  for (int nd = 0; nd < 64; ++nd) acc += h[((size_t)g * 64 + nd) * 256 + tid] * w[nd];
  g_rep[(size_t)g * 256 + tid] = f2b(acc);
}
__global__ __launch_bounds__(256) void head_value(
    const float* __restrict__ vt, const bf16* __restrict__ w2, const bf16* __restrict__ b2,
    bf16* __restrict__ out)
{
  int gidx = blockIdx.x * 4 + (threadIdx.x >> 6); int lane = threadIdx.x & 63;
  float acc = 0.f;
  #pragma unroll
  for (int j = 0; j < 4; ++j) { int c = j * 64 + lane; acc += vt[(size_t)gidx * 256 + c] * b2f(w2[c]); }
  acc = wave_sum(acc);
  if (lane == 0) out[gidx] = f2b(tanhf(acc + b2f(b2[0])));
}
__global__ __launch_bounds__(256) void head_unc(
    const float* __restrict__ ut, const bf16* __restrict__ w2, const bf16* __restrict__ b2,
    bf16* __restrict__ out)
{
  int gidx = blockIdx.x * 4 + (threadIdx.x >> 6); int lane = threadIdx.x & 63;
  float acc = 0.f;
  #pragma unroll
  for (int j = 0; j < 2; ++j) { int c = j * 64 + lane; acc += ut[(size_t)gidx * 128 + c] * b2f(w2[c]); }
  acc = wave_sum(acc);
  if (lane == 0) {
    float x = acc + b2f(b2[0]);
    float sp = (x > 20.f) ? x : log1pf(expf(x));
    out[gidx] = f2b(sp);
  }
}

// ---------------------------------------------------------------------------
extern "C" void kernel_launch(void* const* d_in, const int* in_sizes, int n_in,
                              void* d_out, int out_size, void* d_ws, size_t ws_size,
                              hipStream_t stream)
{
  (void)out_size;
  const int* eidx = (const int*)d_in[1];

  char* ws = (char*)d_ws;
  size_t wo = 0;
  auto alloc = [&](size_t bytes) -> char* {
    char* p = ws + wo; wo += (bytes + 255) & ~(size_t)255; return p;
  };
  int*   flags = (int*)alloc(256);
  int*   cnt   = (int*)alloc((size_t)N_NODES * 4);
  int*   fillc = (int*)alloc((size_t)N_NODES * 4);
  size_t zero_end = wo;

  bf16* conv[38] = {};
  static const int fidx[35] = {0,4,5,6,7,8,9,10,11,12,13,14,15,16,17,18,19,
                               20,21,22,23,24,25,26,27,28,29,30,31,32,33,34,35,36,37};
  for (int j = 0; j < 35; ++j) {
    int idx = fidx[j];
    conv[idx] = (bf16*)alloc((size_t)in_sizes[idx] * 2);
  }
  float* h     = (float*)alloc((size_t)N_NODES * 256 * 4);
  bf16*  hb    = (bf16*) alloc((size_t)N_NODES * 256 * 2);   // bf16 mirror of h
  bf16*  big   = (bf16*) alloc((size_t)N_NODES * 1024 * 2);
  const int OUT_ELEMS = 256 + N_NODES * 256 + 256;
  bf16*  tn     = (bf16*)alloc((size_t)N_NODES * 256 * 2);   // adjacent to ostage
  bf16*  ostage = (bf16*)alloc((size_t)OUT_ELEMS * 2);
  int*   off   = (int*)alloc((size_t)(N_NODES + 1) * 4);
  int*   list  = (int*)alloc((size_t)NE2 * 4);
  float* logits= (float*)alloc((size_t)N_NODES * 4);
  float* redb  = (float*)alloc(256);
  bf16*  g_rep = (bf16*)alloc((size_t)256 * 256 * 2);
  float* val_t = (float*)alloc((size_t)256 * 256 * 4);
  float* unc_t = (float*)alloc((size_t)256 * 128 * 4);
  size_t base_needed = wo;

  if (n_in != 38)                   { write_sentinel<<<1,256,0,stream>>>((bf16*)d_out, 4.f);  return; }
  if (in_sizes[0] != N_NODES * 128) { write_sentinel<<<1,256,0,stream>>>((bf16*)d_out, 8.f);  return; }
  if (in_sizes[1] != 2 * NE)        { write_sentinel<<<1,256,0,stream>>>((bf16*)d_out, 16.f); return; }
  if (ws_size < base_needed)        { write_sentinel<<<1,256,0,stream>>>((bf16*)d_out, 32.f); return; }

  size_t msg_bytes = (size_t)4 * N_NODES * 256 * 2;
  bf16* msg4; int halves;
  if (ws_size >= base_needed + msg_bytes + 256) {
    msg4 = (bf16*)alloc(msg_bytes); halves = 1;
  } else {
    msg4 = tn; halves = 2;
  }

  hipMemsetAsync(d_ws, 0, zero_end, stream);

  detect_dtype<<<256, 256, 0, stream>>>((const unsigned short*)d_in[0], 65536, flags);
  {
    ConvArgs ca;
    int cum = 0;
    for (int j = 0; j < 35; ++j) {
      int idx = fidx[j];
      ca.src[j] = d_in[idx];
      ca.dst[j] = (unsigned short*)conv[idx];
      ca.cumg[j] = cum;
      ca.n[j] = in_sizes[idx];
      cum += (in_sizes[idx] + 3) >> 2;
    }
    ca.cumg[35] = cum;
    conv_all4<<<(cum + 255) / 256, 256, 0, stream>>>(ca, flags);
  }
  const bf16 *xb = conv[0], *emb_w = conv[4], *emb_b = conv[5], *gat_w = conv[6],
             *gat_as = conv[7], *gat_ad = conv[8], *gat_b = conv[9], *gnn_g = conv[10],
             *gnn_beta = conv[11], *ln1_g = conv[12], *ln1_b = conv[13], *in_w = conv[14],
             *in_b = conv[15], *out_w = conv[16], *out_b = conv[17], *ln2_g = conv[18],
             *ln2_b = conv[19], *ff1_w = conv[20], *ff1_b = conv[21], *ff2_w = conv[22],
             *ff2_b = conv[23], *pool_w = conv[24], *pool_b = conv[25],
             *vw1 = conv[26], *vb1 = conv[27], *vw2 = conv[28], *vb2 = conv[29],
             *pw1 = conv[30], *pb1 = conv[31], *pw2 = conv[32], *pb2 = conv[33],
             *uw1 = conv[34], *ub1 = conv[35], *uw2 = conv[36], *ub2 = conv[37];

  bf16* qkv  = big;
  bf16* obuf = big + (size_t)N_NODES * 768;
  bf16* hp   = big;
  bf16* ffb  = big;
  bf16* o_val = ostage;
  bf16* o_pol = ostage + 256;
  bf16* o_unc = ostage + 256 + (size_t)N_NODES * 256;

  csr_count<<<(NE2 + 255) / 256, 256, 0, stream>>>(eidx + NE, cnt);
  csr_scan<<<1, 1024, 0, stream>>>(cnt, off);
  csr_fill<<<(NE2 + 255) / 256, 256, 0, stream>>>(eidx + NE, off, fillc, list);

  // Embedding: h (f32) + hb (bf16 mirror)
  gemm2<float, GF_MIR><<<dim3(2, 128), 256, 0, stream>>>(
      xb, emb_w, emb_b, nullptr, h, hb, N_NODES, 256, 128);

  const int gph = 256 / halves;
  const int hn  = N_NODES / halves;
  for (int l = 0; l < 8; ++l) {
    gemm2<bf16, 0><<<dim3(8, 128), 256, 0, stream>>>(
        hb, gat_w + (size_t)l * 1024 * 256, nullptr, nullptr, hp, nullptr, N_NODES, 1024, 256);
    for (int ph = 0; ph < halves; ++ph) {
      gat_graph2<<<gph * 4, 256, 0, stream>>>(eidx, hp, off, list,
          gat_as + l * 1024, gat_ad + l * 1024, msg4, ph * gph, hn);
      gat_epi<<<hn / 4, 256, 0, stream>>>(msg4, hn, ph * hn,
          gat_b + l * 256, gnn_g + l * 256, gnn_beta + l * 256, h, hb);
    }
  }

  for (int l = 0; l < 6; ++l) {
    ln_kernel<<<N_NODES / 4, 256, 0, stream>>>(h, tn, ln1_g + l * 256, ln1_b + l * 256);
    gemm2<bf16, 0><<<dim3(6, 128), 256, 0, stream>>>(
        tn, in_w + (size_t)l * 768 * 256, in_b + l * 768, nullptr, qkv, nullptr, N_NODES, 768, 256);
    attn_mfma<<<512, 256, 0, stream>>>(qkv, obuf);
    gemm2<float, GF_RES><<<dim3(2, 128), 256, 0, stream>>>(
        obuf, out_w + (size_t)l * 256 * 256, out_b + l * 256, h, h, nullptr, N_NODES, 256, 256);
    ln_kernel<<<N_NODES / 4, 256, 0, stream>>>(h, tn, ln2_g + l * 256, ln2_b + l * 256);
    gemm2<bf16, GF_GELU><<<dim3(8, 128), 256, 0, stream>>>(
        tn, ff1_w + (size_t)l * 1024 * 256, ff1_b + l * 1024, nullptr, ffb, nullptr, N_NODES, 1024, 256);
    if (l < 5)
      gemm2<float, GF_RES><<<dim3(2, 128), 256, 0, stream>>>(
          ffb, ff2_w + (size_t)l * 256 * 1024, ff2_b + l * 256, h, h, nullptr, N_NODES, 256, 1024);
    else
      gemm2<float, GF_RES | GF_MIR><<<dim3(2, 128), 256, 0, stream>>>(
          ffb, ff2_w + (size_t)l * 256 * 1024, ff2_b + l * 256, h, h, hb, N_NODES, 256, 1024);
  }

  pool_logit<<<N_NODES / 4, 256, 0, stream>>>(h, pool_w, pool_b, logits);
  pool_reduce<<<1, 1024, 0, stream>>>(logits, redb);
  pool_grep<<<256, 256, 0, stream>>>(h, logits, redb, g_rep);
  gemm2<float, GF_GELU><<<dim3(2, 2), 256, 0, stream>>>(
      g_rep, vw1, vb1, nullptr, val_t, nullptr, 256, 256, 256);
  head_value<<<64, 256, 0, stream>>>(val_t, vw2, vb2, o_val);
  gemm2<float, GF_GELU><<<dim3(1, 2), 256, 0, stream>>>(
      g_rep, uw1, ub1, nullptr, unc_t, nullptr, 256, 128, 256);
  head_unc<<<64, 256, 0, stream>>>(unc_t, uw2, ub2, o_unc);
  gemm2<bf16, GF_GELU><<<dim3(2, 128), 256, 0, stream>>>(
      hb, pw1, pb1, nullptr, tn, nullptr, N_NODES, 256, 256);
  gemm2<bf16, 0><<<dim3(2, 128), 256, 0, stream>>>(
      tn, pw2, pb2, nullptr, o_pol, nullptr, N_NODES, 256, 256);

  emit_out<<<(OUT_ELEMS + 255) / 256, 256, 0, stream>>>(
      (const unsigned short*)ostage, d_out, OUT_ELEMS, flags);
}